// Round 1
// baseline (5400.526 us; speedup 1.0000x reference)
//
#include <hip/hip_runtime.h>
#include <math.h>

// Problem constants
static constexpr int B_  = 2;
static constexpr int L_  = 1024;
static constexpr int DM_ = 768;
static constexpr int NL_ = 4;
static constexpr int E_  = 2 * DM_;     // 1536
static constexpr int N_  = 16;
static constexpr int K_  = 4;
static constexpr int R_  = DM_ / 16;    // 48
static constexpr int M_  = B_ * L_;     // 2048 tokens

// ---------------------------------------------------------------------------
// Block-wide sum over 256 threads (4 waves of 64)
// ---------------------------------------------------------------------------
__device__ __forceinline__ float block_sum(float val, float* sm) {
#pragma unroll
    for (int o = 32; o > 0; o >>= 1) val += __shfl_down(val, o);
    int lane = threadIdx.x & 63, wid = threadIdx.x >> 6;
    __syncthreads();
    if (lane == 0) sm[wid] = val;
    __syncthreads();
    return sm[0] + sm[1] + sm[2] + sm[3];
}

// ---------------------------------------------------------------------------
// resid = (do_add ? resid + src : src);  out = LayerNorm(resid) * w + b
// ---------------------------------------------------------------------------
__global__ __launch_bounds__(256) void add_ln_kernel(
    const float* __restrict__ src, float* __restrict__ resid,
    const float* __restrict__ w, const float* __restrict__ b,
    float* __restrict__ out, int do_add)
{
    constexpr int D = DM_;
    const int row = blockIdx.x;
    const int tid = threadIdx.x;
    __shared__ float sm[4];
    const float* sp = src + (size_t)row * D;
    float* rp = resid + (size_t)row * D;

    float v[3];
    float s = 0.f;
#pragma unroll
    for (int j = 0; j < 3; ++j) {
        int d = j * 256 + tid;
        float vv = sp[d];
        if (do_add) vv += rp[d];
        rp[d] = vv;
        v[j] = vv;
        s += vv;
    }
    float mean = block_sum(s, sm) * (1.f / D);
    float s2 = 0.f;
#pragma unroll
    for (int j = 0; j < 3; ++j) { float dlt = v[j] - mean; s2 += dlt * dlt; }
    float var = block_sum(s2, sm) * (1.f / D);
    float inv = rsqrtf(var + 1e-5f);
    float* op = out + (size_t)row * D;
#pragma unroll
    for (int j = 0; j < 3; ++j) {
        int d = j * 256 + tid;
        op[d] = (v[j] - mean) * inv * w[d] + b[d];
    }
}

// ---------------------------------------------------------------------------
// Generic f32 GEMM:  C[M x N] = act( A[M x Kd] @ W[N x Kd]^T + bias + u⊗v )
// 64x64 tile, BK=16, 256 threads, 4x4 micro-tile per thread.
// act: 0=none 1=silu 2=sigmoid 3=softplus
// ---------------------------------------------------------------------------
__global__ __launch_bounds__(256) void gemm_f32(
    const float* __restrict__ A, int lda,
    const float* __restrict__ W, int ldw,
    float* __restrict__ C, int ldc,
    int M, int N, int Kd,
    const float* __restrict__ bias, int act,
    const float* __restrict__ u, const float* __restrict__ v, int vstride)
{
    __shared__ float As[16][65];
    __shared__ float Bs[16][65];
    const int bm = blockIdx.y * 64;
    const int bn = blockIdx.x * 64;
    const int tid = threadIdx.x;
    const int tx = tid & 15;
    const int ty = tid >> 4;
    const int lr = tid >> 2;          // 0..63 : row within tile for loading
    const int lc = (tid & 3) << 2;    // 0,4,8,12 : col group for loading

    float acc[4][4] = {};

    for (int k0 = 0; k0 < Kd; k0 += 16) {
        // ---- load A tile (64 x 16) ----
        {
            int m = bm + lr;
            float t0 = 0.f, t1 = 0.f, t2 = 0.f, t3 = 0.f;
            if (m < M) {
                const float* src = A + (size_t)m * lda + k0 + lc;
                if ((k0 + lc + 3 < Kd) && ((lda & 3) == 0)) {
                    float4 f = *(const float4*)src;
                    t0 = f.x; t1 = f.y; t2 = f.z; t3 = f.w;
                } else {
                    if (k0 + lc + 0 < Kd) t0 = src[0];
                    if (k0 + lc + 1 < Kd) t1 = src[1];
                    if (k0 + lc + 2 < Kd) t2 = src[2];
                    if (k0 + lc + 3 < Kd) t3 = src[3];
                }
            }
            As[lc + 0][lr] = t0; As[lc + 1][lr] = t1;
            As[lc + 2][lr] = t2; As[lc + 3][lr] = t3;
        }
        // ---- load W tile (64 x 16) ----
        {
            int n = bn + lr;
            float t0 = 0.f, t1 = 0.f, t2 = 0.f, t3 = 0.f;
            if (n < N) {
                const float* src = W + (size_t)n * ldw + k0 + lc;
                if ((k0 + lc + 3 < Kd) && ((ldw & 3) == 0)) {
                    float4 f = *(const float4*)src;
                    t0 = f.x; t1 = f.y; t2 = f.z; t3 = f.w;
                } else {
                    if (k0 + lc + 0 < Kd) t0 = src[0];
                    if (k0 + lc + 1 < Kd) t1 = src[1];
                    if (k0 + lc + 2 < Kd) t2 = src[2];
                    if (k0 + lc + 3 < Kd) t3 = src[3];
                }
            }
            Bs[lc + 0][lr] = t0; Bs[lc + 1][lr] = t1;
            Bs[lc + 2][lr] = t2; Bs[lc + 3][lr] = t3;
        }
        __syncthreads();
#pragma unroll
        for (int k = 0; k < 16; ++k) {
            float a0 = As[k][ty * 4 + 0];
            float a1 = As[k][ty * 4 + 1];
            float a2 = As[k][ty * 4 + 2];
            float a3 = As[k][ty * 4 + 3];
            float b0 = Bs[k][tx * 4 + 0];
            float b1 = Bs[k][tx * 4 + 1];
            float b2 = Bs[k][tx * 4 + 2];
            float b3 = Bs[k][tx * 4 + 3];
            acc[0][0] += a0 * b0; acc[0][1] += a0 * b1; acc[0][2] += a0 * b2; acc[0][3] += a0 * b3;
            acc[1][0] += a1 * b0; acc[1][1] += a1 * b1; acc[1][2] += a1 * b2; acc[1][3] += a1 * b3;
            acc[2][0] += a2 * b0; acc[2][1] += a2 * b1; acc[2][2] += a2 * b2; acc[2][3] += a2 * b3;
            acc[3][0] += a3 * b0; acc[3][1] += a3 * b1; acc[3][2] += a3 * b2; acc[3][3] += a3 * b3;
        }
        __syncthreads();
    }

#pragma unroll
    for (int i = 0; i < 4; ++i) {
        int m = bm + ty * 4 + i;
        if (m >= M) continue;
#pragma unroll
        for (int j = 0; j < 4; ++j) {
            int n = bn + tx * 4 + j;
            if (n >= N) continue;
            float val = acc[i][j];
            if (bias) val += bias[n];
            if (u) val += u[m] * v[(size_t)n * vstride];
            if (act == 1)      val = val / (1.f + __expf(-val));               // silu
            else if (act == 2) val = 1.f / (1.f + __expf(-val));               // sigmoid
            else if (act == 3) val = (val > 20.f) ? val : log1pf(__expf(val)); // softplus
            C[(size_t)m * ldc + n] = val;
        }
    }
}

// ---------------------------------------------------------------------------
// Causal depthwise conv (K=4) + bias + silu.
// xz row-major [M][2E]; uses first E columns.  xc: [M][E]
// ---------------------------------------------------------------------------
__global__ __launch_bounds__(256) void conv_silu_kernel(
    const float* __restrict__ xz, const float* __restrict__ cw,
    const float* __restrict__ cb, float* __restrict__ xc)
{
    int idx = blockIdx.x * 256 + threadIdx.x;   // over M_*E_
    if (idx >= M_ * E_) return;
    int e = idx % E_;
    int m = idx / E_;
    int l = m % L_;
    float acc = cb[e];
    const float w0 = cw[e * 4 + 0], w1 = cw[e * 4 + 1],
                w2 = cw[e * 4 + 2], w3 = cw[e * 4 + 3];
    const float* base = xz + (size_t)m * (2 * E_) + e;
    if (l >= 3) acc += base[-3 * 2 * E_] * w0;
    if (l >= 2) acc += base[-2 * 2 * E_] * w1;
    if (l >= 1) acc += base[-1 * 2 * E_] * w2;
    acc += base[0] * w3;
    xc[idx] = acc / (1.f + __expf(-acc)); // silu
}

// ---------------------------------------------------------------------------
// Sequential SSM scan.  16 lanes cooperate on one (b,e) channel; lane n owns
// state n of N=16.  Fuses  y = (scan_y + xc*D) * silu(z).
// ---------------------------------------------------------------------------
__global__ __launch_bounds__(256) void scan_kernel(
    const float* __restrict__ xc, const float* __restrict__ dt,
    const float* __restrict__ dbl, const float* __restrict__ xz,
    const float* __restrict__ A_log, const float* __restrict__ ssm_D,
    float* __restrict__ y)
{
    const int tid = threadIdx.x;
    const int n = tid & 15;
    const int g = tid >> 4;
    const int c = blockIdx.x * 16 + g;     // channel 0..B_*E_-1
    const int b = c / E_;
    const int e = c % E_;

    const float Av = -__expf(A_log[e * N_ + n]);
    const float Dv = ssm_D[e];
    float h = 0.f;

    const size_t m0 = (size_t)b * L_;
    for (int l = 0; l < L_; ++l) {
        size_t m = m0 + l;
        float dtv = dt[m * E_ + e];
        float xv  = xc[m * E_ + e];
        float Bv  = dbl[m * 80 + R_ + n];
        float Cv  = dbl[m * 80 + R_ + N_ + n];
        float dA  = __expf(dtv * Av);
        h = dA * h + (dtv * xv) * Bv;
        float p = h * Cv;
        p += __shfl_xor(p, 1);
        p += __shfl_xor(p, 2);
        p += __shfl_xor(p, 4);
        p += __shfl_xor(p, 8);
        if (n == 0) {
            float zv = xz[m * (2 * E_) + E_ + e];
            float yv = p + xv * Dv;
            yv = yv * (zv / (1.f + __expf(-zv)));
            y[m * E_ + e] = yv;
        }
    }
}

// ---------------------------------------------------------------------------
// out = x + gate*(mixed - x);  d_out[..] = LayerNorm(out)*w + b
// ---------------------------------------------------------------------------
__global__ __launch_bounds__(256) void final_out_kernel(
    const float* __restrict__ x, const float* __restrict__ gate,
    const float* __restrict__ mixed, const float* __restrict__ w,
    const float* __restrict__ b, float* __restrict__ outp)
{
    constexpr int D = DM_;
    const int row = blockIdx.x;
    const int tid = threadIdx.x;
    __shared__ float sm[4];
    const float* xp = x + (size_t)row * D;
    const float* gp = gate + (size_t)row * D;
    const float* mp = mixed + (size_t)row * D;

    float v[3];
    float s = 0.f;
#pragma unroll
    for (int j = 0; j < 3; ++j) {
        int d = j * 256 + tid;
        float xv = xp[d];
        float o = xv + gp[d] * (mp[d] - xv);
        v[j] = o;
        s += o;
    }
    float mean = block_sum(s, sm) * (1.f / D);
    float s2 = 0.f;
#pragma unroll
    for (int j = 0; j < 3; ++j) { float dlt = v[j] - mean; s2 += dlt * dlt; }
    float var = block_sum(s2, sm) * (1.f / D);
    float inv = rsqrtf(var + 1e-5f);
    float* op = outp + (size_t)row * D;
#pragma unroll
    for (int j = 0; j < 3; ++j) {
        int d = j * 256 + tid;
        op[d] = (v[j] - mean) * inv * w[d] + b[d];
    }
}

// ---------------------------------------------------------------------------
extern "C" void kernel_launch(void* const* d_in, const int* in_sizes, int n_in,
                              void* d_out, int out_size, void* d_ws, size_t ws_size,
                              hipStream_t stream)
{
    const float* x    = (const float*)d_in[0];
    const float* bp   = (const float*)d_in[1];
    const float* inw  = (const float*)d_in[2];
    const float* cw   = (const float*)d_in[3];
    const float* cb   = (const float*)d_in[4];
    const float* xpw  = (const float*)d_in[5];
    const float* dpw  = (const float*)d_in[6];
    const float* dpb  = (const float*)d_in[7];
    const float* alog = (const float*)d_in[8];
    const float* sD   = (const float*)d_in[9];
    const float* opw  = (const float*)d_in[10];
    const float* lnw  = (const float*)d_in[11];
    const float* lnb  = (const float*)d_in[12];
    const float* nfw  = (const float*)d_in[13];
    const float* nfb  = (const float*)d_in[14];
    const float* cw1  = (const float*)d_in[15];
    const float* cb1  = (const float*)d_in[16];
    const float* cw2  = (const float*)d_in[17];
    const float* cb2  = (const float*)d_in[18];
    const float* olnw = (const float*)d_in[19];
    const float* olnb = (const float*)d_in[20];
    float* out = (float*)d_out;

    // workspace layout (floats), total ~82 MB
    float* ws    = (float*)d_ws;
    float* resid = ws;                     ws += (size_t)M_ * DM_;
    float* hln   = ws;                     ws += (size_t)M_ * DM_;   // also "mixed"
    float* xzb   = ws;                     ws += (size_t)M_ * 2 * E_;
    float* xcb   = ws;                     ws += (size_t)M_ * E_;    // also "h1"
    float* dblb  = ws;                     ws += (size_t)M_ * 80;
    float* dtb   = ws;                     ws += (size_t)M_ * E_;
    float* yb    = ws;                     ws += (size_t)M_ * E_;
    float* hs    = ws;                     ws += (size_t)M_ * DM_;
    float* gate  = out + (size_t)M_ * DM_; // second output, written in place

    for (int i = 0; i < NL_; ++i) {
        add_ln_kernel<<<M_, 256, 0, stream>>>(i == 0 ? x : hs, resid,
                                              lnw + i * DM_, lnb + i * DM_,
                                              hln, i > 0 ? 1 : 0);
        // xz = hln @ in_proj_w[i]^T : (2048 x 3072), K=768
        gemm_f32<<<dim3(48, 32), 256, 0, stream>>>(
            hln, DM_, inw + (size_t)i * 2 * E_ * DM_, DM_,
            xzb, 2 * E_, M_, 2 * E_, DM_, nullptr, 0, nullptr, nullptr, 0);
        conv_silu_kernel<<<(M_ * E_) / 256, 256, 0, stream>>>(
            xzb, cw + (size_t)i * E_ * K_, cb + (size_t)i * E_, xcb);
        // dbl = xc @ x_proj_w[i]^T : (2048 x 80), K=1536
        gemm_f32<<<dim3(2, 32), 256, 0, stream>>>(
            xcb, E_, xpw + (size_t)i * 80 * E_, E_,
            dblb, 80, M_, 80, E_, nullptr, 0, nullptr, nullptr, 0);
        // dt = softplus(dbl[:, :48] @ dt_proj_w[i]^T + b) : (2048 x 1536), K=48
        gemm_f32<<<dim3(24, 32), 256, 0, stream>>>(
            dblb, 80, dpw + (size_t)i * E_ * R_, R_,
            dtb, E_, M_, E_, R_, dpb + (size_t)i * E_, 3, nullptr, nullptr, 0);
        scan_kernel<<<(B_ * E_) / 16, 256, 0, stream>>>(
            xcb, dtb, dblb, xzb, alog + (size_t)i * E_ * N_, sD + (size_t)i * E_, yb);
        // hs = y @ out_proj_w[i]^T : (2048 x 768), K=1536
        gemm_f32<<<dim3(12, 32), 256, 0, stream>>>(
            yb, E_, opw + (size_t)i * DM_ * E_, E_,
            hs, DM_, M_, DM_, E_, nullptr, 0, nullptr, nullptr, 0);
    }

    // resid += hs ; mixed = LN(resid, normf)
    add_ln_kernel<<<M_, 256, 0, stream>>>(hs, resid, nfw, nfb, hln, 1);

    // h1 = silu(x @ ctrl_w1[:, :768]^T + bp ⊗ ctrl_w1[:, 768] + b1)
    gemm_f32<<<dim3(12, 32), 256, 0, stream>>>(
        x, DM_, cw1, DM_ + 1, xcb, DM_, M_, DM_, DM_, cb1, 1, bp, cw1 + DM_, DM_ + 1);
    // gate = sigmoid(h1 @ ctrl_w2^T + b2) -> straight into d_out[BLD:]
    gemm_f32<<<dim3(12, 32), 256, 0, stream>>>(
        xcb, DM_, cw2, DM_, gate, DM_, M_, DM_, DM_, cb2, 2, nullptr, nullptr, 0);
    // out = x + gate*(mixed-x); d_out[:BLD] = LN(out)
    final_out_kernel<<<M_, 256, 0, stream>>>(x, gate, hln, olnw, olnb, out);
}

// Round 2
// 3005.656 us; speedup vs baseline: 1.7968x; 1.7968x over previous
//
#include <hip/hip_runtime.h>
#include <math.h>

// Problem constants
static constexpr int B_  = 2;
static constexpr int L_  = 1024;
static constexpr int DM_ = 768;
static constexpr int NL_ = 4;
static constexpr int E_  = 2 * DM_;     // 1536
static constexpr int N_  = 16;
static constexpr int K_  = 4;
static constexpr int R_  = DM_ / 16;    // 48
static constexpr int M_  = B_ * L_;     // 2048 tokens
static constexpr int NC_ = 16;          // scan chunks per sequence
static constexpr int T_  = L_ / NC_;    // 64 steps per chunk

// ---------------------------------------------------------------------------
// Block-wide sum over 256 threads (4 waves of 64)
// ---------------------------------------------------------------------------
__device__ __forceinline__ float block_sum(float val, float* sm) {
#pragma unroll
    for (int o = 32; o > 0; o >>= 1) val += __shfl_down(val, o);
    int lane = threadIdx.x & 63, wid = threadIdx.x >> 6;
    __syncthreads();
    if (lane == 0) sm[wid] = val;
    __syncthreads();
    return sm[0] + sm[1] + sm[2] + sm[3];
}

// ---------------------------------------------------------------------------
// resid = (do_add ? resid + src : src);  out = LayerNorm(resid) * w + b
// ---------------------------------------------------------------------------
__global__ __launch_bounds__(256) void add_ln_kernel(
    const float* __restrict__ src, float* __restrict__ resid,
    const float* __restrict__ w, const float* __restrict__ b,
    float* __restrict__ out, int do_add)
{
    constexpr int D = DM_;
    const int row = blockIdx.x;
    const int tid = threadIdx.x;
    __shared__ float sm[4];
    const float* sp = src + (size_t)row * D;
    float* rp = resid + (size_t)row * D;

    float v[3];
    float s = 0.f;
#pragma unroll
    for (int j = 0; j < 3; ++j) {
        int d = j * 256 + tid;
        float vv = sp[d];
        if (do_add) vv += rp[d];
        rp[d] = vv;
        v[j] = vv;
        s += vv;
    }
    float mean = block_sum(s, sm) * (1.f / D);
    float s2 = 0.f;
#pragma unroll
    for (int j = 0; j < 3; ++j) { float dlt = v[j] - mean; s2 += dlt * dlt; }
    float var = block_sum(s2, sm) * (1.f / D);
    float inv = rsqrtf(var + 1e-5f);
    float* op = out + (size_t)row * D;
#pragma unroll
    for (int j = 0; j < 3; ++j) {
        int d = j * 256 + tid;
        op[d] = (v[j] - mean) * inv * w[d] + b[d];
    }
}

// ---------------------------------------------------------------------------
// Generic f32 GEMM:  C[M x N] = act( A[M x Kd] @ W[N x Kd]^T + bias + u⊗v )
// 64x64 tile, BK=16, 256 threads, 4x4 micro-tile per thread.
// act: 0=none 1=silu 2=sigmoid 3=softplus
// ---------------------------------------------------------------------------
__global__ __launch_bounds__(256) void gemm_f32(
    const float* __restrict__ A, int lda,
    const float* __restrict__ W, int ldw,
    float* __restrict__ C, int ldc,
    int M, int N, int Kd,
    const float* __restrict__ bias, int act,
    const float* __restrict__ u, const float* __restrict__ v, int vstride)
{
    __shared__ float As[16][65];
    __shared__ float Bs[16][65];
    const int bm = blockIdx.y * 64;
    const int bn = blockIdx.x * 64;
    const int tid = threadIdx.x;
    const int tx = tid & 15;
    const int ty = tid >> 4;
    const int lr = tid >> 2;          // 0..63 : row within tile for loading
    const int lc = (tid & 3) << 2;    // 0,4,8,12 : col group for loading

    float acc[4][4] = {};

    for (int k0 = 0; k0 < Kd; k0 += 16) {
        // ---- load A tile (64 x 16) ----
        {
            int m = bm + lr;
            float t0 = 0.f, t1 = 0.f, t2 = 0.f, t3 = 0.f;
            if (m < M) {
                const float* src = A + (size_t)m * lda + k0 + lc;
                if ((k0 + lc + 3 < Kd) && ((lda & 3) == 0)) {
                    float4 f = *(const float4*)src;
                    t0 = f.x; t1 = f.y; t2 = f.z; t3 = f.w;
                } else {
                    if (k0 + lc + 0 < Kd) t0 = src[0];
                    if (k0 + lc + 1 < Kd) t1 = src[1];
                    if (k0 + lc + 2 < Kd) t2 = src[2];
                    if (k0 + lc + 3 < Kd) t3 = src[3];
                }
            }
            As[lc + 0][lr] = t0; As[lc + 1][lr] = t1;
            As[lc + 2][lr] = t2; As[lc + 3][lr] = t3;
        }
        // ---- load W tile (64 x 16) ----
        {
            int n = bn + lr;
            float t0 = 0.f, t1 = 0.f, t2 = 0.f, t3 = 0.f;
            if (n < N) {
                const float* src = W + (size_t)n * ldw + k0 + lc;
                if ((k0 + lc + 3 < Kd) && ((ldw & 3) == 0)) {
                    float4 f = *(const float4*)src;
                    t0 = f.x; t1 = f.y; t2 = f.z; t3 = f.w;
                } else {
                    if (k0 + lc + 0 < Kd) t0 = src[0];
                    if (k0 + lc + 1 < Kd) t1 = src[1];
                    if (k0 + lc + 2 < Kd) t2 = src[2];
                    if (k0 + lc + 3 < Kd) t3 = src[3];
                }
            }
            Bs[lc + 0][lr] = t0; Bs[lc + 1][lr] = t1;
            Bs[lc + 2][lr] = t2; Bs[lc + 3][lr] = t3;
        }
        __syncthreads();
#pragma unroll
        for (int k = 0; k < 16; ++k) {
            float a0 = As[k][ty * 4 + 0];
            float a1 = As[k][ty * 4 + 1];
            float a2 = As[k][ty * 4 + 2];
            float a3 = As[k][ty * 4 + 3];
            float b0 = Bs[k][tx * 4 + 0];
            float b1 = Bs[k][tx * 4 + 1];
            float b2 = Bs[k][tx * 4 + 2];
            float b3 = Bs[k][tx * 4 + 3];
            acc[0][0] += a0 * b0; acc[0][1] += a0 * b1; acc[0][2] += a0 * b2; acc[0][3] += a0 * b3;
            acc[1][0] += a1 * b0; acc[1][1] += a1 * b1; acc[1][2] += a1 * b2; acc[1][3] += a1 * b3;
            acc[2][0] += a2 * b0; acc[2][1] += a2 * b1; acc[2][2] += a2 * b2; acc[2][3] += a2 * b3;
            acc[3][0] += a3 * b0; acc[3][1] += a3 * b1; acc[3][2] += a3 * b2; acc[3][3] += a3 * b3;
        }
        __syncthreads();
    }

#pragma unroll
    for (int i = 0; i < 4; ++i) {
        int m = bm + ty * 4 + i;
        if (m >= M) continue;
#pragma unroll
        for (int j = 0; j < 4; ++j) {
            int n = bn + tx * 4 + j;
            if (n >= N) continue;
            float val = acc[i][j];
            if (bias) val += bias[n];
            if (u) val += u[m] * v[(size_t)n * vstride];
            if (act == 1)      val = val / (1.f + __expf(-val));               // silu
            else if (act == 2) val = 1.f / (1.f + __expf(-val));               // sigmoid
            else if (act == 3) val = (val > 20.f) ? val : log1pf(__expf(val)); // softplus
            C[(size_t)m * ldc + n] = val;
        }
    }
}

// ---------------------------------------------------------------------------
// Causal depthwise conv (K=4) + bias + silu.
// ---------------------------------------------------------------------------
__global__ __launch_bounds__(256) void conv_silu_kernel(
    const float* __restrict__ xz, const float* __restrict__ cw,
    const float* __restrict__ cb, float* __restrict__ xc)
{
    int idx = blockIdx.x * 256 + threadIdx.x;   // over M_*E_
    if (idx >= M_ * E_) return;
    int e = idx % E_;
    int m = idx / E_;
    int l = m % L_;
    float acc = cb[e];
    const float w0 = cw[e * 4 + 0], w1 = cw[e * 4 + 1],
                w2 = cw[e * 4 + 2], w3 = cw[e * 4 + 3];
    const float* base = xz + (size_t)m * (2 * E_) + e;
    if (l >= 3) acc += base[-3 * 2 * E_] * w0;
    if (l >= 2) acc += base[-2 * 2 * E_] * w1;
    if (l >= 1) acc += base[-1 * 2 * E_] * w2;
    acc += base[0] * w3;
    xc[idx] = acc / (1.f + __expf(-acc)); // silu
}

// ---------------------------------------------------------------------------
// Chunked SSM scan — phase 1: per-(channel, chunk) summaries with h_start=0.
// 16-lane group per (c, chunk); lane n owns state n.
// Group->work mapping is chunk-major so consecutive groups in a block have
// consecutive channels e (coalesced dt/xc lines at each step).
// ---------------------------------------------------------------------------
__global__ __launch_bounds__(256) void scan_part1(
    const float* __restrict__ xc, const float* __restrict__ dt,
    const float* __restrict__ dbl, const float* __restrict__ A_log,
    float* __restrict__ sumA, float* __restrict__ sumH)
{
    const int tid = threadIdx.x;
    const int n = tid & 15;
    const int g = tid >> 4;
    const int gid = blockIdx.x * 16 + g;     // 0 .. B*E*NC-1
    const int c = gid % (B_ * E_);
    const int chunk = gid / (B_ * E_);
    const int b = c / E_;
    const int e = c % E_;

    const float Av = -__expf(A_log[e * N_ + n]);
    float h = 0.f, ap = 1.f;
    const size_t m0 = (size_t)b * L_ + (size_t)chunk * T_;
    for (int l = 0; l < T_; ++l) {
        size_t m = m0 + l;
        float dtv = dt[m * E_ + e];
        float xv  = xc[m * E_ + e];
        float Bv  = dbl[m * 80 + R_ + n];
        float dA  = __expf(dtv * Av);
        h = dA * h + (dtv * xv) * Bv;
        ap *= dA;
    }
    size_t sidx = ((size_t)c * N_ + n) * NC_ + chunk;
    sumA[sidx] = ap;
    sumH[sidx] = h;
}

// ---------------------------------------------------------------------------
// Phase 2: per-(channel, state) sequential combine of NC chunk summaries
// -> per-chunk starting state hstart[c][chunk][n].
// ---------------------------------------------------------------------------
__global__ __launch_bounds__(256) void scan_part2(
    const float* __restrict__ sumA, const float* __restrict__ sumH,
    float* __restrict__ hstart)
{
    int idx = blockIdx.x * 256 + threadIdx.x;  // over B*E*N
    if (idx >= B_ * E_ * N_) return;
    int c = idx / N_;
    int n = idx % N_;
    float h = 0.f;
    size_t sbase = (size_t)idx * NC_;
#pragma unroll
    for (int j = 0; j < NC_; ++j) {
        hstart[((size_t)c * NC_ + j) * N_ + n] = h;
        h = sumA[sbase + j] * h + sumH[sbase + j];
    }
}

// ---------------------------------------------------------------------------
// Phase 3: recompute chunk with correct h_start, emit
// y = (sum_n h*C + xc*D) * silu(z).
// ---------------------------------------------------------------------------
__global__ __launch_bounds__(256) void scan_part3(
    const float* __restrict__ xc, const float* __restrict__ dt,
    const float* __restrict__ dbl, const float* __restrict__ xz,
    const float* __restrict__ A_log, const float* __restrict__ ssm_D,
    const float* __restrict__ hstart, float* __restrict__ y)
{
    const int tid = threadIdx.x;
    const int n = tid & 15;
    const int g = tid >> 4;
    const int gid = blockIdx.x * 16 + g;
    const int c = gid % (B_ * E_);
    const int chunk = gid / (B_ * E_);
    const int b = c / E_;
    const int e = c % E_;

    const float Av = -__expf(A_log[e * N_ + n]);
    const float Dv = ssm_D[e];
    float h = hstart[((size_t)c * NC_ + chunk) * N_ + n];
    const size_t m0 = (size_t)b * L_ + (size_t)chunk * T_;
    for (int l = 0; l < T_; ++l) {
        size_t m = m0 + l;
        float dtv = dt[m * E_ + e];
        float xv  = xc[m * E_ + e];
        float Bv  = dbl[m * 80 + R_ + n];
        float Cv  = dbl[m * 80 + R_ + N_ + n];
        float dA  = __expf(dtv * Av);
        h = dA * h + (dtv * xv) * Bv;
        float p = h * Cv;
        p += __shfl_xor(p, 1);
        p += __shfl_xor(p, 2);
        p += __shfl_xor(p, 4);
        p += __shfl_xor(p, 8);
        if (n == 0) {
            float zv = xz[m * (2 * E_) + E_ + e];
            float yv = p + xv * Dv;
            y[m * E_ + e] = yv * (zv / (1.f + __expf(-zv)));
        }
    }
}

// ---------------------------------------------------------------------------
// out = x + gate*(mixed - x);  d_out[..] = LayerNorm(out)*w + b
// ---------------------------------------------------------------------------
__global__ __launch_bounds__(256) void final_out_kernel(
    const float* __restrict__ x, const float* __restrict__ gate,
    const float* __restrict__ mixed, const float* __restrict__ w,
    const float* __restrict__ b, float* __restrict__ outp)
{
    constexpr int D = DM_;
    const int row = blockIdx.x;
    const int tid = threadIdx.x;
    __shared__ float sm[4];
    const float* xp = x + (size_t)row * D;
    const float* gp = gate + (size_t)row * D;
    const float* mp = mixed + (size_t)row * D;

    float v[3];
    float s = 0.f;
#pragma unroll
    for (int j = 0; j < 3; ++j) {
        int d = j * 256 + tid;
        float xv = xp[d];
        float o = xv + gp[d] * (mp[d] - xv);
        v[j] = o;
        s += o;
    }
    float mean = block_sum(s, sm) * (1.f / D);
    float s2 = 0.f;
#pragma unroll
    for (int j = 0; j < 3; ++j) { float dlt = v[j] - mean; s2 += dlt * dlt; }
    float var = block_sum(s2, sm) * (1.f / D);
    float inv = rsqrtf(var + 1e-5f);
    float* op = outp + (size_t)row * D;
#pragma unroll
    for (int j = 0; j < 3; ++j) {
        int d = j * 256 + tid;
        op[d] = (v[j] - mean) * inv * w[d] + b[d];
    }
}

// ---------------------------------------------------------------------------
extern "C" void kernel_launch(void* const* d_in, const int* in_sizes, int n_in,
                              void* d_out, int out_size, void* d_ws, size_t ws_size,
                              hipStream_t stream)
{
    const float* x    = (const float*)d_in[0];
    const float* bp   = (const float*)d_in[1];
    const float* inw  = (const float*)d_in[2];
    const float* cw   = (const float*)d_in[3];
    const float* cb   = (const float*)d_in[4];
    const float* xpw  = (const float*)d_in[5];
    const float* dpw  = (const float*)d_in[6];
    const float* dpb  = (const float*)d_in[7];
    const float* alog = (const float*)d_in[8];
    const float* sD   = (const float*)d_in[9];
    const float* opw  = (const float*)d_in[10];
    const float* lnw  = (const float*)d_in[11];
    const float* lnb  = (const float*)d_in[12];
    const float* nfw  = (const float*)d_in[13];
    const float* nfb  = (const float*)d_in[14];
    const float* cw1  = (const float*)d_in[15];
    const float* cb1  = (const float*)d_in[16];
    const float* cw2  = (const float*)d_in[17];
    const float* cb2  = (const float*)d_in[18];
    const float* olnw = (const float*)d_in[19];
    const float* olnb = (const float*)d_in[20];
    float* out = (float*)d_out;

    // workspace layout (floats), total ~82 MB (unchanged footprint)
    float* ws    = (float*)d_ws;
    float* resid = ws;                     ws += (size_t)M_ * DM_;
    float* hln   = ws;                     ws += (size_t)M_ * DM_;   // also "mixed"
    float* xzb   = ws;                     ws += (size_t)M_ * 2 * E_;
    float* xcb   = ws;                     ws += (size_t)M_ * E_;    // also "h1"
    float* dblb  = ws;                     ws += (size_t)M_ * 80;
    float* dtb   = ws;                     ws += (size_t)M_ * E_;
    float* yb    = ws;                     ws += (size_t)M_ * E_;
    float* hs    = ws;                     ws += (size_t)M_ * DM_;
    float* gate  = out + (size_t)M_ * DM_; // second output, written in place

    // Scan scratch overlays buffers that are dead during the scan:
    //   hln (LN output) is consumed by the in_proj GEMM before the scan;
    //   hs (layer output) is consumed by add_ln before the scan and only
    //   rewritten by out_proj after it.  Sizes: 3 MB each vs 6 MB available.
    float* sumA   = hln;                                 // B*E*N*NC floats
    float* sumH   = hln + (size_t)B_ * E_ * N_ * NC_;    // B*E*N*NC floats
    float* hstart = hs;                                  // B*E*NC*N floats

    for (int i = 0; i < NL_; ++i) {
        add_ln_kernel<<<M_, 256, 0, stream>>>(i == 0 ? x : hs, resid,
                                              lnw + i * DM_, lnb + i * DM_,
                                              hln, i > 0 ? 1 : 0);
        // xz = hln @ in_proj_w[i]^T : (2048 x 3072), K=768
        gemm_f32<<<dim3(48, 32), 256, 0, stream>>>(
            hln, DM_, inw + (size_t)i * 2 * E_ * DM_, DM_,
            xzb, 2 * E_, M_, 2 * E_, DM_, nullptr, 0, nullptr, nullptr, 0);
        conv_silu_kernel<<<(M_ * E_) / 256, 256, 0, stream>>>(
            xzb, cw + (size_t)i * E_ * K_, cb + (size_t)i * E_, xcb);
        // dbl = xc @ x_proj_w[i]^T : (2048 x 80), K=1536
        gemm_f32<<<dim3(2, 32), 256, 0, stream>>>(
            xcb, E_, xpw + (size_t)i * 80 * E_, E_,
            dblb, 80, M_, 80, E_, nullptr, 0, nullptr, nullptr, 0);
        // dt = softplus(dbl[:, :48] @ dt_proj_w[i]^T + b) : (2048 x 1536), K=48
        gemm_f32<<<dim3(24, 32), 256, 0, stream>>>(
            dblb, 80, dpw + (size_t)i * E_ * R_, R_,
            dtb, E_, M_, E_, R_, dpb + (size_t)i * E_, 3, nullptr, nullptr, 0);
        // Chunked SSM scan: summaries -> combine -> emit
        scan_part1<<<(B_ * E_ * NC_) / 16, 256, 0, stream>>>(
            xcb, dtb, dblb, alog + (size_t)i * E_ * N_, sumA, sumH);
        scan_part2<<<(B_ * E_ * N_ + 255) / 256, 256, 0, stream>>>(
            sumA, sumH, hstart);
        scan_part3<<<(B_ * E_ * NC_) / 16, 256, 0, stream>>>(
            xcb, dtb, dblb, xzb, alog + (size_t)i * E_ * N_, sD + (size_t)i * E_,
            hstart, yb);
        // hs = y @ out_proj_w[i]^T : (2048 x 768), K=1536
        gemm_f32<<<dim3(12, 32), 256, 0, stream>>>(
            yb, E_, opw + (size_t)i * DM_ * E_, E_,
            hs, DM_, M_, DM_, E_, nullptr, 0, nullptr, nullptr, 0);
    }

    // resid += hs ; mixed = LN(resid, normf)
    add_ln_kernel<<<M_, 256, 0, stream>>>(hs, resid, nfw, nfb, hln, 1);

    // h1 = silu(x @ ctrl_w1[:, :768]^T + bp ⊗ ctrl_w1[:, 768] + b1)
    gemm_f32<<<dim3(12, 32), 256, 0, stream>>>(
        x, DM_, cw1, DM_ + 1, xcb, DM_, M_, DM_, DM_, cb1, 1, bp, cw1 + DM_, DM_ + 1);
    // gate = sigmoid(h1 @ ctrl_w2^T + b2) -> straight into d_out[BLD:]
    gemm_f32<<<dim3(12, 32), 256, 0, stream>>>(
        xcb, DM_, cw2, DM_, gate, DM_, M_, DM_, DM_, cb2, 2, nullptr, nullptr, 0);
    // out = x + gate*(mixed-x); d_out[:BLD] = LN(out)
    final_out_kernel<<<M_, 256, 0, stream>>>(x, gate, hln, olnw, olnb, out);
}

// Round 3
// 2094.905 us; speedup vs baseline: 2.5779x; 1.4347x over previous
//
#include <hip/hip_runtime.h>
#include <math.h>

// Problem constants
static constexpr int B_  = 2;
static constexpr int L_  = 1024;
static constexpr int DM_ = 768;
static constexpr int NL_ = 4;
static constexpr int E_  = 2 * DM_;     // 1536
static constexpr int N_  = 16;
static constexpr int K_  = 4;
static constexpr int R_  = DM_ / 16;    // 48
static constexpr int M_  = B_ * L_;     // 2048 tokens
static constexpr int NC_ = 16;          // scan chunks per sequence
static constexpr int T_  = L_ / NC_;    // 64 steps per chunk

typedef __bf16 bf16x8 __attribute__((ext_vector_type(8)));
typedef short short8  __attribute__((ext_vector_type(8)));
typedef float f32x4   __attribute__((ext_vector_type(4)));

// ---------------------------------------------------------------------------
__device__ __forceinline__ short f2bf(float x) {
    __bf16 h = (__bf16)x;
    return __builtin_bit_cast(short, h);
}
__device__ __forceinline__ void st8(short* p, float4 x, float4 y) {
    short8 s;
    s[0] = f2bf(x.x); s[1] = f2bf(x.y); s[2] = f2bf(x.z); s[3] = f2bf(x.w);
    s[4] = f2bf(y.x); s[5] = f2bf(y.y); s[6] = f2bf(y.z); s[7] = f2bf(y.w);
    *(short8*)p = s;
}

// ---------------------------------------------------------------------------
// bf16 MFMA GEMM: C[M x N] = act( A[M x Kd] @ W[N x Kd]^T + bias + u⊗v )
// BM=128 fixed, BN in {128, 64}.  BK=32.  4 waves, wave tile 64 x BN/2,
// 16x16x32 fragments.  A, W are f32 in HBM; converted to bf16 during staging.
// Requires: M % 128 == 0, N % BN == 0, Kd % 32 == 0, lda % 4 == 0.
// walign: W rows 16B-aligned (ldw % 4 == 0) -> float4 loads.
// act: 0=none 1=silu 2=sigmoid
// ---------------------------------------------------------------------------
template<int BN>
__global__ __launch_bounds__(256) void gemm_mfma(
    const float* __restrict__ A, int lda,
    const float* __restrict__ W, int ldw, int walign,
    float* __restrict__ C, int ldc, int Kd,
    const float* __restrict__ bias, int act,
    const float* __restrict__ u, const float* __restrict__ v, int vstride)
{
    constexpr int BM = 128;
    constexpr int SA = 40;                 // shorts per LDS row (32 + 8 pad = 80B)
    constexpr int WN = BN / 2;             // wave tile cols
    constexpr int FM = 4;                  // 4 x 16 = 64 rows per wave
    constexpr int FN = WN / 16;
    constexpr int BRT = 256 / BN;          // threads per W row: 2 (BN=128) / 4 (BN=64)
    constexpr int NB4 = 32 / BRT / 4;      // float4 per thread for W: 4 / 2

    __shared__ short As[BM * SA];
    __shared__ short Bs[BN * SA];

    const int tid  = threadIdx.x;
    const int lane = tid & 63;
    const int wave = tid >> 6;
    const int wr = wave >> 1, wc = wave & 1;
    const int bm = blockIdx.y * BM;
    const int bn = blockIdx.x * BN;

    // A staging map: row = tid>>1 (0..127), 16 cols at (tid&1)*16
    const int ar = tid >> 1;
    const int ac = (tid & 1) << 4;
    const float* aptr = A + (size_t)(bm + ar) * lda + ac;
    short* awr = &As[ar * SA + ac];

    // W staging map
    const int br = tid / BRT;
    const int bc = (tid % BRT) * (32 / BRT);
    const float* wptr = W + (size_t)(bn + br) * ldw + bc;
    short* bwr = &Bs[br * SA + bc];

    f32x4 acc[FM][FN];
#pragma unroll
    for (int i = 0; i < FM; ++i)
#pragma unroll
        for (int j = 0; j < FN; ++j)
            acc[i][j] = (f32x4){0.f, 0.f, 0.f, 0.f};

    const short* ard = &As[(wr * 64 + (lane & 15)) * SA + ((lane >> 4) << 3)];
    const short* brd = &Bs[(wc * WN + (lane & 15)) * SA + ((lane >> 4) << 3)];

    float4 aR[4], bR[NB4];
    auto loadA = [&](int k0) {
#pragma unroll
        for (int i = 0; i < 4; ++i)
            aR[i] = *(const float4*)(aptr + k0 + i * 4);
    };
    auto loadW = [&](int k0) {
        const float* p = wptr + k0;
        if (walign) {
#pragma unroll
            for (int i = 0; i < NB4; ++i)
                bR[i] = *(const float4*)(p + i * 4);
        } else {
#pragma unroll
            for (int i = 0; i < NB4; ++i) {
                bR[i].x = p[i * 4 + 0]; bR[i].y = p[i * 4 + 1];
                bR[i].z = p[i * 4 + 2]; bR[i].w = p[i * 4 + 3];
            }
        }
    };

    const int NT = Kd / 32;
    loadA(0); loadW(0);

    for (int t = 0; t < NT; ++t) {
        __syncthreads();                    // LDS free (prev compute done)
        st8(awr, aR[0], aR[1]);
        st8(awr + 8, aR[2], aR[3]);
        st8(bwr, bR[0], bR[1]);
        if constexpr (NB4 == 4) st8(bwr + 8, bR[2], bR[3]);
        __syncthreads();                    // tile visible
        if (t + 1 < NT) { loadA((t + 1) * 32); loadW((t + 1) * 32); } // prefetch
        bf16x8 af[FM], bf[FN];
#pragma unroll
        for (int m = 0; m < FM; ++m)
            af[m] = *(const bf16x8*)(ard + m * 16 * SA);
#pragma unroll
        for (int n = 0; n < FN; ++n)
            bf[n] = *(const bf16x8*)(brd + n * 16 * SA);
#pragma unroll
        for (int m = 0; m < FM; ++m)
#pragma unroll
            for (int n = 0; n < FN; ++n)
                acc[m][n] = __builtin_amdgcn_mfma_f32_16x16x32_bf16(
                    af[m], bf[n], acc[m][n], 0, 0, 0);
    }

    // Epilogue.  D layout: col = lane&15, row = (lane>>4)*4 + reg.
#pragma unroll
    for (int m = 0; m < FM; ++m) {
        const int row0 = bm + wr * 64 + m * 16 + ((lane >> 4) << 2);
#pragma unroll
        for (int n = 0; n < FN; ++n) {
            const int col = bn + wc * WN + n * 16 + (lane & 15);
            const float bia = bias ? bias[col] : 0.f;
            const float vv = u ? v[(size_t)col * vstride] : 0.f;
#pragma unroll
            for (int r = 0; r < 4; ++r) {
                float val = acc[m][n][r] + bia;
                if (u) val += u[row0 + r] * vv;
                if (act == 1)      val = val / (1.f + __expf(-val));
                else if (act == 2) val = 1.f / (1.f + __expf(-val));
                C[(size_t)(row0 + r) * ldc + col] = val;
            }
        }
    }
}

// ---------------------------------------------------------------------------
// Block-wide sum over 256 threads (4 waves of 64)
// ---------------------------------------------------------------------------
__device__ __forceinline__ float block_sum(float val, float* sm) {
#pragma unroll
    for (int o = 32; o > 0; o >>= 1) val += __shfl_down(val, o);
    int lane = threadIdx.x & 63, wid = threadIdx.x >> 6;
    __syncthreads();
    if (lane == 0) sm[wid] = val;
    __syncthreads();
    return sm[0] + sm[1] + sm[2] + sm[3];
}

// ---------------------------------------------------------------------------
// resid = (do_add ? resid + src : src);  out = LayerNorm(resid) * w + b
// ---------------------------------------------------------------------------
__global__ __launch_bounds__(256) void add_ln_kernel(
    const float* __restrict__ src, float* __restrict__ resid,
    const float* __restrict__ w, const float* __restrict__ b,
    float* __restrict__ out, int do_add)
{
    constexpr int D = DM_;
    const int row = blockIdx.x;
    const int tid = threadIdx.x;
    __shared__ float sm[4];
    const float* sp = src + (size_t)row * D;
    float* rp = resid + (size_t)row * D;

    float v[3];
    float s = 0.f;
#pragma unroll
    for (int j = 0; j < 3; ++j) {
        int d = j * 256 + tid;
        float vv = sp[d];
        if (do_add) vv += rp[d];
        rp[d] = vv;
        v[j] = vv;
        s += vv;
    }
    float mean = block_sum(s, sm) * (1.f / D);
    float s2 = 0.f;
#pragma unroll
    for (int j = 0; j < 3; ++j) { float dlt = v[j] - mean; s2 += dlt * dlt; }
    float var = block_sum(s2, sm) * (1.f / D);
    float inv = rsqrtf(var + 1e-5f);
    float* op = out + (size_t)row * D;
#pragma unroll
    for (int j = 0; j < 3; ++j) {
        int d = j * 256 + tid;
        op[d] = (v[j] - mean) * inv * w[d] + b[d];
    }
}

// ---------------------------------------------------------------------------
// Generic f32 GEMM (small shapes: x_proj N=80, dt_proj K=48)
// act: 0=none 3=softplus
// ---------------------------------------------------------------------------
__global__ __launch_bounds__(256) void gemm_f32(
    const float* __restrict__ A, int lda,
    const float* __restrict__ W, int ldw,
    float* __restrict__ C, int ldc,
    int M, int N, int Kd,
    const float* __restrict__ bias, int act)
{
    __shared__ float As[16][65];
    __shared__ float Bs[16][65];
    const int bm = blockIdx.y * 64;
    const int bn = blockIdx.x * 64;
    const int tid = threadIdx.x;
    const int tx = tid & 15;
    const int ty = tid >> 4;
    const int lr = tid >> 2;
    const int lc = (tid & 3) << 2;

    float acc[4][4] = {};

    for (int k0 = 0; k0 < Kd; k0 += 16) {
        {
            int m = bm + lr;
            float t0 = 0.f, t1 = 0.f, t2 = 0.f, t3 = 0.f;
            if (m < M) {
                const float* src = A + (size_t)m * lda + k0 + lc;
                if ((k0 + lc + 3 < Kd) && ((lda & 3) == 0)) {
                    float4 f = *(const float4*)src;
                    t0 = f.x; t1 = f.y; t2 = f.z; t3 = f.w;
                } else {
                    if (k0 + lc + 0 < Kd) t0 = src[0];
                    if (k0 + lc + 1 < Kd) t1 = src[1];
                    if (k0 + lc + 2 < Kd) t2 = src[2];
                    if (k0 + lc + 3 < Kd) t3 = src[3];
                }
            }
            As[lc + 0][lr] = t0; As[lc + 1][lr] = t1;
            As[lc + 2][lr] = t2; As[lc + 3][lr] = t3;
        }
        {
            int n = bn + lr;
            float t0 = 0.f, t1 = 0.f, t2 = 0.f, t3 = 0.f;
            if (n < N) {
                const float* src = W + (size_t)n * ldw + k0 + lc;
                if ((k0 + lc + 3 < Kd) && ((ldw & 3) == 0)) {
                    float4 f = *(const float4*)src;
                    t0 = f.x; t1 = f.y; t2 = f.z; t3 = f.w;
                } else {
                    if (k0 + lc + 0 < Kd) t0 = src[0];
                    if (k0 + lc + 1 < Kd) t1 = src[1];
                    if (k0 + lc + 2 < Kd) t2 = src[2];
                    if (k0 + lc + 3 < Kd) t3 = src[3];
                }
            }
            Bs[lc + 0][lr] = t0; Bs[lc + 1][lr] = t1;
            Bs[lc + 2][lr] = t2; Bs[lc + 3][lr] = t3;
        }
        __syncthreads();
#pragma unroll
        for (int k = 0; k < 16; ++k) {
            float a0 = As[k][ty * 4 + 0];
            float a1 = As[k][ty * 4 + 1];
            float a2 = As[k][ty * 4 + 2];
            float a3 = As[k][ty * 4 + 3];
            float b0 = Bs[k][tx * 4 + 0];
            float b1 = Bs[k][tx * 4 + 1];
            float b2 = Bs[k][tx * 4 + 2];
            float b3 = Bs[k][tx * 4 + 3];
            acc[0][0] += a0 * b0; acc[0][1] += a0 * b1; acc[0][2] += a0 * b2; acc[0][3] += a0 * b3;
            acc[1][0] += a1 * b0; acc[1][1] += a1 * b1; acc[1][2] += a1 * b2; acc[1][3] += a1 * b3;
            acc[2][0] += a2 * b0; acc[2][1] += a2 * b1; acc[2][2] += a2 * b2; acc[2][3] += a2 * b3;
            acc[3][0] += a3 * b0; acc[3][1] += a3 * b1; acc[3][2] += a3 * b2; acc[3][3] += a3 * b3;
        }
        __syncthreads();
    }

#pragma unroll
    for (int i = 0; i < 4; ++i) {
        int m = bm + ty * 4 + i;
        if (m >= M) continue;
#pragma unroll
        for (int j = 0; j < 4; ++j) {
            int n = bn + tx * 4 + j;
            if (n >= N) continue;
            float val = acc[i][j];
            if (bias) val += bias[n];
            if (act == 3) val = (val > 20.f) ? val : log1pf(__expf(val));
            C[(size_t)m * ldc + n] = val;
        }
    }
}

// ---------------------------------------------------------------------------
// Causal depthwise conv (K=4) + bias + silu.
// ---------------------------------------------------------------------------
__global__ __launch_bounds__(256) void conv_silu_kernel(
    const float* __restrict__ xz, const float* __restrict__ cw,
    const float* __restrict__ cb, float* __restrict__ xc)
{
    int idx = blockIdx.x * 256 + threadIdx.x;
    if (idx >= M_ * E_) return;
    int e = idx % E_;
    int m = idx / E_;
    int l = m % L_;
    float acc = cb[e];
    const float w0 = cw[e * 4 + 0], w1 = cw[e * 4 + 1],
                w2 = cw[e * 4 + 2], w3 = cw[e * 4 + 3];
    const float* base = xz + (size_t)m * (2 * E_) + e;
    if (l >= 3) acc += base[-3 * 2 * E_] * w0;
    if (l >= 2) acc += base[-2 * 2 * E_] * w1;
    if (l >= 1) acc += base[-1 * 2 * E_] * w2;
    acc += base[0] * w3;
    xc[idx] = acc / (1.f + __expf(-acc));
}

// ---------------------------------------------------------------------------
// Chunked SSM scan — phase 1: per-(channel, chunk) summaries with h_start=0.
// ---------------------------------------------------------------------------
__global__ __launch_bounds__(256) void scan_part1(
    const float* __restrict__ xc, const float* __restrict__ dt,
    const float* __restrict__ dbl, const float* __restrict__ A_log,
    float* __restrict__ sumA, float* __restrict__ sumH)
{
    const int tid = threadIdx.x;
    const int n = tid & 15;
    const int g = tid >> 4;
    const int gid = blockIdx.x * 16 + g;
    const int c = gid % (B_ * E_);
    const int chunk = gid / (B_ * E_);
    const int b = c / E_;
    const int e = c % E_;

    const float Av = -__expf(A_log[e * N_ + n]);
    float h = 0.f, ap = 1.f;
    const size_t m0 = (size_t)b * L_ + (size_t)chunk * T_;
    for (int l = 0; l < T_; ++l) {
        size_t m = m0 + l;
        float dtv = dt[m * E_ + e];
        float xv  = xc[m * E_ + e];
        float Bv  = dbl[m * 80 + R_ + n];
        float dA  = __expf(dtv * Av);
        h = dA * h + (dtv * xv) * Bv;
        ap *= dA;
    }
    size_t sidx = ((size_t)c * N_ + n) * NC_ + chunk;
    sumA[sidx] = ap;
    sumH[sidx] = h;
}

// ---------------------------------------------------------------------------
// Phase 2: per-(channel, state) sequential combine -> per-chunk start states.
// ---------------------------------------------------------------------------
__global__ __launch_bounds__(256) void scan_part2(
    const float* __restrict__ sumA, const float* __restrict__ sumH,
    float* __restrict__ hstart)
{
    int idx = blockIdx.x * 256 + threadIdx.x;
    if (idx >= B_ * E_ * N_) return;
    int c = idx / N_;
    int n = idx % N_;
    float h = 0.f;
    size_t sbase = (size_t)idx * NC_;
#pragma unroll
    for (int j = 0; j < NC_; ++j) {
        hstart[((size_t)c * NC_ + j) * N_ + n] = h;
        h = sumA[sbase + j] * h + sumH[sbase + j];
    }
}

// ---------------------------------------------------------------------------
// Phase 3: recompute chunk with correct h_start, emit gated y.
// ---------------------------------------------------------------------------
__global__ __launch_bounds__(256) void scan_part3(
    const float* __restrict__ xc, const float* __restrict__ dt,
    const float* __restrict__ dbl, const float* __restrict__ xz,
    const float* __restrict__ A_log, const float* __restrict__ ssm_D,
    const float* __restrict__ hstart, float* __restrict__ y)
{
    const int tid = threadIdx.x;
    const int n = tid & 15;
    const int g = tid >> 4;
    const int gid = blockIdx.x * 16 + g;
    const int c = gid % (B_ * E_);
    const int chunk = gid / (B_ * E_);
    const int b = c / E_;
    const int e = c % E_;

    const float Av = -__expf(A_log[e * N_ + n]);
    const float Dv = ssm_D[e];
    float h = hstart[((size_t)c * NC_ + chunk) * N_ + n];
    const size_t m0 = (size_t)b * L_ + (size_t)chunk * T_;
    for (int l = 0; l < T_; ++l) {
        size_t m = m0 + l;
        float dtv = dt[m * E_ + e];
        float xv  = xc[m * E_ + e];
        float Bv  = dbl[m * 80 + R_ + n];
        float Cv  = dbl[m * 80 + R_ + N_ + n];
        float dA  = __expf(dtv * Av);
        h = dA * h + (dtv * xv) * Bv;
        float p = h * Cv;
        p += __shfl_xor(p, 1);
        p += __shfl_xor(p, 2);
        p += __shfl_xor(p, 4);
        p += __shfl_xor(p, 8);
        if (n == 0) {
            float zv = xz[m * (2 * E_) + E_ + e];
            float yv = p + xv * Dv;
            y[m * E_ + e] = yv * (zv / (1.f + __expf(-zv)));
        }
    }
}

// ---------------------------------------------------------------------------
// out = x + gate*(mixed - x);  d_out[..] = LayerNorm(out)*w + b
// ---------------------------------------------------------------------------
__global__ __launch_bounds__(256) void final_out_kernel(
    const float* __restrict__ x, const float* __restrict__ gate,
    const float* __restrict__ mixed, const float* __restrict__ w,
    const float* __restrict__ b, float* __restrict__ outp)
{
    constexpr int D = DM_;
    const int row = blockIdx.x;
    const int tid = threadIdx.x;
    __shared__ float sm[4];
    const float* xp = x + (size_t)row * D;
    const float* gp = gate + (size_t)row * D;
    const float* mp = mixed + (size_t)row * D;

    float v[3];
    float s = 0.f;
#pragma unroll
    for (int j = 0; j < 3; ++j) {
        int d = j * 256 + tid;
        float xv = xp[d];
        float o = xv + gp[d] * (mp[d] - xv);
        v[j] = o;
        s += o;
    }
    float mean = block_sum(s, sm) * (1.f / D);
    float s2 = 0.f;
#pragma unroll
    for (int j = 0; j < 3; ++j) { float dlt = v[j] - mean; s2 += dlt * dlt; }
    float var = block_sum(s2, sm) * (1.f / D);
    float inv = rsqrtf(var + 1e-5f);
    float* op = outp + (size_t)row * D;
#pragma unroll
    for (int j = 0; j < 3; ++j) {
        int d = j * 256 + tid;
        op[d] = (v[j] - mean) * inv * w[d] + b[d];
    }
}

// ---------------------------------------------------------------------------
extern "C" void kernel_launch(void* const* d_in, const int* in_sizes, int n_in,
                              void* d_out, int out_size, void* d_ws, size_t ws_size,
                              hipStream_t stream)
{
    const float* x    = (const float*)d_in[0];
    const float* bp   = (const float*)d_in[1];
    const float* inw  = (const float*)d_in[2];
    const float* cw   = (const float*)d_in[3];
    const float* cb   = (const float*)d_in[4];
    const float* xpw  = (const float*)d_in[5];
    const float* dpw  = (const float*)d_in[6];
    const float* dpb  = (const float*)d_in[7];
    const float* alog = (const float*)d_in[8];
    const float* sD   = (const float*)d_in[9];
    const float* opw  = (const float*)d_in[10];
    const float* lnw  = (const float*)d_in[11];
    const float* lnb  = (const float*)d_in[12];
    const float* nfw  = (const float*)d_in[13];
    const float* nfb  = (const float*)d_in[14];
    const float* cw1  = (const float*)d_in[15];
    const float* cb1  = (const float*)d_in[16];
    const float* cw2  = (const float*)d_in[17];
    const float* cb2  = (const float*)d_in[18];
    const float* olnw = (const float*)d_in[19];
    const float* olnb = (const float*)d_in[20];
    float* out = (float*)d_out;

    // workspace layout (floats), total ~82 MB (unchanged)
    float* ws    = (float*)d_ws;
    float* resid = ws;                     ws += (size_t)M_ * DM_;
    float* hln   = ws;                     ws += (size_t)M_ * DM_;   // also "mixed"
    float* xzb   = ws;                     ws += (size_t)M_ * 2 * E_;
    float* xcb   = ws;                     ws += (size_t)M_ * E_;    // also "h1"
    float* dblb  = ws;                     ws += (size_t)M_ * 80;
    float* dtb   = ws;                     ws += (size_t)M_ * E_;
    float* yb    = ws;                     ws += (size_t)M_ * E_;
    float* hs    = ws;                     ws += (size_t)M_ * DM_;
    float* gate  = out + (size_t)M_ * DM_;

    // Scan scratch overlays dead buffers (hln consumed by in_proj GEMM;
    // hs consumed by add_ln; both rewritten only after the scan).
    float* sumA   = hln;
    float* sumH   = hln + (size_t)B_ * E_ * N_ * NC_;
    float* hstart = hs;

    for (int i = 0; i < NL_; ++i) {
        add_ln_kernel<<<M_, 256, 0, stream>>>(i == 0 ? x : hs, resid,
                                              lnw + i * DM_, lnb + i * DM_,
                                              hln, i > 0 ? 1 : 0);
        // xz = hln @ in_proj_w[i]^T : 2048 x 3072, K=768  (MFMA bf16)
        gemm_mfma<128><<<dim3(2 * E_ / 128, M_ / 128), 256, 0, stream>>>(
            hln, DM_, inw + (size_t)i * 2 * E_ * DM_, DM_, 1,
            xzb, 2 * E_, DM_, nullptr, 0, nullptr, nullptr, 0);
        conv_silu_kernel<<<(M_ * E_) / 256, 256, 0, stream>>>(
            xzb, cw + (size_t)i * E_ * K_, cb + (size_t)i * E_, xcb);
        // dbl = xc @ x_proj_w[i]^T : 2048 x 80, K=1536  (f32)
        gemm_f32<<<dim3(2, 32), 256, 0, stream>>>(
            xcb, E_, xpw + (size_t)i * 80 * E_, E_,
            dblb, 80, M_, 80, E_, nullptr, 0);
        // dt = softplus(dbl[:, :48] @ dt_proj_w[i]^T + b) : 2048 x 1536, K=48 (f32)
        gemm_f32<<<dim3(24, 32), 256, 0, stream>>>(
            dblb, 80, dpw + (size_t)i * E_ * R_, R_,
            dtb, E_, M_, E_, R_, dpb + (size_t)i * E_, 3);
        // Chunked SSM scan
        scan_part1<<<(B_ * E_ * NC_) / 16, 256, 0, stream>>>(
            xcb, dtb, dblb, alog + (size_t)i * E_ * N_, sumA, sumH);
        scan_part2<<<(B_ * E_ * N_ + 255) / 256, 256, 0, stream>>>(
            sumA, sumH, hstart);
        scan_part3<<<(B_ * E_ * NC_) / 16, 256, 0, stream>>>(
            xcb, dtb, dblb, xzb, alog + (size_t)i * E_ * N_, sD + (size_t)i * E_,
            hstart, yb);
        // hs = y @ out_proj_w[i]^T : 2048 x 768, K=1536  (MFMA bf16)
        gemm_mfma<64><<<dim3(DM_ / 64, M_ / 128), 256, 0, stream>>>(
            yb, E_, opw + (size_t)i * DM_ * E_, E_, 1,
            hs, DM_, E_, nullptr, 0, nullptr, nullptr, 0);
    }

    // resid += hs ; mixed = LN(resid, normf)
    add_ln_kernel<<<M_, 256, 0, stream>>>(hs, resid, nfw, nfb, hln, 1);

    // h1 = silu(x @ ctrl_w1[:, :768]^T + bp ⊗ ctrl_w1[:, 768] + b1)  (MFMA)
    gemm_mfma<64><<<dim3(DM_ / 64, M_ / 128), 256, 0, stream>>>(
        x, DM_, cw1, DM_ + 1, 0,
        xcb, DM_, DM_, cb1, 1, bp, cw1 + DM_, DM_ + 1);
    // gate = sigmoid(h1 @ ctrl_w2^T + b2) -> d_out[BLD:]  (MFMA)
    gemm_mfma<64><<<dim3(DM_ / 64, M_ / 128), 256, 0, stream>>>(
        xcb, DM_, cw2, DM_, 1,
        gate, DM_, DM_, cb2, 2, nullptr, nullptr, 0);
    // out = x + gate*(mixed-x); d_out[:BLD] = LN(out)
    final_out_kernel<<<M_, 256, 0, stream>>>(x, gate, hln, olnw, olnb, out);
}

// Round 4
// 1614.472 us; speedup vs baseline: 3.3451x; 1.2976x over previous
//
#include <hip/hip_runtime.h>
#include <math.h>

// Problem constants
static constexpr int B_  = 2;
static constexpr int L_  = 1024;
static constexpr int DM_ = 768;
static constexpr int NL_ = 4;
static constexpr int E_  = 2 * DM_;     // 1536
static constexpr int N_  = 16;
static constexpr int K_  = 4;
static constexpr int R_  = DM_ / 16;    // 48
static constexpr int M_  = B_ * L_;     // 2048 tokens
static constexpr int NC_ = 16;          // scan chunks per sequence
static constexpr int T_  = L_ / NC_;    // 64 steps per chunk
static constexpr int SK_ = 8;           // split-K slices for x_proj
static constexpr int KS_ = E_ / SK_;    // 192 per slice

typedef __bf16 bf16x8 __attribute__((ext_vector_type(8)));
typedef short short8  __attribute__((ext_vector_type(8)));
typedef float f32x4   __attribute__((ext_vector_type(4)));

// ---------------------------------------------------------------------------
__device__ __forceinline__ short f2bf(float x) {
    __bf16 h = (__bf16)x;
    return __builtin_bit_cast(short, h);
}
__device__ __forceinline__ void st8(short* p, float4 x, float4 y) {
    short8 s;
    s[0] = f2bf(x.x); s[1] = f2bf(x.y); s[2] = f2bf(x.z); s[3] = f2bf(x.w);
    s[4] = f2bf(y.x); s[5] = f2bf(y.y); s[6] = f2bf(y.z); s[7] = f2bf(y.w);
    *(short8*)p = s;
}

// ---------------------------------------------------------------------------
// bf16 MFMA GEMM: C[M x N] = act( A[M x Kd] @ W[N x Kd]^T + bias + u⊗v )
// BM=128 fixed, BN in {128, 64}.  BK=32.  4 waves, wave tile 64 x BN/2,
// 16x16x32 fragments.  A, W are f32 in HBM; converted to bf16 during staging.
// Kd may be any multiple of 16 (K-tail zero-padded in LDS).
// Requires: M % 128 == 0, N % BN == 0, lda % 4 == 0.
// walign: W rows 16B-aligned (ldw % 4 == 0) -> float4 loads.
// act: 0=none 1=silu 2=sigmoid 3=softplus
// ---------------------------------------------------------------------------
template<int BN>
__global__ __launch_bounds__(256) void gemm_mfma(
    const float* __restrict__ A, int lda,
    const float* __restrict__ W, int ldw, int walign,
    float* __restrict__ C, int ldc, int Kd,
    const float* __restrict__ bias, int act,
    const float* __restrict__ u, const float* __restrict__ v, int vstride)
{
    constexpr int BM = 128;
    constexpr int SA = 40;                 // shorts per LDS row (32 + 8 pad)
    constexpr int WN = BN / 2;             // wave tile cols
    constexpr int FM = 4;                  // 4 x 16 = 64 rows per wave
    constexpr int FN = WN / 16;
    constexpr int BRT = 256 / BN;          // threads per W row
    constexpr int NB4 = 32 / BRT / 4;      // float4 per thread for W

    __shared__ short As[BM * SA];
    __shared__ short Bs[BN * SA];

    const int tid  = threadIdx.x;
    const int lane = tid & 63;
    const int wave = tid >> 6;
    const int wr = wave >> 1, wc = wave & 1;
    const int bm = blockIdx.y * BM;
    const int bn = blockIdx.x * BN;

    // A staging map: row = tid>>1 (0..127), 16 cols at (tid&1)*16
    const int ar = tid >> 1;
    const int ac = (tid & 1) << 4;
    const float* aptr = A + (size_t)(bm + ar) * lda + ac;
    short* awr = &As[ar * SA + ac];

    // W staging map
    const int br = tid / BRT;
    const int bc = (tid % BRT) * (32 / BRT);
    const float* wptr = W + (size_t)(bn + br) * ldw + bc;
    short* bwr = &Bs[br * SA + bc];

    f32x4 acc[FM][FN];
#pragma unroll
    for (int i = 0; i < FM; ++i)
#pragma unroll
        for (int j = 0; j < FN; ++j)
            acc[i][j] = (f32x4){0.f, 0.f, 0.f, 0.f};

    const short* ard = &As[(wr * 64 + (lane & 15)) * SA + ((lane >> 4) << 3)];
    const short* brd = &Bs[(wc * WN + (lane & 15)) * SA + ((lane >> 4) << 3)];

    float4 aR[4], bR[NB4];
    auto loadA = [&](int k0) {
        if (k0 + ac < Kd) {
#pragma unroll
            for (int i = 0; i < 4; ++i)
                aR[i] = *(const float4*)(aptr + k0 + i * 4);
        } else {
#pragma unroll
            for (int i = 0; i < 4; ++i) aR[i] = {0.f, 0.f, 0.f, 0.f};
        }
    };
    auto loadW = [&](int k0) {
        const float* p = wptr + k0;
        if (k0 + bc < Kd) {
            if (walign) {
#pragma unroll
                for (int i = 0; i < NB4; ++i)
                    bR[i] = *(const float4*)(p + i * 4);
            } else {
#pragma unroll
                for (int i = 0; i < NB4; ++i) {
                    bR[i].x = p[i * 4 + 0]; bR[i].y = p[i * 4 + 1];
                    bR[i].z = p[i * 4 + 2]; bR[i].w = p[i * 4 + 3];
                }
            }
        } else {
#pragma unroll
            for (int i = 0; i < NB4; ++i) bR[i] = {0.f, 0.f, 0.f, 0.f};
        }
    };

    const int NT = (Kd + 31) / 32;
    loadA(0); loadW(0);

    for (int t = 0; t < NT; ++t) {
        __syncthreads();
        st8(awr, aR[0], aR[1]);
        st8(awr + 8, aR[2], aR[3]);
        st8(bwr, bR[0], bR[1]);
        if constexpr (NB4 == 4) st8(bwr + 8, bR[2], bR[3]);
        __syncthreads();
        if (t + 1 < NT) { loadA((t + 1) * 32); loadW((t + 1) * 32); }
        bf16x8 af[FM], bf[FN];
#pragma unroll
        for (int m = 0; m < FM; ++m)
            af[m] = *(const bf16x8*)(ard + m * 16 * SA);
#pragma unroll
        for (int n = 0; n < FN; ++n)
            bf[n] = *(const bf16x8*)(brd + n * 16 * SA);
#pragma unroll
        for (int m = 0; m < FM; ++m)
#pragma unroll
            for (int n = 0; n < FN; ++n)
                acc[m][n] = __builtin_amdgcn_mfma_f32_16x16x32_bf16(
                    af[m], bf[n], acc[m][n], 0, 0, 0);
    }

    // Epilogue.  D layout: col = lane&15, row = (lane>>4)*4 + reg.
#pragma unroll
    for (int m = 0; m < FM; ++m) {
        const int row0 = bm + wr * 64 + m * 16 + ((lane >> 4) << 2);
#pragma unroll
        for (int n = 0; n < FN; ++n) {
            const int col = bn + wc * WN + n * 16 + (lane & 15);
            const float bia = bias ? bias[col] : 0.f;
            const float vv = u ? v[(size_t)col * vstride] : 0.f;
#pragma unroll
            for (int r = 0; r < 4; ++r) {
                float val = acc[m][n][r] + bia;
                if (u) val += u[row0 + r] * vv;
                if (act == 1)      val = val / (1.f + __expf(-val));
                else if (act == 2) val = 1.f / (1.f + __expf(-val));
                else if (act == 3) val = (val > 20.f) ? val : log1pf(__expf(val));
                C[(size_t)(row0 + r) * ldc + col] = val;
            }
        }
    }
}

// ---------------------------------------------------------------------------
// x_proj split-K MFMA: part[sk][M][80] = xc[M, sk*192:(sk+1)*192] @ W^T slice
// Grid: (SK_, M/128).  4 waves; wave w owns rows w*32..w*32+32 (2 m-frags),
// all 80 cols (5 n-frags).
// ---------------------------------------------------------------------------
__global__ __launch_bounds__(256) void xproj_mfma(
    const float* __restrict__ A,          // [M][E]
    const float* __restrict__ W,          // [80][E]
    float* __restrict__ part)             // [SK][M][80]
{
    constexpr int SA = 40;
    __shared__ short As[128 * SA];
    __shared__ short Ws[80 * SA];

    const int tid  = threadIdx.x;
    const int lane = tid & 63;
    const int wave = tid >> 6;
    const int sk = blockIdx.x;
    const int bm = blockIdx.y * 128;
    const int kbase = sk * KS_;

    const int ar = tid >> 1;
    const int ac = (tid & 1) << 4;
    const float* aptr = A + (size_t)(bm + ar) * E_ + kbase + ac;
    short* awr = &As[ar * SA + ac];

    const bool wact = tid < 160;
    const int wrow = tid >> 1;            // 0..79 when active
    const float* wptr = W + (size_t)wrow * E_ + kbase + ac;
    short* wwr = &Ws[wrow * SA + ac];

    f32x4 acc[2][5];
#pragma unroll
    for (int i = 0; i < 2; ++i)
#pragma unroll
        for (int j = 0; j < 5; ++j)
            acc[i][j] = (f32x4){0.f, 0.f, 0.f, 0.f};

    const short* ard = &As[(wave * 32 + (lane & 15)) * SA + ((lane >> 4) << 3)];
    const short* brd = &Ws[(lane & 15) * SA + ((lane >> 4) << 3)];

    float4 aR[4], wR[4];
    auto loadT = [&](int k0) {
#pragma unroll
        for (int i = 0; i < 4; ++i)
            aR[i] = *(const float4*)(aptr + k0 + i * 4);
        if (wact) {
#pragma unroll
            for (int i = 0; i < 4; ++i)
                wR[i] = *(const float4*)(wptr + k0 + i * 4);
        }
    };

    constexpr int NT = KS_ / 32;          // 6
    loadT(0);
    for (int t = 0; t < NT; ++t) {
        __syncthreads();
        st8(awr, aR[0], aR[1]);
        st8(awr + 8, aR[2], aR[3]);
        if (wact) {
            st8(wwr, wR[0], wR[1]);
            st8(wwr + 8, wR[2], wR[3]);
        }
        __syncthreads();
        if (t + 1 < NT) loadT((t + 1) * 32);
        bf16x8 af[2], bf[5];
#pragma unroll
        for (int m = 0; m < 2; ++m)
            af[m] = *(const bf16x8*)(ard + m * 16 * SA);
#pragma unroll
        for (int n = 0; n < 5; ++n)
            bf[n] = *(const bf16x8*)(brd + n * 16 * SA);
#pragma unroll
        for (int m = 0; m < 2; ++m)
#pragma unroll
            for (int n = 0; n < 5; ++n)
                acc[m][n] = __builtin_amdgcn_mfma_f32_16x16x32_bf16(
                    af[m], bf[n], acc[m][n], 0, 0, 0);
    }

    float* pout = part + (size_t)sk * M_ * 80;
#pragma unroll
    for (int m = 0; m < 2; ++m) {
        const int row0 = bm + wave * 32 + m * 16 + ((lane >> 4) << 2);
#pragma unroll
        for (int n = 0; n < 5; ++n) {
            const int col = n * 16 + (lane & 15);
#pragma unroll
            for (int r = 0; r < 4; ++r)
                pout[(size_t)(row0 + r) * 80 + col] = acc[m][n][r];
        }
    }
}

// part[SK][M*80] -> dbl[M*80]  (deterministic reduce, no atomics)
__global__ __launch_bounds__(256) void xproj_reduce(
    const float* __restrict__ part, float* __restrict__ dbl)
{
    int idx = blockIdx.x * 256 + threadIdx.x;   // over M_*80
    float s = 0.f;
#pragma unroll
    for (int k = 0; k < SK_; ++k) s += part[(size_t)k * M_ * 80 + idx];
    dbl[idx] = s;
}

// ---------------------------------------------------------------------------
// Block-wide sum over 256 threads (4 waves of 64)
// ---------------------------------------------------------------------------
__device__ __forceinline__ float block_sum(float val, float* sm) {
#pragma unroll
    for (int o = 32; o > 0; o >>= 1) val += __shfl_down(val, o);
    int lane = threadIdx.x & 63, wid = threadIdx.x >> 6;
    __syncthreads();
    if (lane == 0) sm[wid] = val;
    __syncthreads();
    return sm[0] + sm[1] + sm[2] + sm[3];
}

// ---------------------------------------------------------------------------
// resid = (do_add ? resid + src : src);  out = LayerNorm(resid) * w + b
// ---------------------------------------------------------------------------
__global__ __launch_bounds__(256) void add_ln_kernel(
    const float* __restrict__ src, float* __restrict__ resid,
    const float* __restrict__ w, const float* __restrict__ b,
    float* __restrict__ out, int do_add)
{
    constexpr int D = DM_;
    const int row = blockIdx.x;
    const int tid = threadIdx.x;
    __shared__ float sm[4];
    const float* sp = src + (size_t)row * D;
    float* rp = resid + (size_t)row * D;

    float v[3];
    float s = 0.f;
#pragma unroll
    for (int j = 0; j < 3; ++j) {
        int d = j * 256 + tid;
        float vv = sp[d];
        if (do_add) vv += rp[d];
        rp[d] = vv;
        v[j] = vv;
        s += vv;
    }
    float mean = block_sum(s, sm) * (1.f / D);
    float s2 = 0.f;
#pragma unroll
    for (int j = 0; j < 3; ++j) { float dlt = v[j] - mean; s2 += dlt * dlt; }
    float var = block_sum(s2, sm) * (1.f / D);
    float inv = rsqrtf(var + 1e-5f);
    float* op = out + (size_t)row * D;
#pragma unroll
    for (int j = 0; j < 3; ++j) {
        int d = j * 256 + tid;
        op[d] = (v[j] - mean) * inv * w[d] + b[d];
    }
}

// ---------------------------------------------------------------------------
// Causal depthwise conv (K=4) + bias + silu.
// ---------------------------------------------------------------------------
__global__ __launch_bounds__(256) void conv_silu_kernel(
    const float* __restrict__ xz, const float* __restrict__ cw,
    const float* __restrict__ cb, float* __restrict__ xc)
{
    int idx = blockIdx.x * 256 + threadIdx.x;
    if (idx >= M_ * E_) return;
    int e = idx % E_;
    int m = idx / E_;
    int l = m % L_;
    float acc = cb[e];
    const float w0 = cw[e * 4 + 0], w1 = cw[e * 4 + 1],
                w2 = cw[e * 4 + 2], w3 = cw[e * 4 + 3];
    const float* base = xz + (size_t)m * (2 * E_) + e;
    if (l >= 3) acc += base[-3 * 2 * E_] * w0;
    if (l >= 2) acc += base[-2 * 2 * E_] * w1;
    if (l >= 1) acc += base[-1 * 2 * E_] * w2;
    acc += base[0] * w3;
    xc[idx] = acc / (1.f + __expf(-acc));
}

// ---------------------------------------------------------------------------
// Chunked SSM scan — phase 1: per-(channel, chunk) summaries with h_start=0.
// ---------------------------------------------------------------------------
__global__ __launch_bounds__(256) void scan_part1(
    const float* __restrict__ xc, const float* __restrict__ dt,
    const float* __restrict__ dbl, const float* __restrict__ A_log,
    float* __restrict__ sumA, float* __restrict__ sumH)
{
    const int tid = threadIdx.x;
    const int n = tid & 15;
    const int g = tid >> 4;
    const int gid = blockIdx.x * 16 + g;
    const int c = gid % (B_ * E_);
    const int chunk = gid / (B_ * E_);
    const int b = c / E_;
    const int e = c % E_;

    const float Av = -__expf(A_log[e * N_ + n]);
    float h = 0.f, ap = 1.f;
    const size_t m0 = (size_t)b * L_ + (size_t)chunk * T_;
    for (int l = 0; l < T_; ++l) {
        size_t m = m0 + l;
        float dtv = dt[m * E_ + e];
        float xv  = xc[m * E_ + e];
        float Bv  = dbl[m * 80 + R_ + n];
        float dA  = __expf(dtv * Av);
        h = dA * h + (dtv * xv) * Bv;
        ap *= dA;
    }
    size_t sidx = ((size_t)c * N_ + n) * NC_ + chunk;
    sumA[sidx] = ap;
    sumH[sidx] = h;
}

// ---------------------------------------------------------------------------
// Phase 2: per-(channel, state) sequential combine -> per-chunk start states.
// ---------------------------------------------------------------------------
__global__ __launch_bounds__(256) void scan_part2(
    const float* __restrict__ sumA, const float* __restrict__ sumH,
    float* __restrict__ hstart)
{
    int idx = blockIdx.x * 256 + threadIdx.x;
    if (idx >= B_ * E_ * N_) return;
    int c = idx / N_;
    int n = idx % N_;
    float h = 0.f;
    size_t sbase = (size_t)idx * NC_;
#pragma unroll
    for (int j = 0; j < NC_; ++j) {
        hstart[((size_t)c * NC_ + j) * N_ + n] = h;
        h = sumA[sbase + j] * h + sumH[sbase + j];
    }
}

// ---------------------------------------------------------------------------
// Phase 3: recompute chunk with correct h_start, emit gated y.
// ---------------------------------------------------------------------------
__global__ __launch_bounds__(256) void scan_part3(
    const float* __restrict__ xc, const float* __restrict__ dt,
    const float* __restrict__ dbl, const float* __restrict__ xz,
    const float* __restrict__ A_log, const float* __restrict__ ssm_D,
    const float* __restrict__ hstart, float* __restrict__ y)
{
    const int tid = threadIdx.x;
    const int n = tid & 15;
    const int g = tid >> 4;
    const int gid = blockIdx.x * 16 + g;
    const int c = gid % (B_ * E_);
    const int chunk = gid / (B_ * E_);
    const int b = c / E_;
    const int e = c % E_;

    const float Av = -__expf(A_log[e * N_ + n]);
    const float Dv = ssm_D[e];
    float h = hstart[((size_t)c * NC_ + chunk) * N_ + n];
    const size_t m0 = (size_t)b * L_ + (size_t)chunk * T_;
    for (int l = 0; l < T_; ++l) {
        size_t m = m0 + l;
        float dtv = dt[m * E_ + e];
        float xv  = xc[m * E_ + e];
        float Bv  = dbl[m * 80 + R_ + n];
        float Cv  = dbl[m * 80 + R_ + N_ + n];
        float dA  = __expf(dtv * Av);
        h = dA * h + (dtv * xv) * Bv;
        float p = h * Cv;
        p += __shfl_xor(p, 1);
        p += __shfl_xor(p, 2);
        p += __shfl_xor(p, 4);
        p += __shfl_xor(p, 8);
        if (n == 0) {
            float zv = xz[m * (2 * E_) + E_ + e];
            float yv = p + xv * Dv;
            y[m * E_ + e] = yv * (zv / (1.f + __expf(-zv)));
        }
    }
}

// ---------------------------------------------------------------------------
// out = x + gate*(mixed - x);  d_out[..] = LayerNorm(out)*w + b
// ---------------------------------------------------------------------------
__global__ __launch_bounds__(256) void final_out_kernel(
    const float* __restrict__ x, const float* __restrict__ gate,
    const float* __restrict__ mixed, const float* __restrict__ w,
    const float* __restrict__ b, float* __restrict__ outp)
{
    constexpr int D = DM_;
    const int row = blockIdx.x;
    const int tid = threadIdx.x;
    __shared__ float sm[4];
    const float* xp = x + (size_t)row * D;
    const float* gp = gate + (size_t)row * D;
    const float* mp = mixed + (size_t)row * D;

    float v[3];
    float s = 0.f;
#pragma unroll
    for (int j = 0; j < 3; ++j) {
        int d = j * 256 + tid;
        float xv = xp[d];
        float o = xv + gp[d] * (mp[d] - xv);
        v[j] = o;
        s += o;
    }
    float mean = block_sum(s, sm) * (1.f / D);
    float s2 = 0.f;
#pragma unroll
    for (int j = 0; j < 3; ++j) { float dlt = v[j] - mean; s2 += dlt * dlt; }
    float var = block_sum(s2, sm) * (1.f / D);
    float inv = rsqrtf(var + 1e-5f);
    float* op = outp + (size_t)row * D;
#pragma unroll
    for (int j = 0; j < 3; ++j) {
        int d = j * 256 + tid;
        op[d] = (v[j] - mean) * inv * w[d] + b[d];
    }
}

// ---------------------------------------------------------------------------
extern "C" void kernel_launch(void* const* d_in, const int* in_sizes, int n_in,
                              void* d_out, int out_size, void* d_ws, size_t ws_size,
                              hipStream_t stream)
{
    const float* x    = (const float*)d_in[0];
    const float* bp   = (const float*)d_in[1];
    const float* inw  = (const float*)d_in[2];
    const float* cw   = (const float*)d_in[3];
    const float* cb   = (const float*)d_in[4];
    const float* xpw  = (const float*)d_in[5];
    const float* dpw  = (const float*)d_in[6];
    const float* dpb  = (const float*)d_in[7];
    const float* alog = (const float*)d_in[8];
    const float* sD   = (const float*)d_in[9];
    const float* opw  = (const float*)d_in[10];
    const float* lnw  = (const float*)d_in[11];
    const float* lnb  = (const float*)d_in[12];
    const float* nfw  = (const float*)d_in[13];
    const float* nfb  = (const float*)d_in[14];
    const float* cw1  = (const float*)d_in[15];
    const float* cb1  = (const float*)d_in[16];
    const float* cw2  = (const float*)d_in[17];
    const float* cb2  = (const float*)d_in[18];
    const float* olnw = (const float*)d_in[19];
    const float* olnb = (const float*)d_in[20];
    float* out = (float*)d_out;

    // workspace layout (floats), total ~82 MB (unchanged)
    float* ws    = (float*)d_ws;
    float* resid = ws;                     ws += (size_t)M_ * DM_;
    float* hln   = ws;                     ws += (size_t)M_ * DM_;   // also "mixed"
    float* xzb   = ws;                     ws += (size_t)M_ * 2 * E_;
    float* xcb   = ws;                     ws += (size_t)M_ * E_;    // also "h1"
    float* dblb  = ws;                     ws += (size_t)M_ * 80;
    float* dtb   = ws;                     ws += (size_t)M_ * E_;
    float* yb    = ws;                     ws += (size_t)M_ * E_;
    float* hs    = ws;                     ws += (size_t)M_ * DM_;
    float* gate  = out + (size_t)M_ * DM_;

    // Overlays on dead buffers:
    //   sumA/sumH on hln (dead after in_proj GEMM consumes it);
    //   hstart on hs (dead between add_ln and out_proj);
    //   x_proj split-K partials on yb (prev layer's y already consumed;
    //   scan_part3 rewrites yb only after the reduce).
    float* sumA   = hln;
    float* sumH   = hln + (size_t)B_ * E_ * N_ * NC_;
    float* hstart = hs;
    float* xpart  = yb;                    // SK_*M_*80 = 1.31M floats < M_*E_

    for (int i = 0; i < NL_; ++i) {
        add_ln_kernel<<<M_, 256, 0, stream>>>(i == 0 ? x : hs, resid,
                                              lnw + i * DM_, lnb + i * DM_,
                                              hln, i > 0 ? 1 : 0);
        // xz = hln @ in_proj_w[i]^T : 2048 x 3072, K=768  (MFMA bf16)
        gemm_mfma<128><<<dim3(2 * E_ / 128, M_ / 128), 256, 0, stream>>>(
            hln, DM_, inw + (size_t)i * 2 * E_ * DM_, DM_, 1,
            xzb, 2 * E_, DM_, nullptr, 0, nullptr, nullptr, 0);
        conv_silu_kernel<<<(M_ * E_) / 256, 256, 0, stream>>>(
            xzb, cw + (size_t)i * E_ * K_, cb + (size_t)i * E_, xcb);
        // dbl = xc @ x_proj_w[i]^T : 2048 x 80, K=1536  (split-K MFMA)
        xproj_mfma<<<dim3(SK_, M_ / 128), 256, 0, stream>>>(
            xcb, xpw + (size_t)i * 80 * E_, xpart);
        xproj_reduce<<<(M_ * 80) / 256, 256, 0, stream>>>(xpart, dblb);
        // dt = softplus(dbl[:, :48] @ dt_proj_w[i]^T + b) : 2048 x 1536, K=48 (MFMA)
        gemm_mfma<64><<<dim3(E_ / 64, M_ / 128), 256, 0, stream>>>(
            dblb, 80, dpw + (size_t)i * E_ * R_, R_, 1,
            dtb, E_, R_, dpb + (size_t)i * E_, 3, nullptr, nullptr, 0);
        // Chunked SSM scan
        scan_part1<<<(B_ * E_ * NC_) / 16, 256, 0, stream>>>(
            xcb, dtb, dblb, alog + (size_t)i * E_ * N_, sumA, sumH);
        scan_part2<<<(B_ * E_ * N_ + 255) / 256, 256, 0, stream>>>(
            sumA, sumH, hstart);
        scan_part3<<<(B_ * E_ * NC_) / 16, 256, 0, stream>>>(
            xcb, dtb, dblb, xzb, alog + (size_t)i * E_ * N_, sD + (size_t)i * E_,
            hstart, yb);
        // hs = y @ out_proj_w[i]^T : 2048 x 768, K=1536  (MFMA bf16)
        gemm_mfma<64><<<dim3(DM_ / 64, M_ / 128), 256, 0, stream>>>(
            yb, E_, opw + (size_t)i * DM_ * E_, E_, 1,
            hs, DM_, E_, nullptr, 0, nullptr, nullptr, 0);
    }

    // resid += hs ; mixed = LN(resid, normf)
    add_ln_kernel<<<M_, 256, 0, stream>>>(hs, resid, nfw, nfb, hln, 1);

    // h1 = silu(x @ ctrl_w1[:, :768]^T + bp ⊗ ctrl_w1[:, 768] + b1)  (MFMA)
    gemm_mfma<64><<<dim3(DM_ / 64, M_ / 128), 256, 0, stream>>>(
        x, DM_, cw1, DM_ + 1, 0,
        xcb, DM_, DM_, cb1, 1, bp, cw1 + DM_, DM_ + 1);
    // gate = sigmoid(h1 @ ctrl_w2^T + b2) -> d_out[BLD:]  (MFMA)
    gemm_mfma<64><<<dim3(DM_ / 64, M_ / 128), 256, 0, stream>>>(
        xcb, DM_, cw2, DM_, 1,
        gate, DM_, DM_, cb2, 2, nullptr, nullptr, 0);
    // out = x + gate*(mixed-x); d_out[:BLD] = LN(out)
    final_out_kernel<<<M_, 256, 0, stream>>>(x, gate, hln, olnw, olnb, out);
}

// Round 5
// 1079.140 us; speedup vs baseline: 5.0045x; 1.4961x over previous
//
#include <hip/hip_runtime.h>
#include <math.h>

// Problem constants
static constexpr int B_  = 2;
static constexpr int L_  = 1024;
static constexpr int DM_ = 768;
static constexpr int NL_ = 4;
static constexpr int E_  = 2 * DM_;     // 1536
static constexpr int N_  = 16;
static constexpr int K_  = 4;
static constexpr int R_  = DM_ / 16;    // 48
static constexpr int M_  = B_ * L_;     // 2048 tokens
static constexpr int NC_ = 16;          // scan chunks per sequence
static constexpr int T_  = L_ / NC_;    // 64 steps per chunk
static constexpr int SK_ = 8;           // split-K slices for x_proj
static constexpr int KS_ = E_ / SK_;    // 192 per slice

typedef __bf16 bf16x8 __attribute__((ext_vector_type(8)));
typedef short short8  __attribute__((ext_vector_type(8)));
typedef float f32x4   __attribute__((ext_vector_type(4)));

// ---------------------------------------------------------------------------
__device__ __forceinline__ short f2bf(float x) {
    __bf16 h = (__bf16)x;
    return __builtin_bit_cast(short, h);
}
__device__ __forceinline__ void st8(short* p, float4 x, float4 y) {
    short8 s;
    s[0] = f2bf(x.x); s[1] = f2bf(x.y); s[2] = f2bf(x.z); s[3] = f2bf(x.w);
    s[4] = f2bf(y.x); s[5] = f2bf(y.y); s[6] = f2bf(y.z); s[7] = f2bf(y.w);
    *(short8*)p = s;
}

// async global->LDS, 16 bytes per lane.  LDS dest is wave-uniform base +
// lane*16 (hardware rule); global src is per-lane.
__device__ __forceinline__ void gload16(const void* g, void* l) {
    __builtin_amdgcn_global_load_lds(
        (const __attribute__((address_space(1))) unsigned int*)g,
        (__attribute__((address_space(3))) unsigned int*)l,
        16, 0, 0);
}

// ---------------------------------------------------------------------------
// bf16-input MFMA GEMM, m97 structure: global_load_lds(16B) staging into
// linear LDS [rows][32] bf16, 2 barriers per K-step, 16x16x32 MFMA.
// BM=128; BN in {128, 64}.  4 waves, wave tile 64 x BN/2.
// Split-K via blockIdx.z: slice z uses A+z*Kd, W+z*Kd, writes C+z*M*ldc.
// act: 0=none 1=silu 2=sigmoid.  out_bf16: write __bf16 instead of float.
// Requires: M%128==0, N%BN==0, Kd%32==0, rows of A/W 16B-aligned.
// ---------------------------------------------------------------------------
template<int BN>
__global__ __launch_bounds__(256) void gemm_bf16(
    const __bf16* __restrict__ A, int lda,
    const __bf16* __restrict__ W, int ldw,
    void* __restrict__ Cout, int ldc, int Kd, int out_bf16,
    const float* __restrict__ bias, int act,
    const float* __restrict__ u, const float* __restrict__ v, int vstride)
{
    constexpr int BM = 128;
    constexpr int WN = BN / 2;
    constexpr int FM = 4;
    constexpr int FN = WN / 16;

    __shared__ __bf16 As[BM * 32];
    __shared__ __bf16 Bs[BN * 32];

    const int tid  = threadIdx.x;
    const int lane = tid & 63;
    const int wave = tid >> 6;
    const int wr = wave >> 1, wc = wave & 1;
    const int bm = blockIdx.y * BM;
    const int bn = blockIdx.x * BN;
    const int sk = blockIdx.z;

    A += (size_t)sk * Kd;
    W += (size_t)sk * Kd;
    const size_t cz = (size_t)sk * (size_t)gridDim.y * BM * ldc;

    // staging map: instr i covers rows i*64 + tid/4, 16B chunk tid%4
    const int sr = tid >> 2;
    const int sc = (tid & 3) << 3;
    const __bf16* ag0 = A + (size_t)(bm + sr) * lda + sc;
    const __bf16* ag1 = A + (size_t)(bm + 64 + sr) * lda + sc;
    const __bf16* wg0 = W + (size_t)(bn + sr) * ldw + sc;
    const __bf16* wg1 = W + (size_t)(bn + 64 + sr) * ldw + sc;  // BN=128 only

    __bf16* lA0 = As + wave * 512;          // wave-uniform LDS bases
    __bf16* lA1 = As + 2048 + wave * 512;
    __bf16* lB0 = Bs + wave * 512;
    __bf16* lB1 = Bs + 2048 + wave * 512;

    f32x4 acc[FM][FN];
#pragma unroll
    for (int i = 0; i < FM; ++i)
#pragma unroll
        for (int j = 0; j < FN; ++j)
            acc[i][j] = (f32x4){0.f, 0.f, 0.f, 0.f};

    const __bf16* ard = As + (wr * 64 + (lane & 15)) * 32 + ((lane >> 4) << 3);
    const __bf16* brd = Bs + (wc * WN + (lane & 15)) * 32 + ((lane >> 4) << 3);

    const int NT = Kd / 32;
    for (int t = 0; t < NT; ++t) {
        const int k0 = t * 32;
        __syncthreads();                       // prior reads of LDS done
        gload16(ag0 + k0, lA0);
        gload16(ag1 + k0, lA1);
        gload16(wg0 + k0, lB0);
        if constexpr (BN == 128) gload16(wg1 + k0, lB1);
        __syncthreads();                       // vmcnt(0) drain -> tile ready
        bf16x8 af[FM], bf[FN];
#pragma unroll
        for (int m = 0; m < FM; ++m)
            af[m] = *(const bf16x8*)(ard + m * 512);
#pragma unroll
        for (int n = 0; n < FN; ++n)
            bf[n] = *(const bf16x8*)(brd + n * 512);
#pragma unroll
        for (int m = 0; m < FM; ++m)
#pragma unroll
            for (int n = 0; n < FN; ++n)
                acc[m][n] = __builtin_amdgcn_mfma_f32_16x16x32_bf16(
                    af[m], bf[n], acc[m][n], 0, 0, 0);
    }

    // Epilogue.  D layout: col = lane&15, row = (lane>>4)*4 + reg.
#pragma unroll
    for (int m = 0; m < FM; ++m) {
        const int row0 = bm + wr * 64 + m * 16 + ((lane >> 4) << 2);
#pragma unroll
        for (int n = 0; n < FN; ++n) {
            const int col = bn + wc * WN + n * 16 + (lane & 15);
            const float bia = bias ? bias[col] : 0.f;
            const float vv = u ? v[(size_t)col * vstride] : 0.f;
#pragma unroll
            for (int r = 0; r < 4; ++r) {
                float val = acc[m][n][r] + bia;
                if (u) val += u[row0 + r] * vv;
                if (act == 1)      val = val / (1.f + __expf(-val));
                else if (act == 2) val = 1.f / (1.f + __expf(-val));
                size_t off = cz + (size_t)(row0 + r) * ldc + col;
                if (out_bf16) ((__bf16*)Cout)[off] = (__bf16)val;
                else          ((float*)Cout)[off]  = val;
            }
        }
    }
}

// ---------------------------------------------------------------------------
// f32 -> bf16 conversion, 8 elems/thread
// ---------------------------------------------------------------------------
__global__ __launch_bounds__(256) void cvt_bf16_kernel(
    const float* __restrict__ src, __bf16* __restrict__ dst, int n8)
{
    int i = blockIdx.x * 256 + threadIdx.x;
    if (i >= n8) return;
    const float4* s = (const float4*)src;
    st8((short*)(dst + (size_t)i * 8), s[2 * i], s[2 * i + 1]);
}

// ctrl_w1 [768][769] -> bf16 [768][768] (drop last column)
__global__ __launch_bounds__(256) void cvt_cw1_kernel(
    const float* __restrict__ src, __bf16* __restrict__ dst)
{
    int idx = blockIdx.x * 256 + threadIdx.x;
    if (idx >= DM_ * DM_) return;
    int r = idx / DM_, c = idx % DM_;
    dst[idx] = (__bf16)src[(size_t)r * (DM_ + 1) + c];
}

// out = p[0..n) + p[n..2n)
__global__ __launch_bounds__(256) void reduce2_kernel(
    const float* __restrict__ p, float* __restrict__ out)
{
    int idx = blockIdx.x * 256 + threadIdx.x;   // over M_*DM_
    out[idx] = p[idx] + p[(size_t)M_ * DM_ + idx];
}

// ---------------------------------------------------------------------------
// old reg-staged f32->bf16 MFMA GEMM (kept for dt_proj: K=48)
// ---------------------------------------------------------------------------
template<int BN>
__global__ __launch_bounds__(256) void gemm_mfma(
    const float* __restrict__ A, int lda,
    const float* __restrict__ W, int ldw, int walign,
    float* __restrict__ C, int ldc, int Kd,
    const float* __restrict__ bias, int act,
    const float* __restrict__ u, const float* __restrict__ v, int vstride)
{
    constexpr int BM = 128;
    constexpr int SA = 40;
    constexpr int WN = BN / 2;
    constexpr int FM = 4;
    constexpr int FN = WN / 16;
    constexpr int BRT = 256 / BN;
    constexpr int NB4 = 32 / BRT / 4;

    __shared__ short As[BM * SA];
    __shared__ short Bs[BN * SA];

    const int tid  = threadIdx.x;
    const int lane = tid & 63;
    const int wave = tid >> 6;
    const int wr = wave >> 1, wc = wave & 1;
    const int bm = blockIdx.y * BM;
    const int bn = blockIdx.x * BN;

    const int ar = tid >> 1;
    const int ac = (tid & 1) << 4;
    const float* aptr = A + (size_t)(bm + ar) * lda + ac;
    short* awr = &As[ar * SA + ac];

    const int br = tid / BRT;
    const int bc = (tid % BRT) * (32 / BRT);
    const float* wptr = W + (size_t)(bn + br) * ldw + bc;
    short* bwr = &Bs[br * SA + bc];

    f32x4 acc[FM][FN];
#pragma unroll
    for (int i = 0; i < FM; ++i)
#pragma unroll
        for (int j = 0; j < FN; ++j)
            acc[i][j] = (f32x4){0.f, 0.f, 0.f, 0.f};

    const short* ard = &As[(wr * 64 + (lane & 15)) * SA + ((lane >> 4) << 3)];
    const short* brd = &Bs[(wc * WN + (lane & 15)) * SA + ((lane >> 4) << 3)];

    float4 aR[4], bR[NB4];
    auto loadA = [&](int k0) {
        if (k0 + ac < Kd) {
#pragma unroll
            for (int i = 0; i < 4; ++i)
                aR[i] = *(const float4*)(aptr + k0 + i * 4);
        } else {
#pragma unroll
            for (int i = 0; i < 4; ++i) aR[i] = {0.f, 0.f, 0.f, 0.f};
        }
    };
    auto loadW = [&](int k0) {
        const float* p = wptr + k0;
        if (k0 + bc < Kd) {
            if (walign) {
#pragma unroll
                for (int i = 0; i < NB4; ++i)
                    bR[i] = *(const float4*)(p + i * 4);
            } else {
#pragma unroll
                for (int i = 0; i < NB4; ++i) {
                    bR[i].x = p[i * 4 + 0]; bR[i].y = p[i * 4 + 1];
                    bR[i].z = p[i * 4 + 2]; bR[i].w = p[i * 4 + 3];
                }
            }
        } else {
#pragma unroll
            for (int i = 0; i < NB4; ++i) bR[i] = {0.f, 0.f, 0.f, 0.f};
        }
    };

    const int NT = (Kd + 31) / 32;
    loadA(0); loadW(0);

    for (int t = 0; t < NT; ++t) {
        __syncthreads();
        st8(awr, aR[0], aR[1]);
        st8(awr + 8, aR[2], aR[3]);
        st8(bwr, bR[0], bR[1]);
        if constexpr (NB4 == 4) st8(bwr + 8, bR[2], bR[3]);
        __syncthreads();
        if (t + 1 < NT) { loadA((t + 1) * 32); loadW((t + 1) * 32); }
        bf16x8 af[FM], bf[FN];
#pragma unroll
        for (int m = 0; m < FM; ++m)
            af[m] = *(const bf16x8*)(ard + m * 16 * SA);
#pragma unroll
        for (int n = 0; n < FN; ++n)
            bf[n] = *(const bf16x8*)(brd + n * 16 * SA);
#pragma unroll
        for (int m = 0; m < FM; ++m)
#pragma unroll
            for (int n = 0; n < FN; ++n)
                acc[m][n] = __builtin_amdgcn_mfma_f32_16x16x32_bf16(
                    af[m], bf[n], acc[m][n], 0, 0, 0);
    }

#pragma unroll
    for (int m = 0; m < FM; ++m) {
        const int row0 = bm + wr * 64 + m * 16 + ((lane >> 4) << 2);
#pragma unroll
        for (int n = 0; n < FN; ++n) {
            const int col = bn + wc * WN + n * 16 + (lane & 15);
            const float bia = bias ? bias[col] : 0.f;
            const float vv = u ? v[(size_t)col * vstride] : 0.f;
#pragma unroll
            for (int r = 0; r < 4; ++r) {
                float val = acc[m][n][r] + bia;
                if (u) val += u[row0 + r] * vv;
                if (act == 1)      val = val / (1.f + __expf(-val));
                else if (act == 2) val = 1.f / (1.f + __expf(-val));
                else if (act == 3) val = (val > 20.f) ? val : log1pf(__expf(val));
                C[(size_t)(row0 + r) * ldc + col] = val;
            }
        }
    }
}

// ---------------------------------------------------------------------------
// x_proj split-K MFMA (reg-staged f32, unchanged)
// ---------------------------------------------------------------------------
__global__ __launch_bounds__(256) void xproj_mfma(
    const float* __restrict__ A, const float* __restrict__ W,
    float* __restrict__ part)
{
    constexpr int SA = 40;
    __shared__ short As[128 * SA];
    __shared__ short Ws[80 * SA];

    const int tid  = threadIdx.x;
    const int lane = tid & 63;
    const int wave = tid >> 6;
    const int sk = blockIdx.x;
    const int bm = blockIdx.y * 128;
    const int kbase = sk * KS_;

    const int ar = tid >> 1;
    const int ac = (tid & 1) << 4;
    const float* aptr = A + (size_t)(bm + ar) * E_ + kbase + ac;
    short* awr = &As[ar * SA + ac];

    const bool wact = tid < 160;
    const int wrow = tid >> 1;
    const float* wptr = W + (size_t)wrow * E_ + kbase + ac;
    short* wwr = &Ws[wrow * SA + ac];

    f32x4 acc[2][5];
#pragma unroll
    for (int i = 0; i < 2; ++i)
#pragma unroll
        for (int j = 0; j < 5; ++j)
            acc[i][j] = (f32x4){0.f, 0.f, 0.f, 0.f};

    const short* ard = &As[(wave * 32 + (lane & 15)) * SA + ((lane >> 4) << 3)];
    const short* brd = &Ws[(lane & 15) * SA + ((lane >> 4) << 3)];

    float4 aR[4], wR[4];
    auto loadT = [&](int k0) {
#pragma unroll
        for (int i = 0; i < 4; ++i)
            aR[i] = *(const float4*)(aptr + k0 + i * 4);
        if (wact) {
#pragma unroll
            for (int i = 0; i < 4; ++i)
                wR[i] = *(const float4*)(wptr + k0 + i * 4);
        }
    };

    constexpr int NT = KS_ / 32;
    loadT(0);
    for (int t = 0; t < NT; ++t) {
        __syncthreads();
        st8(awr, aR[0], aR[1]);
        st8(awr + 8, aR[2], aR[3]);
        if (wact) {
            st8(wwr, wR[0], wR[1]);
            st8(wwr + 8, wR[2], wR[3]);
        }
        __syncthreads();
        if (t + 1 < NT) loadT((t + 1) * 32);
        bf16x8 af[2], bf[5];
#pragma unroll
        for (int m = 0; m < 2; ++m)
            af[m] = *(const bf16x8*)(ard + m * 16 * SA);
#pragma unroll
        for (int n = 0; n < 5; ++n)
            bf[n] = *(const bf16x8*)(brd + n * 16 * SA);
#pragma unroll
        for (int m = 0; m < 2; ++m)
#pragma unroll
            for (int n = 0; n < 5; ++n)
                acc[m][n] = __builtin_amdgcn_mfma_f32_16x16x32_bf16(
                    af[m], bf[n], acc[m][n], 0, 0, 0);
    }

    float* pout = part + (size_t)sk * M_ * 80;
#pragma unroll
    for (int m = 0; m < 2; ++m) {
        const int row0 = bm + wave * 32 + m * 16 + ((lane >> 4) << 2);
#pragma unroll
        for (int n = 0; n < 5; ++n) {
            const int col = n * 16 + (lane & 15);
#pragma unroll
            for (int r = 0; r < 4; ++r)
                pout[(size_t)(row0 + r) * 80 + col] = acc[m][n][r];
        }
    }
}

__global__ __launch_bounds__(256) void xproj_reduce(
    const float* __restrict__ part, float* __restrict__ dbl)
{
    int idx = blockIdx.x * 256 + threadIdx.x;
    float s = 0.f;
#pragma unroll
    for (int k = 0; k < SK_; ++k) s += part[(size_t)k * M_ * 80 + idx];
    dbl[idx] = s;
}

// ---------------------------------------------------------------------------
__device__ __forceinline__ float block_sum(float val, float* sm) {
#pragma unroll
    for (int o = 32; o > 0; o >>= 1) val += __shfl_down(val, o);
    int lane = threadIdx.x & 63, wid = threadIdx.x >> 6;
    __syncthreads();
    if (lane == 0) sm[wid] = val;
    __syncthreads();
    return sm[0] + sm[1] + sm[2] + sm[3];
}

// ---------------------------------------------------------------------------
// resid = (do_add ? resid + src : src); LN -> outf (f32, opt) and outb (bf16, opt)
// ---------------------------------------------------------------------------
__global__ __launch_bounds__(256) void add_ln_kernel(
    const float* __restrict__ src, float* __restrict__ resid,
    const float* __restrict__ w, const float* __restrict__ b,
    float* __restrict__ outf, __bf16* __restrict__ outb, int do_add)
{
    constexpr int D = DM_;
    const int row = blockIdx.x;
    const int tid = threadIdx.x;
    __shared__ float sm[4];
    const float* sp = src + (size_t)row * D;
    float* rp = resid + (size_t)row * D;

    float v[3];
    float s = 0.f;
#pragma unroll
    for (int j = 0; j < 3; ++j) {
        int d = j * 256 + tid;
        float vv = sp[d];
        if (do_add) vv += rp[d];
        rp[d] = vv;
        v[j] = vv;
        s += vv;
    }
    float mean = block_sum(s, sm) * (1.f / D);
    float s2 = 0.f;
#pragma unroll
    for (int j = 0; j < 3; ++j) { float dlt = v[j] - mean; s2 += dlt * dlt; }
    float var = block_sum(s2, sm) * (1.f / D);
    float inv = rsqrtf(var + 1e-5f);
#pragma unroll
    for (int j = 0; j < 3; ++j) {
        int d = j * 256 + tid;
        float r = (v[j] - mean) * inv * w[d] + b[d];
        if (outf) outf[(size_t)row * D + d] = r;
        if (outb) outb[(size_t)row * D + d] = (__bf16)r;
    }
}

// ---------------------------------------------------------------------------
__global__ __launch_bounds__(256) void conv_silu_kernel(
    const float* __restrict__ xz, const float* __restrict__ cw,
    const float* __restrict__ cb, float* __restrict__ xc)
{
    int idx = blockIdx.x * 256 + threadIdx.x;
    if (idx >= M_ * E_) return;
    int e = idx % E_;
    int m = idx / E_;
    int l = m % L_;
    float acc = cb[e];
    const float w0 = cw[e * 4 + 0], w1 = cw[e * 4 + 1],
                w2 = cw[e * 4 + 2], w3 = cw[e * 4 + 3];
    const float* base = xz + (size_t)m * (2 * E_) + e;
    if (l >= 3) acc += base[-3 * 2 * E_] * w0;
    if (l >= 2) acc += base[-2 * 2 * E_] * w1;
    if (l >= 1) acc += base[-1 * 2 * E_] * w2;
    acc += base[0] * w3;
    xc[idx] = acc / (1.f + __expf(-acc));
}

// ---------------------------------------------------------------------------
__global__ __launch_bounds__(256) void scan_part1(
    const float* __restrict__ xc, const float* __restrict__ dt,
    const float* __restrict__ dbl, const float* __restrict__ A_log,
    float* __restrict__ sumA, float* __restrict__ sumH)
{
    const int tid = threadIdx.x;
    const int n = tid & 15;
    const int g = tid >> 4;
    const int gid = blockIdx.x * 16 + g;
    const int c = gid % (B_ * E_);
    const int chunk = gid / (B_ * E_);
    const int b = c / E_;
    const int e = c % E_;

    const float Av = -__expf(A_log[e * N_ + n]);
    float h = 0.f, ap = 1.f;
    const size_t m0 = (size_t)b * L_ + (size_t)chunk * T_;
    for (int l = 0; l < T_; ++l) {
        size_t m = m0 + l;
        float dtv = dt[m * E_ + e];
        float xv  = xc[m * E_ + e];
        float Bv  = dbl[m * 80 + R_ + n];
        float dA  = __expf(dtv * Av);
        h = dA * h + (dtv * xv) * Bv;
        ap *= dA;
    }
    size_t sidx = ((size_t)c * N_ + n) * NC_ + chunk;
    sumA[sidx] = ap;
    sumH[sidx] = h;
}

__global__ __launch_bounds__(256) void scan_part2(
    const float* __restrict__ sumA, const float* __restrict__ sumH,
    float* __restrict__ hstart)
{
    int idx = blockIdx.x * 256 + threadIdx.x;
    if (idx >= B_ * E_ * N_) return;
    int c = idx / N_;
    int n = idx % N_;
    float h = 0.f;
    size_t sbase = (size_t)idx * NC_;
#pragma unroll
    for (int j = 0; j < NC_; ++j) {
        hstart[((size_t)c * NC_ + j) * N_ + n] = h;
        h = sumA[sbase + j] * h + sumH[sbase + j];
    }
}

__global__ __launch_bounds__(256) void scan_part3(
    const float* __restrict__ xc, const float* __restrict__ dt,
    const float* __restrict__ dbl, const float* __restrict__ xz,
    const float* __restrict__ A_log, const float* __restrict__ ssm_D,
    const float* __restrict__ hstart, __bf16* __restrict__ y)
{
    const int tid = threadIdx.x;
    const int n = tid & 15;
    const int g = tid >> 4;
    const int gid = blockIdx.x * 16 + g;
    const int c = gid % (B_ * E_);
    const int chunk = gid / (B_ * E_);
    const int b = c / E_;
    const int e = c % E_;

    const float Av = -__expf(A_log[e * N_ + n]);
    const float Dv = ssm_D[e];
    float h = hstart[((size_t)c * NC_ + chunk) * N_ + n];
    const size_t m0 = (size_t)b * L_ + (size_t)chunk * T_;
    for (int l = 0; l < T_; ++l) {
        size_t m = m0 + l;
        float dtv = dt[m * E_ + e];
        float xv  = xc[m * E_ + e];
        float Bv  = dbl[m * 80 + R_ + n];
        float Cv  = dbl[m * 80 + R_ + N_ + n];
        float dA  = __expf(dtv * Av);
        h = dA * h + (dtv * xv) * Bv;
        float p = h * Cv;
        p += __shfl_xor(p, 1);
        p += __shfl_xor(p, 2);
        p += __shfl_xor(p, 4);
        p += __shfl_xor(p, 8);
        if (n == 0) {
            float zv = xz[m * (2 * E_) + E_ + e];
            float yv = p + xv * Dv;
            y[m * E_ + e] = (__bf16)(yv * (zv / (1.f + __expf(-zv))));
        }
    }
}

// ---------------------------------------------------------------------------
__global__ __launch_bounds__(256) void final_out_kernel(
    const float* __restrict__ x, const float* __restrict__ gate,
    const float* __restrict__ mixed, const float* __restrict__ w,
    const float* __restrict__ b, float* __restrict__ outp)
{
    constexpr int D = DM_;
    const int row = blockIdx.x;
    const int tid = threadIdx.x;
    __shared__ float sm[4];
    const float* xp = x + (size_t)row * D;
    const float* gp = gate + (size_t)row * D;
    const float* mp = mixed + (size_t)row * D;

    float v[3];
    float s = 0.f;
#pragma unroll
    for (int j = 0; j < 3; ++j) {
        int d = j * 256 + tid;
        float xv = xp[d];
        float o = xv + gp[d] * (mp[d] - xv);
        v[j] = o;
        s += o;
    }
    float mean = block_sum(s, sm) * (1.f / D);
    float s2 = 0.f;
#pragma unroll
    for (int j = 0; j < 3; ++j) { float dlt = v[j] - mean; s2 += dlt * dlt; }
    float var = block_sum(s2, sm) * (1.f / D);
    float inv = rsqrtf(var + 1e-5f);
    float* op = outp + (size_t)row * D;
#pragma unroll
    for (int j = 0; j < 3; ++j) {
        int d = j * 256 + tid;
        op[d] = (v[j] - mean) * inv * w[d] + b[d];
    }
}

// ---------------------------------------------------------------------------
extern "C" void kernel_launch(void* const* d_in, const int* in_sizes, int n_in,
                              void* d_out, int out_size, void* d_ws, size_t ws_size,
                              hipStream_t stream)
{
    const float* x    = (const float*)d_in[0];
    const float* bp   = (const float*)d_in[1];
    const float* inw  = (const float*)d_in[2];
    const float* cw   = (const float*)d_in[3];
    const float* cb   = (const float*)d_in[4];
    const float* xpw  = (const float*)d_in[5];
    const float* dpw  = (const float*)d_in[6];
    const float* dpb  = (const float*)d_in[7];
    const float* alog = (const float*)d_in[8];
    const float* sD   = (const float*)d_in[9];
    const float* opw  = (const float*)d_in[10];
    const float* lnw  = (const float*)d_in[11];
    const float* lnb  = (const float*)d_in[12];
    const float* nfw  = (const float*)d_in[13];
    const float* nfb  = (const float*)d_in[14];
    const float* cw1  = (const float*)d_in[15];
    const float* cb1  = (const float*)d_in[16];
    const float* cw2  = (const float*)d_in[17];
    const float* cb2  = (const float*)d_in[18];
    const float* olnw = (const float*)d_in[19];
    const float* olnb = (const float*)d_in[20];
    float* out = (float*)d_out;

    // ---- workspace carve (floats), total 78.5 MB ----
    float* p = (float*)d_ws;
    float* resid  = p;  p += (size_t)M_ * DM_;        // 6.3 MB, live all launch
    float* xzb    = p;  p += (size_t)M_ * 2 * E_;     // 25.2 MB; + out_proj parts
    float* xcb    = p;  p += (size_t)M_ * E_;         // 12.6 MB; + x_bf/h1_bf at end
    float* dblb   = p;  p += (size_t)M_ * 80;         // 0.66 MB
    float* dtb    = p;  p += (size_t)M_ * E_;         // 12.6 MB; + hln_bf/xpart/mixed
    float* hs     = p;  p += (size_t)M_ * DM_;        // 6.3 MB; + hstart
    float* region = p;  p += (size_t)2 * B_ * E_ * N_ * NC_; // 6.3 MB: wbuf/sumA/sumH
    __bf16* y_bf  = (__bf16*)p; p += (size_t)M_ * E_ / 2;    // 6.3 MB
    __bf16* cw1b  = (__bf16*)p; p += (size_t)DM_ * DM_ / 2;  // 1.2 MB
    __bf16* cw2b  = (__bf16*)p; p += (size_t)DM_ * DM_ / 2;  // 1.2 MB
    float* gate   = out + (size_t)M_ * DM_;

    // overlays (timing-safe, see per-step comments)
    __bf16* wbuf   = (__bf16*)region;                 // weight slice (in/out proj)
    float*  sumA   = region;                          // scan summaries (after in_proj)
    float*  sumH   = region + (size_t)B_ * E_ * N_ * NC_;
    float*  hstart = hs;                              // hs dead during scan
    __bf16* hln_bf = (__bf16*)dtb;                    // dead before dt GEMM writes dtb
    float*  xpart  = dtb;                             // dead before dt GEMM writes dtb
    float*  mixedf = dtb;                             // final phase only
    __bf16* x_bf   = (__bf16*)xcb;                    // final phase only
    __bf16* h1_bf  = (__bf16*)(xcb + (size_t)M_ * DM_);
    float*  part01 = xzb;                             // out_proj split-K partials

    // one-time weight conversions for the control MLP
    cvt_cw1_kernel<<<(DM_ * DM_) / 256, 256, 0, stream>>>(cw1, cw1b);
    cvt_bf16_kernel<<<(DM_ * DM_ / 8 + 255) / 256, 256, 0, stream>>>(
        cw2, cw2b, DM_ * DM_ / 8);

    for (int i = 0; i < NL_; ++i) {
        // resid (+)= src ; hln_bf = LN(resid) [bf16]   (hln_bf on dtb: prev dt dead)
        add_ln_kernel<<<M_, 256, 0, stream>>>(i == 0 ? x : hs, resid,
                                              lnw + i * DM_, lnb + i * DM_,
                                              nullptr, hln_bf, i > 0 ? 1 : 0);
        // in_proj weights -> bf16 (region as wbuf)
        cvt_bf16_kernel<<<(2 * E_ * DM_ / 8) / 256, 256, 0, stream>>>(
            inw + (size_t)i * 2 * E_ * DM_, wbuf, 2 * E_ * DM_ / 8);
        // xz = hln @ in_proj^T : 2048 x 3072, K=768
        gemm_bf16<128><<<dim3(2 * E_ / 128, M_ / 128, 1), 256, 0, stream>>>(
            hln_bf, DM_, wbuf, DM_, xzb, 2 * E_, DM_, 0,
            nullptr, 0, nullptr, nullptr, 0);
        conv_silu_kernel<<<(M_ * E_) / 256, 256, 0, stream>>>(
            xzb, cw + (size_t)i * E_ * K_, cb + (size_t)i * E_, xcb);
        // dbl = xc @ x_proj^T (split-K partials on dtb; hln_bf dead)
        xproj_mfma<<<dim3(SK_, M_ / 128), 256, 0, stream>>>(
            xcb, xpw + (size_t)i * 80 * E_, xpart);
        xproj_reduce<<<(M_ * 80) / 256, 256, 0, stream>>>(xpart, dblb);
        // dt = softplus(dbl[:,:48] @ dt_proj^T + b)  (writes dtb; xpart dead)
        gemm_mfma<64><<<dim3(E_ / 64, M_ / 128), 256, 0, stream>>>(
            dblb, 80, dpw + (size_t)i * E_ * R_, R_, 1,
            dtb, E_, R_, dpb + (size_t)i * E_, 3, nullptr, nullptr, 0);
        // scan: summaries (region; wbuf dead) -> combine (hstart on hs) -> emit
        scan_part1<<<(B_ * E_ * NC_) / 16, 256, 0, stream>>>(
            xcb, dtb, dblb, alog + (size_t)i * E_ * N_, sumA, sumH);
        scan_part2<<<(B_ * E_ * N_ + 255) / 256, 256, 0, stream>>>(
            sumA, sumH, hstart);
        // out_proj weights -> bf16 (region; sumA/sumH dead after part2)
        cvt_bf16_kernel<<<(DM_ * E_ / 8) / 256, 256, 0, stream>>>(
            opw + (size_t)i * DM_ * E_, wbuf, DM_ * E_ / 8);
        scan_part3<<<(B_ * E_ * NC_) / 16, 256, 0, stream>>>(
            xcb, dtb, dblb, xzb, alog + (size_t)i * E_ * N_, sD + (size_t)i * E_,
            hstart, y_bf);
        // hs = y @ out_proj^T : split-K=2 partials on xzb (xz dead after part3)
        gemm_bf16<64><<<dim3(DM_ / 64, M_ / 128, 2), 256, 0, stream>>>(
            y_bf, E_, wbuf, E_, part01, DM_, E_ / 2, 0,
            nullptr, 0, nullptr, nullptr, 0);
        reduce2_kernel<<<(M_ * DM_) / 256, 256, 0, stream>>>(part01, hs);
    }

    // resid += hs ; mixed = LN(resid, normf) -> f32 on dtb (dt dead)
    add_ln_kernel<<<M_, 256, 0, stream>>>(hs, resid, nfw, nfb,
                                          mixedf, nullptr, 1);
    // x -> bf16 (xcb dead after last scan)
    cvt_bf16_kernel<<<(M_ * DM_ / 8) / 256, 256, 0, stream>>>(
        x, x_bf, M_ * DM_ / 8);
    // h1 = silu(x @ ctrl_w1[:,:768]^T + bp ⊗ ctrl_w1[:,768] + b1) -> bf16
    gemm_bf16<64><<<dim3(DM_ / 64, M_ / 128, 1), 256, 0, stream>>>(
        x_bf, DM_, cw1b, DM_, h1_bf, DM_, DM_, 1,
        cb1, 1, bp, cw1 + DM_, DM_ + 1);
    // gate = sigmoid(h1 @ ctrl_w2^T + b2) -> d_out[BLD:]
    gemm_bf16<64><<<dim3(DM_ / 64, M_ / 128, 1), 256, 0, stream>>>(
        h1_bf, DM_, cw2b, DM_, gate, DM_, DM_, 0,
        cb2, 2, nullptr, nullptr, 0);
    // out = x + gate*(mixed-x); d_out[:BLD] = LN(out)
    final_out_kernel<<<M_, 256, 0, stream>>>(x, gate, mixedf, olnw, olnb, out);
}

// Round 6
// 858.687 us; speedup vs baseline: 6.2893x; 1.2567x over previous
//
#include <hip/hip_runtime.h>
#include <math.h>

// Problem constants
static constexpr int B_  = 2;
static constexpr int L_  = 1024;
static constexpr int DM_ = 768;
static constexpr int NL_ = 4;
static constexpr int E_  = 2 * DM_;     // 1536
static constexpr int N_  = 16;
static constexpr int K_  = 4;
static constexpr int R_  = DM_ / 16;    // 48
static constexpr int M_  = B_ * L_;     // 2048 tokens
static constexpr int NC_ = 32;          // scan chunks per sequence
static constexpr int T_  = L_ / NC_;    // 32 steps per chunk
static constexpr int SK_ = 8;           // split-K slices for x_proj
static constexpr int KS_ = E_ / SK_;    // 192 per slice

typedef __bf16 bf16x8 __attribute__((ext_vector_type(8)));
typedef short short8  __attribute__((ext_vector_type(8)));
typedef float f32x4   __attribute__((ext_vector_type(4)));

// ---------------------------------------------------------------------------
__device__ __forceinline__ short f2bf(float x) {
    __bf16 h = (__bf16)x;
    return __builtin_bit_cast(short, h);
}
__device__ __forceinline__ void st8(short* p, float4 x, float4 y) {
    short8 s;
    s[0] = f2bf(x.x); s[1] = f2bf(x.y); s[2] = f2bf(x.z); s[3] = f2bf(x.w);
    s[4] = f2bf(y.x); s[5] = f2bf(y.y); s[6] = f2bf(y.z); s[7] = f2bf(y.w);
    *(short8*)p = s;
}

// async global->LDS, 16 bytes per lane.  LDS dest is wave-uniform base +
// lane*16 (hardware rule); global src is per-lane.
__device__ __forceinline__ void gload16(const void* g, void* l) {
    __builtin_amdgcn_global_load_lds(
        (const __attribute__((address_space(1))) unsigned int*)g,
        (__attribute__((address_space(3))) unsigned int*)l,
        16, 0, 0);
}

// ---------------------------------------------------------------------------
// bf16-input MFMA GEMM, m97 structure: global_load_lds(16B) staging into
// linear LDS [rows][32] bf16, 2 barriers per K-step, 16x16x32 MFMA.
// BM=128; BN in {128, 64}.  4 waves, wave tile 64 x BN/2.
// Split-K via blockIdx.z: slice z uses A+z*Kd, W+z*Kd, writes C+z*M*ldc.
// act: 0=none 1=silu 2=sigmoid.  out_bf16: write __bf16 instead of float.
// ---------------------------------------------------------------------------
template<int BN>
__global__ __launch_bounds__(256) void gemm_bf16(
    const __bf16* __restrict__ A, int lda,
    const __bf16* __restrict__ W, int ldw,
    void* __restrict__ Cout, int ldc, int Kd, int out_bf16,
    const float* __restrict__ bias, int act,
    const float* __restrict__ u, const float* __restrict__ v, int vstride)
{
    constexpr int BM = 128;
    constexpr int WN = BN / 2;
    constexpr int FM = 4;
    constexpr int FN = WN / 16;

    __shared__ __bf16 As[BM * 32];
    __shared__ __bf16 Bs[BN * 32];

    const int tid  = threadIdx.x;
    const int lane = tid & 63;
    const int wave = tid >> 6;
    const int wr = wave >> 1, wc = wave & 1;
    const int bm = blockIdx.y * BM;
    const int bn = blockIdx.x * BN;
    const int sk = blockIdx.z;

    A += (size_t)sk * Kd;
    W += (size_t)sk * Kd;
    const size_t cz = (size_t)sk * (size_t)gridDim.y * BM * ldc;

    const int sr = tid >> 2;
    const int sc = (tid & 3) << 3;
    const __bf16* ag0 = A + (size_t)(bm + sr) * lda + sc;
    const __bf16* ag1 = A + (size_t)(bm + 64 + sr) * lda + sc;
    const __bf16* wg0 = W + (size_t)(bn + sr) * ldw + sc;
    const __bf16* wg1 = W + (size_t)(bn + 64 + sr) * ldw + sc;  // BN=128 only

    __bf16* lA0 = As + wave * 512;
    __bf16* lA1 = As + 2048 + wave * 512;
    __bf16* lB0 = Bs + wave * 512;
    __bf16* lB1 = Bs + 2048 + wave * 512;

    f32x4 acc[FM][FN];
#pragma unroll
    for (int i = 0; i < FM; ++i)
#pragma unroll
        for (int j = 0; j < FN; ++j)
            acc[i][j] = (f32x4){0.f, 0.f, 0.f, 0.f};

    const __bf16* ard = As + (wr * 64 + (lane & 15)) * 32 + ((lane >> 4) << 3);
    const __bf16* brd = Bs + (wc * WN + (lane & 15)) * 32 + ((lane >> 4) << 3);

    const int NT = Kd / 32;
    for (int t = 0; t < NT; ++t) {
        const int k0 = t * 32;
        __syncthreads();
        gload16(ag0 + k0, lA0);
        gload16(ag1 + k0, lA1);
        gload16(wg0 + k0, lB0);
        if constexpr (BN == 128) gload16(wg1 + k0, lB1);
        __syncthreads();
        bf16x8 af[FM], bf[FN];
#pragma unroll
        for (int m = 0; m < FM; ++m)
            af[m] = *(const bf16x8*)(ard + m * 512);
#pragma unroll
        for (int n = 0; n < FN; ++n)
            bf[n] = *(const bf16x8*)(brd + n * 512);
#pragma unroll
        for (int m = 0; m < FM; ++m)
#pragma unroll
            for (int n = 0; n < FN; ++n)
                acc[m][n] = __builtin_amdgcn_mfma_f32_16x16x32_bf16(
                    af[m], bf[n], acc[m][n], 0, 0, 0);
    }

#pragma unroll
    for (int m = 0; m < FM; ++m) {
        const int row0 = bm + wr * 64 + m * 16 + ((lane >> 4) << 2);
#pragma unroll
        for (int n = 0; n < FN; ++n) {
            const int col = bn + wc * WN + n * 16 + (lane & 15);
            const float bia = bias ? bias[col] : 0.f;
            const float vv = u ? v[(size_t)col * vstride] : 0.f;
#pragma unroll
            for (int r = 0; r < 4; ++r) {
                float val = acc[m][n][r] + bia;
                if (u) val += u[row0 + r] * vv;
                if (act == 1)      val = val / (1.f + __expf(-val));
                else if (act == 2) val = 1.f / (1.f + __expf(-val));
                size_t off = cz + (size_t)(row0 + r) * ldc + col;
                if (out_bf16) ((__bf16*)Cout)[off] = (__bf16)val;
                else          ((float*)Cout)[off]  = val;
            }
        }
    }
}

// ---------------------------------------------------------------------------
__global__ __launch_bounds__(256) void cvt_bf16_kernel(
    const float* __restrict__ src, __bf16* __restrict__ dst, int n8)
{
    int i = blockIdx.x * 256 + threadIdx.x;
    if (i >= n8) return;
    const float4* s = (const float4*)src;
    st8((short*)(dst + (size_t)i * 8), s[2 * i], s[2 * i + 1]);
}

// ctrl_w1 [768][769] -> bf16 [768][768] (drop last column)
__global__ __launch_bounds__(256) void cvt_cw1_kernel(
    const float* __restrict__ src, __bf16* __restrict__ dst)
{
    int idx = blockIdx.x * 256 + threadIdx.x;
    if (idx >= DM_ * DM_) return;
    int r = idx / DM_, c = idx % DM_;
    dst[idx] = (__bf16)src[(size_t)r * (DM_ + 1) + c];
}

__global__ __launch_bounds__(256) void reduce2_kernel(
    const float* __restrict__ p, float* __restrict__ out)
{
    int idx = blockIdx.x * 256 + threadIdx.x;   // over M_*DM_
    out[idx] = p[idx] + p[(size_t)M_ * DM_ + idx];
}

// ---------------------------------------------------------------------------
// reg-staged f32->bf16 MFMA GEMM (kept for dt_proj: K=48)
// ---------------------------------------------------------------------------
template<int BN>
__global__ __launch_bounds__(256) void gemm_mfma(
    const float* __restrict__ A, int lda,
    const float* __restrict__ W, int ldw, int walign,
    float* __restrict__ C, int ldc, int Kd,
    const float* __restrict__ bias, int act,
    const float* __restrict__ u, const float* __restrict__ v, int vstride)
{
    constexpr int BM = 128;
    constexpr int SA = 40;
    constexpr int WN = BN / 2;
    constexpr int FM = 4;
    constexpr int FN = WN / 16;
    constexpr int BRT = 256 / BN;
    constexpr int NB4 = 32 / BRT / 4;

    __shared__ short As[BM * SA];
    __shared__ short Bs[BN * SA];

    const int tid  = threadIdx.x;
    const int lane = tid & 63;
    const int wave = tid >> 6;
    const int wr = wave >> 1, wc = wave & 1;
    const int bm = blockIdx.y * BM;
    const int bn = blockIdx.x * BN;

    const int ar = tid >> 1;
    const int ac = (tid & 1) << 4;
    const float* aptr = A + (size_t)(bm + ar) * lda + ac;
    short* awr = &As[ar * SA + ac];

    const int br = tid / BRT;
    const int bc = (tid % BRT) * (32 / BRT);
    const float* wptr = W + (size_t)(bn + br) * ldw + bc;
    short* bwr = &Bs[br * SA + bc];

    f32x4 acc[FM][FN];
#pragma unroll
    for (int i = 0; i < FM; ++i)
#pragma unroll
        for (int j = 0; j < FN; ++j)
            acc[i][j] = (f32x4){0.f, 0.f, 0.f, 0.f};

    const short* ard = &As[(wr * 64 + (lane & 15)) * SA + ((lane >> 4) << 3)];
    const short* brd = &Bs[(wc * WN + (lane & 15)) * SA + ((lane >> 4) << 3)];

    float4 aR[4], bR[NB4];
    auto loadA = [&](int k0) {
        if (k0 + ac < Kd) {
#pragma unroll
            for (int i = 0; i < 4; ++i)
                aR[i] = *(const float4*)(aptr + k0 + i * 4);
        } else {
#pragma unroll
            for (int i = 0; i < 4; ++i) aR[i] = {0.f, 0.f, 0.f, 0.f};
        }
    };
    auto loadW = [&](int k0) {
        const float* p = wptr + k0;
        if (k0 + bc < Kd) {
            if (walign) {
#pragma unroll
                for (int i = 0; i < NB4; ++i)
                    bR[i] = *(const float4*)(p + i * 4);
            } else {
#pragma unroll
                for (int i = 0; i < NB4; ++i) {
                    bR[i].x = p[i * 4 + 0]; bR[i].y = p[i * 4 + 1];
                    bR[i].z = p[i * 4 + 2]; bR[i].w = p[i * 4 + 3];
                }
            }
        } else {
#pragma unroll
            for (int i = 0; i < NB4; ++i) bR[i] = {0.f, 0.f, 0.f, 0.f};
        }
    };

    const int NT = (Kd + 31) / 32;
    loadA(0); loadW(0);

    for (int t = 0; t < NT; ++t) {
        __syncthreads();
        st8(awr, aR[0], aR[1]);
        st8(awr + 8, aR[2], aR[3]);
        st8(bwr, bR[0], bR[1]);
        if constexpr (NB4 == 4) st8(bwr + 8, bR[2], bR[3]);
        __syncthreads();
        if (t + 1 < NT) { loadA((t + 1) * 32); loadW((t + 1) * 32); }
        bf16x8 af[FM], bf[FN];
#pragma unroll
        for (int m = 0; m < FM; ++m)
            af[m] = *(const bf16x8*)(ard + m * 16 * SA);
#pragma unroll
        for (int n = 0; n < FN; ++n)
            bf[n] = *(const bf16x8*)(brd + n * 16 * SA);
#pragma unroll
        for (int m = 0; m < FM; ++m)
#pragma unroll
            for (int n = 0; n < FN; ++n)
                acc[m][n] = __builtin_amdgcn_mfma_f32_16x16x32_bf16(
                    af[m], bf[n], acc[m][n], 0, 0, 0);
    }

#pragma unroll
    for (int m = 0; m < FM; ++m) {
        const int row0 = bm + wr * 64 + m * 16 + ((lane >> 4) << 2);
#pragma unroll
        for (int n = 0; n < FN; ++n) {
            const int col = bn + wc * WN + n * 16 + (lane & 15);
            const float bia = bias ? bias[col] : 0.f;
            const float vv = u ? v[(size_t)col * vstride] : 0.f;
#pragma unroll
            for (int r = 0; r < 4; ++r) {
                float val = acc[m][n][r] + bia;
                if (u) val += u[row0 + r] * vv;
                if (act == 1)      val = val / (1.f + __expf(-val));
                else if (act == 2) val = 1.f / (1.f + __expf(-val));
                else if (act == 3) val = (val > 20.f) ? val : log1pf(__expf(val));
                C[(size_t)(row0 + r) * ldc + col] = val;
            }
        }
    }
}

// ---------------------------------------------------------------------------
// x_proj split-K MFMA (reg-staged f32)
// ---------------------------------------------------------------------------
__global__ __launch_bounds__(256) void xproj_mfma(
    const float* __restrict__ A, const float* __restrict__ W,
    float* __restrict__ part)
{
    constexpr int SA = 40;
    __shared__ short As[128 * SA];
    __shared__ short Ws[80 * SA];

    const int tid  = threadIdx.x;
    const int lane = tid & 63;
    const int wave = tid >> 6;
    const int sk = blockIdx.x;
    const int bm = blockIdx.y * 128;
    const int kbase = sk * KS_;

    const int ar = tid >> 1;
    const int ac = (tid & 1) << 4;
    const float* aptr = A + (size_t)(bm + ar) * E_ + kbase + ac;
    short* awr = &As[ar * SA + ac];

    const bool wact = tid < 160;
    const int wrow = tid >> 1;
    const float* wptr = W + (size_t)wrow * E_ + kbase + ac;
    short* wwr = &Ws[wrow * SA + ac];

    f32x4 acc[2][5];
#pragma unroll
    for (int i = 0; i < 2; ++i)
#pragma unroll
        for (int j = 0; j < 5; ++j)
            acc[i][j] = (f32x4){0.f, 0.f, 0.f, 0.f};

    const short* ard = &As[(wave * 32 + (lane & 15)) * SA + ((lane >> 4) << 3)];
    const short* brd = &Ws[(lane & 15) * SA + ((lane >> 4) << 3)];

    float4 aR[4], wR[4];
    auto loadT = [&](int k0) {
#pragma unroll
        for (int i = 0; i < 4; ++i)
            aR[i] = *(const float4*)(aptr + k0 + i * 4);
        if (wact) {
#pragma unroll
            for (int i = 0; i < 4; ++i)
                wR[i] = *(const float4*)(wptr + k0 + i * 4);
        }
    };

    constexpr int NT = KS_ / 32;
    loadT(0);
    for (int t = 0; t < NT; ++t) {
        __syncthreads();
        st8(awr, aR[0], aR[1]);
        st8(awr + 8, aR[2], aR[3]);
        if (wact) {
            st8(wwr, wR[0], wR[1]);
            st8(wwr + 8, wR[2], wR[3]);
        }
        __syncthreads();
        if (t + 1 < NT) loadT((t + 1) * 32);
        bf16x8 af[2], bf[5];
#pragma unroll
        for (int m = 0; m < 2; ++m)
            af[m] = *(const bf16x8*)(ard + m * 16 * SA);
#pragma unroll
        for (int n = 0; n < 5; ++n)
            bf[n] = *(const bf16x8*)(brd + n * 16 * SA);
#pragma unroll
        for (int m = 0; m < 2; ++m)
#pragma unroll
            for (int n = 0; n < 5; ++n)
                acc[m][n] = __builtin_amdgcn_mfma_f32_16x16x32_bf16(
                    af[m], bf[n], acc[m][n], 0, 0, 0);
    }

    float* pout = part + (size_t)sk * M_ * 80;
#pragma unroll
    for (int m = 0; m < 2; ++m) {
        const int row0 = bm + wave * 32 + m * 16 + ((lane >> 4) << 2);
#pragma unroll
        for (int n = 0; n < 5; ++n) {
            const int col = n * 16 + (lane & 15);
#pragma unroll
            for (int r = 0; r < 4; ++r)
                pout[(size_t)(row0 + r) * 80 + col] = acc[m][n][r];
        }
    }
}

__global__ __launch_bounds__(256) void xproj_reduce(
    const float* __restrict__ part, float* __restrict__ dbl)
{
    int idx = blockIdx.x * 256 + threadIdx.x;
    float s = 0.f;
#pragma unroll
    for (int k = 0; k < SK_; ++k) s += part[(size_t)k * M_ * 80 + idx];
    dbl[idx] = s;
}

// ---------------------------------------------------------------------------
__device__ __forceinline__ float block_sum(float val, float* sm) {
#pragma unroll
    for (int o = 32; o > 0; o >>= 1) val += __shfl_down(val, o);
    int lane = threadIdx.x & 63, wid = threadIdx.x >> 6;
    __syncthreads();
    if (lane == 0) sm[wid] = val;
    __syncthreads();
    return sm[0] + sm[1] + sm[2] + sm[3];
}

// ---------------------------------------------------------------------------
__global__ __launch_bounds__(256) void add_ln_kernel(
    const float* __restrict__ src, float* __restrict__ resid,
    const float* __restrict__ w, const float* __restrict__ b,
    float* __restrict__ outf, __bf16* __restrict__ outb, int do_add)
{
    constexpr int D = DM_;
    const int row = blockIdx.x;
    const int tid = threadIdx.x;
    __shared__ float sm[4];
    const float* sp = src + (size_t)row * D;
    float* rp = resid + (size_t)row * D;

    float v[3];
    float s = 0.f;
#pragma unroll
    for (int j = 0; j < 3; ++j) {
        int d = j * 256 + tid;
        float vv = sp[d];
        if (do_add) vv += rp[d];
        rp[d] = vv;
        v[j] = vv;
        s += vv;
    }
    float mean = block_sum(s, sm) * (1.f / D);
    float s2 = 0.f;
#pragma unroll
    for (int j = 0; j < 3; ++j) { float dlt = v[j] - mean; s2 += dlt * dlt; }
    float var = block_sum(s2, sm) * (1.f / D);
    float inv = rsqrtf(var + 1e-5f);
#pragma unroll
    for (int j = 0; j < 3; ++j) {
        int d = j * 256 + tid;
        float r = (v[j] - mean) * inv * w[d] + b[d];
        if (outf) outf[(size_t)row * D + d] = r;
        if (outb) outb[(size_t)row * D + d] = (__bf16)r;
    }
}

// ---------------------------------------------------------------------------
__global__ __launch_bounds__(256) void conv_silu_kernel(
    const float* __restrict__ xz, const float* __restrict__ cw,
    const float* __restrict__ cb, float* __restrict__ xc)
{
    int idx = blockIdx.x * 256 + threadIdx.x;
    if (idx >= M_ * E_) return;
    int e = idx % E_;
    int m = idx / E_;
    int l = m % L_;
    float acc = cb[e];
    const float w0 = cw[e * 4 + 0], w1 = cw[e * 4 + 1],
                w2 = cw[e * 4 + 2], w3 = cw[e * 4 + 3];
    const float* base = xz + (size_t)m * (2 * E_) + e;
    if (l >= 3) acc += base[-3 * 2 * E_] * w0;
    if (l >= 2) acc += base[-2 * 2 * E_] * w1;
    if (l >= 1) acc += base[-1 * 2 * E_] * w2;
    acc += base[0] * w3;
    xc[idx] = acc / (1.f + __expf(-acc));
}

// ---------------------------------------------------------------------------
// Register-state chunked scan.  One thread per (channel, chunk); all N=16
// states live in VGPRs.  B/C rows of dbl are wave-uniform (same m for the
// whole wave) -> broadcast float4 loads.  dt/xc/z/y accesses are coalesced
// (consecutive threads = consecutive e).
// Summary layout: [chunk][n][c]  (c = b*E+e) so every access is c-coalesced.
// Phase 1: per-chunk h (from 0) + decay product exp(Av * sum dt).
// ---------------------------------------------------------------------------
__global__ __launch_bounds__(256) void scan_part1(
    const float* __restrict__ xc, const float* __restrict__ dt,
    const float* __restrict__ dbl, const float* __restrict__ A_log,
    float* __restrict__ sumA, float* __restrict__ sumH)
{
    const int gid = blockIdx.x * 256 + threadIdx.x;   // over NC_*B_*E_
    const int c = gid % (B_ * E_);
    const int chunk = gid / (B_ * E_);
    const int b = c / E_;
    const int e = c % E_;

    float Av[N_];
#pragma unroll
    for (int n = 0; n < N_; ++n) Av[n] = -__expf(A_log[e * N_ + n]);

    float h[N_];
#pragma unroll
    for (int n = 0; n < N_; ++n) h[n] = 0.f;
    float dts = 0.f;

    const size_t m0 = (size_t)b * L_ + (size_t)chunk * T_;
    for (int l = 0; l < T_; ++l) {
        size_t m = m0 + l;
        float dtv = dt[m * E_ + e];
        float xv  = xc[m * E_ + e];
        float dtx = dtv * xv;
        const float4* Bp = (const float4*)(dbl + m * 80 + R_);
        float4 B0 = Bp[0], B1 = Bp[1], B2 = Bp[2], B3 = Bp[3];
        float Bv[N_] = {B0.x, B0.y, B0.z, B0.w, B1.x, B1.y, B1.z, B1.w,
                        B2.x, B2.y, B2.z, B2.w, B3.x, B3.y, B3.z, B3.w};
        dts += dtv;
#pragma unroll
        for (int n = 0; n < N_; ++n) {
            float dA = __expf(dtv * Av[n]);
            h[n] = dA * h[n] + dtx * Bv[n];
        }
    }
    const size_t base = (size_t)chunk * N_ * (B_ * E_) + c;
#pragma unroll
    for (int n = 0; n < N_; ++n) {
        sumA[base + (size_t)n * (B_ * E_)] = __expf(Av[n] * dts);
        sumH[base + (size_t)n * (B_ * E_)] = h[n];
    }
}

// Phase 2: sequential combine across chunks; writes hstart IN PLACE over sumH.
__global__ __launch_bounds__(256) void scan_part2(
    const float* __restrict__ sumA, float* __restrict__ sumH)
{
    const int idx = blockIdx.x * 256 + threadIdx.x;   // n*(B*E) + c
    if (idx >= B_ * E_ * N_) return;
    float h = 0.f;
    for (int j = 0; j < NC_; ++j) {
        size_t o = (size_t)j * N_ * (B_ * E_) + idx;
        float a  = sumA[o];
        float hh = sumH[o];
        sumH[o] = h;                      // hstart for chunk j
        h = a * h + hh;
    }
}

// Phase 3: recompute chunk from hstart, emit y = (h·C + xc*D) * silu(z).
__global__ __launch_bounds__(256) void scan_part3(
    const float* __restrict__ xc, const float* __restrict__ dt,
    const float* __restrict__ dbl, const float* __restrict__ xz,
    const float* __restrict__ A_log, const float* __restrict__ ssm_D,
    const float* __restrict__ hstart, __bf16* __restrict__ y)
{
    const int gid = blockIdx.x * 256 + threadIdx.x;   // over NC_*B_*E_
    const int c = gid % (B_ * E_);
    const int chunk = gid / (B_ * E_);
    const int b = c / E_;
    const int e = c % E_;

    float Av[N_];
#pragma unroll
    for (int n = 0; n < N_; ++n) Av[n] = -__expf(A_log[e * N_ + n]);
    const float Dv = ssm_D[e];

    float h[N_];
    const size_t hb = (size_t)chunk * N_ * (B_ * E_) + c;
#pragma unroll
    for (int n = 0; n < N_; ++n) h[n] = hstart[hb + (size_t)n * (B_ * E_)];

    const size_t m0 = (size_t)b * L_ + (size_t)chunk * T_;
    for (int l = 0; l < T_; ++l) {
        size_t m = m0 + l;
        float dtv = dt[m * E_ + e];
        float xv  = xc[m * E_ + e];
        float dtx = dtv * xv;
        const float4* Bp = (const float4*)(dbl + m * 80 + R_);
        float4 B0 = Bp[0], B1 = Bp[1], B2 = Bp[2], B3 = Bp[3];
        float4 C0 = Bp[4], C1 = Bp[5], C2 = Bp[6], C3 = Bp[7];
        float Bv[N_] = {B0.x, B0.y, B0.z, B0.w, B1.x, B1.y, B1.z, B1.w,
                        B2.x, B2.y, B2.z, B2.w, B3.x, B3.y, B3.z, B3.w};
        float Cv[N_] = {C0.x, C0.y, C0.z, C0.w, C1.x, C1.y, C1.z, C1.w,
                        C2.x, C2.y, C2.z, C2.w, C3.x, C3.y, C3.z, C3.w};
        float p = 0.f;
#pragma unroll
        for (int n = 0; n < N_; ++n) {
            float dA = __expf(dtv * Av[n]);
            h[n] = dA * h[n] + dtx * Bv[n];
            p += h[n] * Cv[n];
        }
        float zv = xz[m * (2 * E_) + E_ + e];
        float yv = (p + xv * Dv) * (zv / (1.f + __expf(-zv)));
        y[m * E_ + e] = (__bf16)yv;
    }
}

// ---------------------------------------------------------------------------
__global__ __launch_bounds__(256) void final_out_kernel(
    const float* __restrict__ x, const float* __restrict__ gate,
    const float* __restrict__ mixed, const float* __restrict__ w,
    const float* __restrict__ b, float* __restrict__ outp)
{
    constexpr int D = DM_;
    const int row = blockIdx.x;
    const int tid = threadIdx.x;
    __shared__ float sm[4];
    const float* xp = x + (size_t)row * D;
    const float* gp = gate + (size_t)row * D;
    const float* mp = mixed + (size_t)row * D;

    float v[3];
    float s = 0.f;
#pragma unroll
    for (int j = 0; j < 3; ++j) {
        int d = j * 256 + tid;
        float xv = xp[d];
        float o = xv + gp[d] * (mp[d] - xv);
        v[j] = o;
        s += o;
    }
    float mean = block_sum(s, sm) * (1.f / D);
    float s2 = 0.f;
#pragma unroll
    for (int j = 0; j < 3; ++j) { float dlt = v[j] - mean; s2 += dlt * dlt; }
    float var = block_sum(s2, sm) * (1.f / D);
    float inv = rsqrtf(var + 1e-5f);
    float* op = outp + (size_t)row * D;
#pragma unroll
    for (int j = 0; j < 3; ++j) {
        int d = j * 256 + tid;
        op[d] = (v[j] - mean) * inv * w[d] + b[d];
    }
}

// ---------------------------------------------------------------------------
extern "C" void kernel_launch(void* const* d_in, const int* in_sizes, int n_in,
                              void* d_out, int out_size, void* d_ws, size_t ws_size,
                              hipStream_t stream)
{
    const float* x    = (const float*)d_in[0];
    const float* bp   = (const float*)d_in[1];
    const float* inw  = (const float*)d_in[2];
    const float* cw   = (const float*)d_in[3];
    const float* cb   = (const float*)d_in[4];
    const float* xpw  = (const float*)d_in[5];
    const float* dpw  = (const float*)d_in[6];
    const float* dpb  = (const float*)d_in[7];
    const float* alog = (const float*)d_in[8];
    const float* sD   = (const float*)d_in[9];
    const float* opw  = (const float*)d_in[10];
    const float* lnw  = (const float*)d_in[11];
    const float* lnb  = (const float*)d_in[12];
    const float* nfw  = (const float*)d_in[13];
    const float* nfb  = (const float*)d_in[14];
    const float* cw1  = (const float*)d_in[15];
    const float* cb1  = (const float*)d_in[16];
    const float* cw2  = (const float*)d_in[17];
    const float* cb2  = (const float*)d_in[18];
    const float* olnw = (const float*)d_in[19];
    const float* olnb = (const float*)d_in[20];
    float* out = (float*)d_out;

    // ---- workspace carve (floats), total ~78.5 MB ----
    float* p = (float*)d_ws;
    float* resid  = p;  p += (size_t)M_ * DM_;        // 6.3 MB, live all launch
    float* xzb    = p;  p += (size_t)M_ * 2 * E_;     // 25.2 MB; + out_proj parts
    float* xcb    = p;  p += (size_t)M_ * E_;         // 12.6 MB; + x_bf/h1_bf at end
    float* dblb   = p;  p += (size_t)M_ * 80;         // 0.66 MB
    float* dtb    = p;  p += (size_t)M_ * E_;         // 12.6 MB; + hln_bf/xpart/mixed
    float* hs     = p;  p += (size_t)M_ * DM_;        // 6.3 MB; + sumH/hstart
    float* region = p;  p += (size_t)NC_ * N_ * B_ * E_;     // 6.3 MB: wbuf/sumA
    __bf16* y_bf  = (__bf16*)p; p += (size_t)M_ * E_ / 2;    // 6.3 MB
    __bf16* cw1b  = (__bf16*)p; p += (size_t)DM_ * DM_ / 2;  // 1.2 MB
    __bf16* cw2b  = (__bf16*)p; p += (size_t)DM_ * DM_ / 2;  // 1.2 MB
    float* gate   = out + (size_t)M_ * DM_;

    // overlays (timing-safe, see per-step comments)
    __bf16* wbuf   = (__bf16*)region;                 // weight slice (in/out proj)
    float*  sumA   = region;                          // NC*N*(B*E) fl = exact fit
    float*  sumHst = hs;                              // sumH, then hstart in place
    __bf16* hln_bf = (__bf16*)dtb;                    // dead before dt GEMM writes dtb
    float*  xpart  = dtb;                             // dead before dt GEMM writes dtb
    float*  mixedf = dtb;                             // final phase only
    __bf16* x_bf   = (__bf16*)xcb;                    // final phase only
    __bf16* h1_bf  = (__bf16*)(xcb + (size_t)M_ * DM_);
    float*  part01 = xzb;                             // out_proj split-K partials

    // one-time weight conversions for the control MLP
    cvt_cw1_kernel<<<(DM_ * DM_) / 256, 256, 0, stream>>>(cw1, cw1b);
    cvt_bf16_kernel<<<(DM_ * DM_ / 8 + 255) / 256, 256, 0, stream>>>(
        cw2, cw2b, DM_ * DM_ / 8);

    for (int i = 0; i < NL_; ++i) {
        // resid (+)= src ; hln_bf = LN(resid) [bf16]  (on dtb: prev dt dead)
        add_ln_kernel<<<M_, 256, 0, stream>>>(i == 0 ? x : hs, resid,
                                              lnw + i * DM_, lnb + i * DM_,
                                              nullptr, hln_bf, i > 0 ? 1 : 0);
        // in_proj weights -> bf16 (region as wbuf)
        cvt_bf16_kernel<<<(2 * E_ * DM_ / 8) / 256, 256, 0, stream>>>(
            inw + (size_t)i * 2 * E_ * DM_, wbuf, 2 * E_ * DM_ / 8);
        // xz = hln @ in_proj^T : 2048 x 3072, K=768
        gemm_bf16<128><<<dim3(2 * E_ / 128, M_ / 128, 1), 256, 0, stream>>>(
            hln_bf, DM_, wbuf, DM_, xzb, 2 * E_, DM_, 0,
            nullptr, 0, nullptr, nullptr, 0);
        conv_silu_kernel<<<(M_ * E_) / 256, 256, 0, stream>>>(
            xzb, cw + (size_t)i * E_ * K_, cb + (size_t)i * E_, xcb);
        // dbl = xc @ x_proj^T (split-K partials on dtb; hln_bf dead)
        xproj_mfma<<<dim3(SK_, M_ / 128), 256, 0, stream>>>(
            xcb, xpw + (size_t)i * 80 * E_, xpart);
        xproj_reduce<<<(M_ * 80) / 256, 256, 0, stream>>>(xpart, dblb);
        // dt = softplus(dbl[:,:48] @ dt_proj^T + b)  (writes dtb; xpart dead)
        gemm_mfma<64><<<dim3(E_ / 64, M_ / 128), 256, 0, stream>>>(
            dblb, 80, dpw + (size_t)i * E_ * R_, R_, 1,
            dtb, E_, R_, dpb + (size_t)i * E_, 3, nullptr, nullptr, 0);
        // scan: summaries (sumA on region — wbuf dead; sumH on hs) ->
        // combine in place -> emit
        scan_part1<<<(NC_ * B_ * E_) / 256, 256, 0, stream>>>(
            xcb, dtb, dblb, alog + (size_t)i * E_ * N_, sumA, sumHst);
        scan_part2<<<(B_ * E_ * N_) / 256, 256, 0, stream>>>(sumA, sumHst);
        // out_proj weights -> bf16 (region; sumA dead after part2)
        cvt_bf16_kernel<<<(DM_ * E_ / 8) / 256, 256, 0, stream>>>(
            opw + (size_t)i * DM_ * E_, wbuf, DM_ * E_ / 8);
        scan_part3<<<(NC_ * B_ * E_) / 256, 256, 0, stream>>>(
            xcb, dtb, dblb, xzb, alog + (size_t)i * E_ * N_, sD + (size_t)i * E_,
            sumHst, y_bf);
        // hs = y @ out_proj^T : split-K=2 partials on xzb (xz dead after part3)
        gemm_bf16<64><<<dim3(DM_ / 64, M_ / 128, 2), 256, 0, stream>>>(
            y_bf, E_, wbuf, E_, part01, DM_, E_ / 2, 0,
            nullptr, 0, nullptr, nullptr, 0);
        reduce2_kernel<<<(M_ * DM_) / 256, 256, 0, stream>>>(part01, hs);
    }

    // resid += hs ; mixed = LN(resid, normf) -> f32 on dtb (dt dead)
    add_ln_kernel<<<M_, 256, 0, stream>>>(hs, resid, nfw, nfb,
                                          mixedf, nullptr, 1);
    // x -> bf16 (xcb dead after last scan)
    cvt_bf16_kernel<<<(M_ * DM_ / 8) / 256, 256, 0, stream>>>(
        x, x_bf, M_ * DM_ / 8);
    // h1 = silu(x @ ctrl_w1[:,:768]^T + bp ⊗ ctrl_w1[:,768] + b1) -> bf16
    gemm_bf16<64><<<dim3(DM_ / 64, M_ / 128, 1), 256, 0, stream>>>(
        x_bf, DM_, cw1b, DM_, h1_bf, DM_, DM_, 1,
        cb1, 1, bp, cw1 + DM_, DM_ + 1);
    // gate = sigmoid(h1 @ ctrl_w2^T + b2) -> d_out[BLD:]
    gemm_bf16<64><<<dim3(DM_ / 64, M_ / 128, 1), 256, 0, stream>>>(
        h1_bf, DM_, cw2b, DM_, gate, DM_, DM_, 0,
        cb2, 2, nullptr, nullptr, 0);
    // out = x + gate*(mixed-x); d_out[:BLD] = LN(out)
    final_out_kernel<<<M_, 256, 0, stream>>>(x, gate, mixedf, olnw, olnb, out);
}

// Round 7
// 814.586 us; speedup vs baseline: 6.6298x; 1.0541x over previous
//
#include <hip/hip_runtime.h>
#include <math.h>

// Problem constants
static constexpr int B_  = 2;
static constexpr int L_  = 1024;
static constexpr int DM_ = 768;
static constexpr int NL_ = 4;
static constexpr int E_  = 2 * DM_;     // 1536
static constexpr int N_  = 16;
static constexpr int K_  = 4;
static constexpr int R_  = DM_ / 16;    // 48
static constexpr int M_  = B_ * L_;     // 2048 tokens
static constexpr int NC_ = 64;          // scan chunks per sequence
static constexpr int T_  = L_ / NC_;    // 16 steps per chunk
static constexpr int SK_ = 8;           // split-K slices for x_proj
static constexpr int KS_ = E_ / SK_;    // 192 per slice

typedef __bf16 bf16x8 __attribute__((ext_vector_type(8)));
typedef short short8  __attribute__((ext_vector_type(8)));
typedef float f32x4   __attribute__((ext_vector_type(4)));

// ---------------------------------------------------------------------------
__device__ __forceinline__ short f2bf(float x) {
    __bf16 h = (__bf16)x;
    return __builtin_bit_cast(short, h);
}
__device__ __forceinline__ void st8(short* p, float4 x, float4 y) {
    short8 s;
    s[0] = f2bf(x.x); s[1] = f2bf(x.y); s[2] = f2bf(x.z); s[3] = f2bf(x.w);
    s[4] = f2bf(y.x); s[5] = f2bf(y.y); s[6] = f2bf(y.z); s[7] = f2bf(y.w);
    *(short8*)p = s;
}

// async global->LDS, 16 bytes per lane.
__device__ __forceinline__ void gload16(const void* g, void* l) {
    __builtin_amdgcn_global_load_lds(
        (const __attribute__((address_space(1))) unsigned int*)g,
        (__attribute__((address_space(3))) unsigned int*)l,
        16, 0, 0);
}

// sumA slab addressing: slab s (= chunk*N+n) of 3072 floats lives in the dead
// xp-halves of xzb rows 2s and 2s+1:  addr = (2s + (c>=E))*2E + (c mod E).
__device__ __forceinline__ size_t sA_addr(int s, int c) {
    int half = (c >= E_) ? 1 : 0;
    int col  = c - half * E_;
    return (size_t)(2 * s + half) * (2 * E_) + col;
}

// ---------------------------------------------------------------------------
// bf16-input MFMA GEMM, m97 structure (global_load_lds 16B staging).
// ---------------------------------------------------------------------------
template<int BN>
__global__ __launch_bounds__(256) void gemm_bf16(
    const __bf16* __restrict__ A, int lda,
    const __bf16* __restrict__ W, int ldw,
    void* __restrict__ Cout, int ldc, int Kd, int out_bf16,
    const float* __restrict__ bias, int act,
    const float* __restrict__ u, const float* __restrict__ v, int vstride)
{
    constexpr int BM = 128;
    constexpr int WN = BN / 2;
    constexpr int FM = 4;
    constexpr int FN = WN / 16;

    __shared__ __bf16 As[BM * 32];
    __shared__ __bf16 Bs[BN * 32];

    const int tid  = threadIdx.x;
    const int lane = tid & 63;
    const int wave = tid >> 6;
    const int wr = wave >> 1, wc = wave & 1;
    const int bm = blockIdx.y * BM;
    const int bn = blockIdx.x * BN;
    const int sk = blockIdx.z;

    A += (size_t)sk * Kd;
    W += (size_t)sk * Kd;
    const size_t cz = (size_t)sk * (size_t)gridDim.y * BM * ldc;

    const int sr = tid >> 2;
    const int sc = (tid & 3) << 3;
    const __bf16* ag0 = A + (size_t)(bm + sr) * lda + sc;
    const __bf16* ag1 = A + (size_t)(bm + 64 + sr) * lda + sc;
    const __bf16* wg0 = W + (size_t)(bn + sr) * ldw + sc;
    const __bf16* wg1 = W + (size_t)(bn + 64 + sr) * ldw + sc;  // BN=128 only

    __bf16* lA0 = As + wave * 512;
    __bf16* lA1 = As + 2048 + wave * 512;
    __bf16* lB0 = Bs + wave * 512;
    __bf16* lB1 = Bs + 2048 + wave * 512;

    f32x4 acc[FM][FN];
#pragma unroll
    for (int i = 0; i < FM; ++i)
#pragma unroll
        for (int j = 0; j < FN; ++j)
            acc[i][j] = (f32x4){0.f, 0.f, 0.f, 0.f};

    const __bf16* ard = As + (wr * 64 + (lane & 15)) * 32 + ((lane >> 4) << 3);
    const __bf16* brd = Bs + (wc * WN + (lane & 15)) * 32 + ((lane >> 4) << 3);

    const int NT = Kd / 32;
    for (int t = 0; t < NT; ++t) {
        const int k0 = t * 32;
        __syncthreads();
        gload16(ag0 + k0, lA0);
        gload16(ag1 + k0, lA1);
        gload16(wg0 + k0, lB0);
        if constexpr (BN == 128) gload16(wg1 + k0, lB1);
        __syncthreads();
        bf16x8 af[FM], bf[FN];
#pragma unroll
        for (int m = 0; m < FM; ++m)
            af[m] = *(const bf16x8*)(ard + m * 512);
#pragma unroll
        for (int n = 0; n < FN; ++n)
            bf[n] = *(const bf16x8*)(brd + n * 512);
#pragma unroll
        for (int m = 0; m < FM; ++m)
#pragma unroll
            for (int n = 0; n < FN; ++n)
                acc[m][n] = __builtin_amdgcn_mfma_f32_16x16x32_bf16(
                    af[m], bf[n], acc[m][n], 0, 0, 0);
    }

#pragma unroll
    for (int m = 0; m < FM; ++m) {
        const int row0 = bm + wr * 64 + m * 16 + ((lane >> 4) << 2);
#pragma unroll
        for (int n = 0; n < FN; ++n) {
            const int col = bn + wc * WN + n * 16 + (lane & 15);
            const float bia = bias ? bias[col] : 0.f;
            const float vv = u ? v[(size_t)col * vstride] : 0.f;
#pragma unroll
            for (int r = 0; r < 4; ++r) {
                float val = acc[m][n][r] + bia;
                if (u) val += u[row0 + r] * vv;
                if (act == 1)      val = val / (1.f + __expf(-val));
                else if (act == 2) val = 1.f / (1.f + __expf(-val));
                size_t off = cz + (size_t)(row0 + r) * ldc + col;
                if (out_bf16) ((__bf16*)Cout)[off] = (__bf16)val;
                else          ((float*)Cout)[off]  = val;
            }
        }
    }
}

// ---------------------------------------------------------------------------
__global__ __launch_bounds__(256) void cvt_bf16_kernel(
    const float* __restrict__ src, __bf16* __restrict__ dst, int n8)
{
    int i = blockIdx.x * 256 + threadIdx.x;
    if (i >= n8) return;
    const float4* s = (const float4*)src;
    st8((short*)(dst + (size_t)i * 8), s[2 * i], s[2 * i + 1]);
}

// ctrl_w1 [768][769] -> bf16 [768][768] (drop last column)
__global__ __launch_bounds__(256) void cvt_cw1_kernel(
    const float* __restrict__ src, __bf16* __restrict__ dst)
{
    int idx = blockIdx.x * 256 + threadIdx.x;
    if (idx >= DM_ * DM_) return;
    int r = idx / DM_, c = idx % DM_;
    dst[idx] = (__bf16)src[(size_t)r * (DM_ + 1) + c];
}

__global__ __launch_bounds__(256) void reduce2_kernel(
    const float* __restrict__ p, float* __restrict__ out)
{
    int idx = blockIdx.x * 256 + threadIdx.x;   // over M_*DM_
    out[idx] = p[idx] + p[(size_t)M_ * DM_ + idx];
}

// ---------------------------------------------------------------------------
// reg-staged f32->bf16 MFMA GEMM (kept for dt_proj: K=48)
// ---------------------------------------------------------------------------
template<int BN>
__global__ __launch_bounds__(256) void gemm_mfma(
    const float* __restrict__ A, int lda,
    const float* __restrict__ W, int ldw, int walign,
    float* __restrict__ C, int ldc, int Kd,
    const float* __restrict__ bias, int act,
    const float* __restrict__ u, const float* __restrict__ v, int vstride)
{
    constexpr int BM = 128;
    constexpr int SA = 40;
    constexpr int WN = BN / 2;
    constexpr int FM = 4;
    constexpr int FN = WN / 16;
    constexpr int BRT = 256 / BN;
    constexpr int NB4 = 32 / BRT / 4;

    __shared__ short As[BM * SA];
    __shared__ short Bs[BN * SA];

    const int tid  = threadIdx.x;
    const int lane = tid & 63;
    const int wave = tid >> 6;
    const int wr = wave >> 1, wc = wave & 1;
    const int bm = blockIdx.y * BM;
    const int bn = blockIdx.x * BN;

    const int ar = tid >> 1;
    const int ac = (tid & 1) << 4;
    const float* aptr = A + (size_t)(bm + ar) * lda + ac;
    short* awr = &As[ar * SA + ac];

    const int br = tid / BRT;
    const int bc = (tid % BRT) * (32 / BRT);
    const float* wptr = W + (size_t)(bn + br) * ldw + bc;
    short* bwr = &Bs[br * SA + bc];

    f32x4 acc[FM][FN];
#pragma unroll
    for (int i = 0; i < FM; ++i)
#pragma unroll
        for (int j = 0; j < FN; ++j)
            acc[i][j] = (f32x4){0.f, 0.f, 0.f, 0.f};

    const short* ard = &As[(wr * 64 + (lane & 15)) * SA + ((lane >> 4) << 3)];
    const short* brd = &Bs[(wc * WN + (lane & 15)) * SA + ((lane >> 4) << 3)];

    float4 aR[4], bR[NB4];
    auto loadA = [&](int k0) {
        if (k0 + ac < Kd) {
#pragma unroll
            for (int i = 0; i < 4; ++i)
                aR[i] = *(const float4*)(aptr + k0 + i * 4);
        } else {
#pragma unroll
            for (int i = 0; i < 4; ++i) aR[i] = {0.f, 0.f, 0.f, 0.f};
        }
    };
    auto loadW = [&](int k0) {
        const float* p = wptr + k0;
        if (k0 + bc < Kd) {
            if (walign) {
#pragma unroll
                for (int i = 0; i < NB4; ++i)
                    bR[i] = *(const float4*)(p + i * 4);
            } else {
#pragma unroll
                for (int i = 0; i < NB4; ++i) {
                    bR[i].x = p[i * 4 + 0]; bR[i].y = p[i * 4 + 1];
                    bR[i].z = p[i * 4 + 2]; bR[i].w = p[i * 4 + 3];
                }
            }
        } else {
#pragma unroll
            for (int i = 0; i < NB4; ++i) bR[i] = {0.f, 0.f, 0.f, 0.f};
        }
    };

    const int NT = (Kd + 31) / 32;
    loadA(0); loadW(0);

    for (int t = 0; t < NT; ++t) {
        __syncthreads();
        st8(awr, aR[0], aR[1]);
        st8(awr + 8, aR[2], aR[3]);
        st8(bwr, bR[0], bR[1]);
        if constexpr (NB4 == 4) st8(bwr + 8, bR[2], bR[3]);
        __syncthreads();
        if (t + 1 < NT) { loadA((t + 1) * 32); loadW((t + 1) * 32); }
        bf16x8 af[FM], bf[FN];
#pragma unroll
        for (int m = 0; m < FM; ++m)
            af[m] = *(const bf16x8*)(ard + m * 16 * SA);
#pragma unroll
        for (int n = 0; n < FN; ++n)
            bf[n] = *(const bf16x8*)(brd + n * 16 * SA);
#pragma unroll
        for (int m = 0; m < FM; ++m)
#pragma unroll
            for (int n = 0; n < FN; ++n)
                acc[m][n] = __builtin_amdgcn_mfma_f32_16x16x32_bf16(
                    af[m], bf[n], acc[m][n], 0, 0, 0);
    }

#pragma unroll
    for (int m = 0; m < FM; ++m) {
        const int row0 = bm + wr * 64 + m * 16 + ((lane >> 4) << 2);
#pragma unroll
        for (int n = 0; n < FN; ++n) {
            const int col = bn + wc * WN + n * 16 + (lane & 15);
            const float bia = bias ? bias[col] : 0.f;
            const float vv = u ? v[(size_t)col * vstride] : 0.f;
#pragma unroll
            for (int r = 0; r < 4; ++r) {
                float val = acc[m][n][r] + bia;
                if (u) val += u[row0 + r] * vv;
                if (act == 1)      val = val / (1.f + __expf(-val));
                else if (act == 2) val = 1.f / (1.f + __expf(-val));
                else if (act == 3) val = (val > 20.f) ? val : log1pf(__expf(val));
                C[(size_t)(row0 + r) * ldc + col] = val;
            }
        }
    }
}

// ---------------------------------------------------------------------------
// x_proj split-K MFMA (reg-staged f32)
// ---------------------------------------------------------------------------
__global__ __launch_bounds__(256) void xproj_mfma(
    const float* __restrict__ A, const float* __restrict__ W,
    float* __restrict__ part)
{
    constexpr int SA = 40;
    __shared__ short As[128 * SA];
    __shared__ short Ws[80 * SA];

    const int tid  = threadIdx.x;
    const int lane = tid & 63;
    const int wave = tid >> 6;
    const int sk = blockIdx.x;
    const int bm = blockIdx.y * 128;
    const int kbase = sk * KS_;

    const int ar = tid >> 1;
    const int ac = (tid & 1) << 4;
    const float* aptr = A + (size_t)(bm + ar) * E_ + kbase + ac;
    short* awr = &As[ar * SA + ac];

    const bool wact = tid < 160;
    const int wrow = tid >> 1;
    const float* wptr = W + (size_t)wrow * E_ + kbase + ac;
    short* wwr = &Ws[wrow * SA + ac];

    f32x4 acc[2][5];
#pragma unroll
    for (int i = 0; i < 2; ++i)
#pragma unroll
        for (int j = 0; j < 5; ++j)
            acc[i][j] = (f32x4){0.f, 0.f, 0.f, 0.f};

    const short* ard = &As[(wave * 32 + (lane & 15)) * SA + ((lane >> 4) << 3)];
    const short* brd = &Ws[(lane & 15) * SA + ((lane >> 4) << 3)];

    float4 aR[4], wR[4];
    auto loadT = [&](int k0) {
#pragma unroll
        for (int i = 0; i < 4; ++i)
            aR[i] = *(const float4*)(aptr + k0 + i * 4);
        if (wact) {
#pragma unroll
            for (int i = 0; i < 4; ++i)
                wR[i] = *(const float4*)(wptr + k0 + i * 4);
        }
    };

    constexpr int NT = KS_ / 32;
    loadT(0);
    for (int t = 0; t < NT; ++t) {
        __syncthreads();
        st8(awr, aR[0], aR[1]);
        st8(awr + 8, aR[2], aR[3]);
        if (wact) {
            st8(wwr, wR[0], wR[1]);
            st8(wwr + 8, wR[2], wR[3]);
        }
        __syncthreads();
        if (t + 1 < NT) loadT((t + 1) * 32);
        bf16x8 af[2], bf[5];
#pragma unroll
        for (int m = 0; m < 2; ++m)
            af[m] = *(const bf16x8*)(ard + m * 16 * SA);
#pragma unroll
        for (int n = 0; n < 5; ++n)
            bf[n] = *(const bf16x8*)(brd + n * 16 * SA);
#pragma unroll
        for (int m = 0; m < 2; ++m)
#pragma unroll
            for (int n = 0; n < 5; ++n)
                acc[m][n] = __builtin_amdgcn_mfma_f32_16x16x32_bf16(
                    af[m], bf[n], acc[m][n], 0, 0, 0);
    }

    float* pout = part + (size_t)sk * M_ * 80;
#pragma unroll
    for (int m = 0; m < 2; ++m) {
        const int row0 = bm + wave * 32 + m * 16 + ((lane >> 4) << 2);
#pragma unroll
        for (int n = 0; n < 5; ++n) {
            const int col = n * 16 + (lane & 15);
#pragma unroll
            for (int r = 0; r < 4; ++r)
                pout[(size_t)(row0 + r) * 80 + col] = acc[m][n][r];
        }
    }
}

__global__ __launch_bounds__(256) void xproj_reduce(
    const float* __restrict__ part, float* __restrict__ dbl)
{
    int idx = blockIdx.x * 256 + threadIdx.x;
    float s = 0.f;
#pragma unroll
    for (int k = 0; k < SK_; ++k) s += part[(size_t)k * M_ * 80 + idx];
    dbl[idx] = s;
}

// ---------------------------------------------------------------------------
__device__ __forceinline__ float block_sum(float val, float* sm) {
#pragma unroll
    for (int o = 32; o > 0; o >>= 1) val += __shfl_down(val, o);
    int lane = threadIdx.x & 63, wid = threadIdx.x >> 6;
    __syncthreads();
    if (lane == 0) sm[wid] = val;
    __syncthreads();
    return sm[0] + sm[1] + sm[2] + sm[3];
}

// ---------------------------------------------------------------------------
__global__ __launch_bounds__(256) void add_ln_kernel(
    const float* __restrict__ src, float* __restrict__ resid,
    const float* __restrict__ w, const float* __restrict__ b,
    float* __restrict__ outf, __bf16* __restrict__ outb, int do_add)
{
    constexpr int D = DM_;
    const int row = blockIdx.x;
    const int tid = threadIdx.x;
    __shared__ float sm[4];
    const float* sp = src + (size_t)row * D;
    float* rp = resid + (size_t)row * D;

    float v[3];
    float s = 0.f;
#pragma unroll
    for (int j = 0; j < 3; ++j) {
        int d = j * 256 + tid;
        float vv = sp[d];
        if (do_add) vv += rp[d];
        rp[d] = vv;
        v[j] = vv;
        s += vv;
    }
    float mean = block_sum(s, sm) * (1.f / D);
    float s2 = 0.f;
#pragma unroll
    for (int j = 0; j < 3; ++j) { float dlt = v[j] - mean; s2 += dlt * dlt; }
    float var = block_sum(s2, sm) * (1.f / D);
    float inv = rsqrtf(var + 1e-5f);
#pragma unroll
    for (int j = 0; j < 3; ++j) {
        int d = j * 256 + tid;
        float r = (v[j] - mean) * inv * w[d] + b[d];
        if (outf) outf[(size_t)row * D + d] = r;
        if (outb) outb[(size_t)row * D + d] = (__bf16)r;
    }
}

// ---------------------------------------------------------------------------
__global__ __launch_bounds__(256) void conv_silu_kernel(
    const float* __restrict__ xz, const float* __restrict__ cw,
    const float* __restrict__ cb, float* __restrict__ xc)
{
    int idx = blockIdx.x * 256 + threadIdx.x;
    if (idx >= M_ * E_) return;
    int e = idx % E_;
    int m = idx / E_;
    int l = m % L_;
    float acc = cb[e];
    const float w0 = cw[e * 4 + 0], w1 = cw[e * 4 + 1],
                w2 = cw[e * 4 + 2], w3 = cw[e * 4 + 3];
    const float* base = xz + (size_t)m * (2 * E_) + e;
    if (l >= 3) acc += base[-3 * 2 * E_] * w0;
    if (l >= 2) acc += base[-2 * 2 * E_] * w1;
    if (l >= 1) acc += base[-1 * 2 * E_] * w2;
    acc += base[0] * w3;
    xc[idx] = acc / (1.f + __expf(-acc));
}

// ---------------------------------------------------------------------------
// Register-state chunked scan (NC=64, T=16).  One thread per (channel,chunk),
// 16 states in VGPRs.  sumA is stored in the dead xp-halves of xzb (sA_addr);
// sumH/hstart is linear [chunk][n][c] on the contiguous hs+region pair.
// ---------------------------------------------------------------------------
__global__ __launch_bounds__(256) void scan_part1(
    const float* __restrict__ xc, const float* __restrict__ dt,
    const float* __restrict__ dbl, const float* __restrict__ A_log,
    float* __restrict__ sumA_x, float* __restrict__ sumH)
{
    const int gid = blockIdx.x * 256 + threadIdx.x;   // over NC_*B_*E_
    const int c = gid % (B_ * E_);
    const int chunk = gid / (B_ * E_);
    const int b = c / E_;
    const int e = c % E_;

    float Av[N_];
    {
        const float4* Ap = (const float4*)(A_log + e * N_);
        float4 A0 = Ap[0], A1 = Ap[1], A2 = Ap[2], A3 = Ap[3];
        float Ax[N_] = {A0.x, A0.y, A0.z, A0.w, A1.x, A1.y, A1.z, A1.w,
                        A2.x, A2.y, A2.z, A2.w, A3.x, A3.y, A3.z, A3.w};
#pragma unroll
        for (int n = 0; n < N_; ++n) Av[n] = -__expf(Ax[n]);
    }

    float h[N_];
#pragma unroll
    for (int n = 0; n < N_; ++n) h[n] = 0.f;
    float dts = 0.f;

    const size_t m0 = (size_t)b * L_ + (size_t)chunk * T_;
    for (int l = 0; l < T_; ++l) {
        size_t m = m0 + l;
        float dtv = dt[m * E_ + e];
        float xv  = xc[m * E_ + e];
        float dtx = dtv * xv;
        const float4* Bp = (const float4*)(dbl + m * 80 + R_);
        float4 B0 = Bp[0], B1 = Bp[1], B2 = Bp[2], B3 = Bp[3];
        float Bv[N_] = {B0.x, B0.y, B0.z, B0.w, B1.x, B1.y, B1.z, B1.w,
                        B2.x, B2.y, B2.z, B2.w, B3.x, B3.y, B3.z, B3.w};
        dts += dtv;
#pragma unroll
        for (int n = 0; n < N_; ++n) {
            float dA = __expf(dtv * Av[n]);
            h[n] = dA * h[n] + dtx * Bv[n];
        }
    }
#pragma unroll
    for (int n = 0; n < N_; ++n) {
        sumA_x[sA_addr(chunk * N_ + n, c)] = __expf(Av[n] * dts);
        sumH[(size_t)(chunk * N_ + n) * (B_ * E_) + c] = h[n];
    }
}

// Phase 2: sequential combine across chunks; writes hstart IN PLACE over sumH.
__global__ __launch_bounds__(256) void scan_part2(
    const float* __restrict__ sumA_x, float* __restrict__ sumH)
{
    const int idx = blockIdx.x * 256 + threadIdx.x;   // n*(B*E) + c
    if (idx >= B_ * E_ * N_) return;
    const int n = idx / (B_ * E_);
    const int c = idx % (B_ * E_);
    float h = 0.f;
    for (int j = 0; j < NC_; ++j) {
        size_t o = (size_t)(j * N_ + n) * (B_ * E_) + c;
        float a  = sumA_x[sA_addr(j * N_ + n, c)];
        float hh = sumH[o];
        sumH[o] = h;                      // hstart for chunk j
        h = a * h + hh;
    }
}

// Phase 3: recompute chunk from hstart, emit y = (h·C + xc*D) * silu(z).
__global__ __launch_bounds__(256) void scan_part3(
    const float* __restrict__ xc, const float* __restrict__ dt,
    const float* __restrict__ dbl, const float* __restrict__ xz,
    const float* __restrict__ A_log, const float* __restrict__ ssm_D,
    const float* __restrict__ hstart, __bf16* __restrict__ y)
{
    const int gid = blockIdx.x * 256 + threadIdx.x;   // over NC_*B_*E_
    const int c = gid % (B_ * E_);
    const int chunk = gid / (B_ * E_);
    const int b = c / E_;
    const int e = c % E_;

    float Av[N_];
    {
        const float4* Ap = (const float4*)(A_log + e * N_);
        float4 A0 = Ap[0], A1 = Ap[1], A2 = Ap[2], A3 = Ap[3];
        float Ax[N_] = {A0.x, A0.y, A0.z, A0.w, A1.x, A1.y, A1.z, A1.w,
                        A2.x, A2.y, A2.z, A2.w, A3.x, A3.y, A3.z, A3.w};
#pragma unroll
        for (int n = 0; n < N_; ++n) Av[n] = -__expf(Ax[n]);
    }
    const float Dv = ssm_D[e];

    float h[N_];
#pragma unroll
    for (int n = 0; n < N_; ++n)
        h[n] = hstart[(size_t)(chunk * N_ + n) * (B_ * E_) + c];

    const size_t m0 = (size_t)b * L_ + (size_t)chunk * T_;
    for (int l = 0; l < T_; ++l) {
        size_t m = m0 + l;
        float dtv = dt[m * E_ + e];
        float xv  = xc[m * E_ + e];
        float dtx = dtv * xv;
        const float4* Bp = (const float4*)(dbl + m * 80 + R_);
        float4 B0 = Bp[0], B1 = Bp[1], B2 = Bp[2], B3 = Bp[3];
        float4 C0 = Bp[4], C1 = Bp[5], C2 = Bp[6], C3 = Bp[7];
        float Bv[N_] = {B0.x, B0.y, B0.z, B0.w, B1.x, B1.y, B1.z, B1.w,
                        B2.x, B2.y, B2.z, B2.w, B3.x, B3.y, B3.z, B3.w};
        float Cv[N_] = {C0.x, C0.y, C0.z, C0.w, C1.x, C1.y, C1.z, C1.w,
                        C2.x, C2.y, C2.z, C2.w, C3.x, C3.y, C3.z, C3.w};
        float p = 0.f;
#pragma unroll
        for (int n = 0; n < N_; ++n) {
            float dA = __expf(dtv * Av[n]);
            h[n] = dA * h[n] + dtx * Bv[n];
            p += h[n] * Cv[n];
        }
        float zv = xz[m * (2 * E_) + E_ + e];
        float yv = (p + xv * Dv) * (zv / (1.f + __expf(-zv)));
        y[m * E_ + e] = (__bf16)yv;
    }
}

// ---------------------------------------------------------------------------
__global__ __launch_bounds__(256) void final_out_kernel(
    const float* __restrict__ x, const float* __restrict__ gate,
    const float* __restrict__ mixed, const float* __restrict__ w,
    const float* __restrict__ b, float* __restrict__ outp)
{
    constexpr int D = DM_;
    const int row = blockIdx.x;
    const int tid = threadIdx.x;
    __shared__ float sm[4];
    const float* xp = x + (size_t)row * D;
    const float* gp = gate + (size_t)row * D;
    const float* mp = mixed + (size_t)row * D;

    float v[3];
    float s = 0.f;
#pragma unroll
    for (int j = 0; j < 3; ++j) {
        int d = j * 256 + tid;
        float xv = xp[d];
        float o = xv + gp[d] * (mp[d] - xv);
        v[j] = o;
        s += o;
    }
    float mean = block_sum(s, sm) * (1.f / D);
    float s2 = 0.f;
#pragma unroll
    for (int j = 0; j < 3; ++j) { float dlt = v[j] - mean; s2 += dlt * dlt; }
    float var = block_sum(s2, sm) * (1.f / D);
    float inv = rsqrtf(var + 1e-5f);
    float* op = outp + (size_t)row * D;
#pragma unroll
    for (int j = 0; j < 3; ++j) {
        int d = j * 256 + tid;
        op[d] = (v[j] - mean) * inv * w[d] + b[d];
    }
}

// ---------------------------------------------------------------------------
extern "C" void kernel_launch(void* const* d_in, const int* in_sizes, int n_in,
                              void* d_out, int out_size, void* d_ws, size_t ws_size,
                              hipStream_t stream)
{
    const float* x    = (const float*)d_in[0];
    const float* bp   = (const float*)d_in[1];
    const float* inw  = (const float*)d_in[2];
    const float* cw   = (const float*)d_in[3];
    const float* cb   = (const float*)d_in[4];
    const float* xpw  = (const float*)d_in[5];
    const float* dpw  = (const float*)d_in[6];
    const float* dpb  = (const float*)d_in[7];
    const float* alog = (const float*)d_in[8];
    const float* sD   = (const float*)d_in[9];
    const float* opw  = (const float*)d_in[10];
    const float* lnw  = (const float*)d_in[11];
    const float* lnb  = (const float*)d_in[12];
    const float* nfw  = (const float*)d_in[13];
    const float* nfb  = (const float*)d_in[14];
    const float* cw1  = (const float*)d_in[15];
    const float* cb1  = (const float*)d_in[16];
    const float* cw2  = (const float*)d_in[17];
    const float* cb2  = (const float*)d_in[18];
    const float* olnw = (const float*)d_in[19];
    const float* olnb = (const float*)d_in[20];
    float* out = (float*)d_out;

    // ---- workspace carve (floats), total ~78.5 MB (unchanged) ----
    float* p = (float*)d_ws;
    float* resid  = p;  p += (size_t)M_ * DM_;        // 6.3 MB, live all launch
    float* xzb    = p;  p += (size_t)M_ * 2 * E_;     // 25.2 MB; xp-halves -> sumA
    float* xcb    = p;  p += (size_t)M_ * E_;         // 12.6 MB; + x_bf/h1_bf at end
    float* dblb   = p;  p += (size_t)M_ * 80;         // 0.66 MB
    float* dtb    = p;  p += (size_t)M_ * E_;         // 12.6 MB; + hln_bf/xpart/mixed
    float* hs     = p;  p += (size_t)M_ * DM_;        // 6.3 MB  \ contiguous pair:
    float* region = p;  p += (size_t)M_ * DM_;        // 6.3 MB  / sumH = hs..region
    __bf16* y_bf  = (__bf16*)p; p += (size_t)M_ * E_ / 2;    // 6.3 MB
    __bf16* cw1b  = (__bf16*)p; p += (size_t)DM_ * DM_ / 2;  // 1.2 MB
    __bf16* cw2b  = (__bf16*)p; p += (size_t)DM_ * DM_ / 2;  // 1.2 MB
    float* gate   = out + (size_t)M_ * DM_;

    // overlays (timing-safe):
    __bf16* wbuf   = (__bf16*)region;   // weight cvt target; dead during scan
    float*  sumHst = hs;                // sumH/hstart: hs+region = 3.146M fl exact
    __bf16* hln_bf = (__bf16*)dtb;      // dead before dt GEMM writes dtb
    float*  xpart  = dtb;               // dead before dt GEMM writes dtb
    float*  mixedf = dtb;               // final phase only
    __bf16* x_bf   = (__bf16*)xcb;      // final phase only
    __bf16* h1_bf  = (__bf16*)(xcb + (size_t)M_ * DM_);
    float*  part01 = xzb;               // out_proj split-K partials

    // one-time weight conversions for the control MLP
    cvt_cw1_kernel<<<(DM_ * DM_) / 256, 256, 0, stream>>>(cw1, cw1b);
    cvt_bf16_kernel<<<(DM_ * DM_ / 8 + 255) / 256, 256, 0, stream>>>(
        cw2, cw2b, DM_ * DM_ / 8);

    for (int i = 0; i < NL_; ++i) {
        // resid (+)= src ; hln_bf = LN(resid) [bf16]  (on dtb: prev dt dead)
        add_ln_kernel<<<M_, 256, 0, stream>>>(i == 0 ? x : hs, resid,
                                              lnw + i * DM_, lnb + i * DM_,
                                              nullptr, hln_bf, i > 0 ? 1 : 0);
        // in_proj weights -> bf16 (wbuf on region; prev sumH dead)
        cvt_bf16_kernel<<<(2 * E_ * DM_ / 8) / 256, 256, 0, stream>>>(
            inw + (size_t)i * 2 * E_ * DM_, wbuf, 2 * E_ * DM_ / 8);
        // xz = hln @ in_proj^T : 2048 x 3072, K=768
        gemm_bf16<128><<<dim3(2 * E_ / 128, M_ / 128, 1), 256, 0, stream>>>(
            hln_bf, DM_, wbuf, DM_, xzb, 2 * E_, DM_, 0,
            nullptr, 0, nullptr, nullptr, 0);
        conv_silu_kernel<<<(M_ * E_) / 256, 256, 0, stream>>>(
            xzb, cw + (size_t)i * E_ * K_, cb + (size_t)i * E_, xcb);
        // dbl = xc @ x_proj^T (split-K partials on dtb; hln_bf dead)
        xproj_mfma<<<dim3(SK_, M_ / 128), 256, 0, stream>>>(
            xcb, xpw + (size_t)i * 80 * E_, xpart);
        xproj_reduce<<<(M_ * 80) / 256, 256, 0, stream>>>(xpart, dblb);
        // dt = softplus(dbl[:,:48] @ dt_proj^T + b)  (writes dtb; xpart dead)
        gemm_mfma<64><<<dim3(E_ / 64, M_ / 128), 256, 0, stream>>>(
            dblb, 80, dpw + (size_t)i * E_ * R_, R_, 1,
            dtb, E_, R_, dpb + (size_t)i * E_, 3, nullptr, nullptr, 0);
        // scan: part1 (sumA -> xzb xp-halves, dead after conv; sumH -> hs+region,
        // both dead during scan) -> part2 in place -> part3 emits gated y
        scan_part1<<<(NC_ * B_ * E_) / 256, 256, 0, stream>>>(
            xcb, dtb, dblb, alog + (size_t)i * E_ * N_, xzb, sumHst);
        scan_part2<<<(B_ * E_ * N_) / 256, 256, 0, stream>>>(xzb, sumHst);
        scan_part3<<<(NC_ * B_ * E_) / 256, 256, 0, stream>>>(
            xcb, dtb, dblb, xzb, alog + (size_t)i * E_ * N_, sD + (size_t)i * E_,
            sumHst, y_bf);
        // out_proj weights -> bf16 (wbuf on region; sumH dead after part3)
        cvt_bf16_kernel<<<(DM_ * E_ / 8) / 256, 256, 0, stream>>>(
            opw + (size_t)i * DM_ * E_, wbuf, DM_ * E_ / 8);
        // hs = y @ out_proj^T : split-K=2 partials on xzb (xz dead after part3)
        gemm_bf16<64><<<dim3(DM_ / 64, M_ / 128, 2), 256, 0, stream>>>(
            y_bf, E_, wbuf, E_, part01, DM_, E_ / 2, 0,
            nullptr, 0, nullptr, nullptr, 0);
        reduce2_kernel<<<(M_ * DM_) / 256, 256, 0, stream>>>(part01, hs);
    }

    // resid += hs ; mixed = LN(resid, normf) -> f32 on dtb (dt dead)
    add_ln_kernel<<<M_, 256, 0, stream>>>(hs, resid, nfw, nfb,
                                          mixedf, nullptr, 1);
    // x -> bf16 (xcb dead after last scan)
    cvt_bf16_kernel<<<(M_ * DM_ / 8) / 256, 256, 0, stream>>>(
        x, x_bf, M_ * DM_ / 8);
    // h1 = silu(x @ ctrl_w1[:,:768]^T + bp ⊗ ctrl_w1[:,768] + b1) -> bf16
    gemm_bf16<64><<<dim3(DM_ / 64, M_ / 128, 1), 256, 0, stream>>>(
        x_bf, DM_, cw1b, DM_, h1_bf, DM_, DM_, 1,
        cb1, 1, bp, cw1 + DM_, DM_ + 1);
    // gate = sigmoid(h1 @ ctrl_w2^T + b2) -> d_out[BLD:]
    gemm_bf16<64><<<dim3(DM_ / 64, M_ / 128, 1), 256, 0, stream>>>(
        h1_bf, DM_, cw2b, DM_, gate, DM_, DM_, 0,
        cb2, 2, nullptr, nullptr, 0);
    // out = x + gate*(mixed-x); d_out[:BLD] = LN(out)
    final_out_kernel<<<M_, 256, 0, stream>>>(x, gate, mixedf, olnw, olnb, out);
}

// Round 8
// 752.826 us; speedup vs baseline: 7.1737x; 1.0820x over previous
//
#include <hip/hip_runtime.h>
#include <math.h>

// Problem constants
static constexpr int B_  = 2;
static constexpr int L_  = 1024;
static constexpr int DM_ = 768;
static constexpr int NL_ = 4;
static constexpr int E_  = 2 * DM_;     // 1536
static constexpr int N_  = 16;
static constexpr int K_  = 4;
static constexpr int R_  = DM_ / 16;    // 48
static constexpr int M_  = B_ * L_;     // 2048 tokens
static constexpr int NC_ = 128;         // scan chunks per sequence
static constexpr int T_  = L_ / NC_;    // 8 steps per chunk
static constexpr int SK_ = 8;           // split-K slices for x_proj
static constexpr int KS_ = E_ / SK_;    // 192 per slice
static constexpr float LOG2E_ = 1.44269504088896340736f;

typedef __bf16 bf16x8 __attribute__((ext_vector_type(8)));
typedef short short8  __attribute__((ext_vector_type(8)));
typedef float f32x4   __attribute__((ext_vector_type(4)));

// ---------------------------------------------------------------------------
__device__ __forceinline__ short f2bf(float x) {
    __bf16 h = (__bf16)x;
    return __builtin_bit_cast(short, h);
}
__device__ __forceinline__ void st8(short* p, float4 x, float4 y) {
    short8 s;
    s[0] = f2bf(x.x); s[1] = f2bf(x.y); s[2] = f2bf(x.z); s[3] = f2bf(x.w);
    s[4] = f2bf(y.x); s[5] = f2bf(y.y); s[6] = f2bf(y.z); s[7] = f2bf(y.w);
    *(short8*)p = s;
}

// async global->LDS, 16 bytes per lane.
__device__ __forceinline__ void gload16(const void* g, void* l) {
    __builtin_amdgcn_global_load_lds(
        (const __attribute__((address_space(1))) unsigned int*)g,
        (__attribute__((address_space(3))) unsigned int*)l,
        16, 0, 0);
}

// ---------------------------------------------------------------------------
// bf16-input MFMA GEMM, m97 structure (global_load_lds 16B staging).
// ---------------------------------------------------------------------------
template<int BN>
__global__ __launch_bounds__(256) void gemm_bf16(
    const __bf16* __restrict__ A, int lda,
    const __bf16* __restrict__ W, int ldw,
    void* __restrict__ Cout, int ldc, int Kd, int out_bf16,
    const float* __restrict__ bias, int act,
    const float* __restrict__ u, const float* __restrict__ v, int vstride)
{
    constexpr int BM = 128;
    constexpr int WN = BN / 2;
    constexpr int FM = 4;
    constexpr int FN = WN / 16;

    __shared__ __bf16 As[BM * 32];
    __shared__ __bf16 Bs[BN * 32];

    const int tid  = threadIdx.x;
    const int lane = tid & 63;
    const int wave = tid >> 6;
    const int wr = wave >> 1, wc = wave & 1;
    const int bm = blockIdx.y * BM;
    const int bn = blockIdx.x * BN;
    const int sk = blockIdx.z;

    A += (size_t)sk * Kd;
    W += (size_t)sk * Kd;
    const size_t cz = (size_t)sk * (size_t)gridDim.y * BM * ldc;

    const int sr = tid >> 2;
    const int sc = (tid & 3) << 3;
    const __bf16* ag0 = A + (size_t)(bm + sr) * lda + sc;
    const __bf16* ag1 = A + (size_t)(bm + 64 + sr) * lda + sc;
    const __bf16* wg0 = W + (size_t)(bn + sr) * ldw + sc;
    const __bf16* wg1 = W + (size_t)(bn + 64 + sr) * ldw + sc;  // BN=128 only

    __bf16* lA0 = As + wave * 512;
    __bf16* lA1 = As + 2048 + wave * 512;
    __bf16* lB0 = Bs + wave * 512;
    __bf16* lB1 = Bs + 2048 + wave * 512;

    f32x4 acc[FM][FN];
#pragma unroll
    for (int i = 0; i < FM; ++i)
#pragma unroll
        for (int j = 0; j < FN; ++j)
            acc[i][j] = (f32x4){0.f, 0.f, 0.f, 0.f};

    const __bf16* ard = As + (wr * 64 + (lane & 15)) * 32 + ((lane >> 4) << 3);
    const __bf16* brd = Bs + (wc * WN + (lane & 15)) * 32 + ((lane >> 4) << 3);

    const int NT = Kd / 32;
    for (int t = 0; t < NT; ++t) {
        const int k0 = t * 32;
        __syncthreads();
        gload16(ag0 + k0, lA0);
        gload16(ag1 + k0, lA1);
        gload16(wg0 + k0, lB0);
        if constexpr (BN == 128) gload16(wg1 + k0, lB1);
        __syncthreads();
        bf16x8 af[FM], bf[FN];
#pragma unroll
        for (int m = 0; m < FM; ++m)
            af[m] = *(const bf16x8*)(ard + m * 512);
#pragma unroll
        for (int n = 0; n < FN; ++n)
            bf[n] = *(const bf16x8*)(brd + n * 512);
#pragma unroll
        for (int m = 0; m < FM; ++m)
#pragma unroll
            for (int n = 0; n < FN; ++n)
                acc[m][n] = __builtin_amdgcn_mfma_f32_16x16x32_bf16(
                    af[m], bf[n], acc[m][n], 0, 0, 0);
    }

#pragma unroll
    for (int m = 0; m < FM; ++m) {
        const int row0 = bm + wr * 64 + m * 16 + ((lane >> 4) << 2);
#pragma unroll
        for (int n = 0; n < FN; ++n) {
            const int col = bn + wc * WN + n * 16 + (lane & 15);
            const float bia = bias ? bias[col] : 0.f;
            const float vv = u ? v[(size_t)col * vstride] : 0.f;
#pragma unroll
            for (int r = 0; r < 4; ++r) {
                float val = acc[m][n][r] + bia;
                if (u) val += u[row0 + r] * vv;
                if (act == 1)      val = val / (1.f + __expf(-val));
                else if (act == 2) val = 1.f / (1.f + __expf(-val));
                size_t off = cz + (size_t)(row0 + r) * ldc + col;
                if (out_bf16) ((__bf16*)Cout)[off] = (__bf16)val;
                else          ((float*)Cout)[off]  = val;
            }
        }
    }
}

// ---------------------------------------------------------------------------
__global__ __launch_bounds__(256) void cvt_bf16_kernel(
    const float* __restrict__ src, __bf16* __restrict__ dst, int n8)
{
    int i = blockIdx.x * 256 + threadIdx.x;
    if (i >= n8) return;
    const float4* s = (const float4*)src;
    st8((short*)(dst + (size_t)i * 8), s[2 * i], s[2 * i + 1]);
}

// ctrl_w1 [768][769] -> bf16 [768][768] (drop last column)
__global__ __launch_bounds__(256) void cvt_cw1_kernel(
    const float* __restrict__ src, __bf16* __restrict__ dst)
{
    int idx = blockIdx.x * 256 + threadIdx.x;
    if (idx >= DM_ * DM_) return;
    int r = idx / DM_, c = idx % DM_;
    dst[idx] = (__bf16)src[(size_t)r * (DM_ + 1) + c];
}

__global__ __launch_bounds__(256) void reduce2_kernel(
    const float* __restrict__ p, float* __restrict__ out)
{
    int idx = blockIdx.x * 256 + threadIdx.x;   // over M_*DM_
    out[idx] = p[idx] + p[(size_t)M_ * DM_ + idx];
}

// ---------------------------------------------------------------------------
// reg-staged f32->bf16 MFMA GEMM (kept for dt_proj: K=48)
// ---------------------------------------------------------------------------
template<int BN>
__global__ __launch_bounds__(256) void gemm_mfma(
    const float* __restrict__ A, int lda,
    const float* __restrict__ W, int ldw, int walign,
    float* __restrict__ C, int ldc, int Kd,
    const float* __restrict__ bias, int act,
    const float* __restrict__ u, const float* __restrict__ v, int vstride)
{
    constexpr int BM = 128;
    constexpr int SA = 40;
    constexpr int WN = BN / 2;
    constexpr int FM = 4;
    constexpr int FN = WN / 16;
    constexpr int BRT = 256 / BN;
    constexpr int NB4 = 32 / BRT / 4;

    __shared__ short As[BM * SA];
    __shared__ short Bs[BN * SA];

    const int tid  = threadIdx.x;
    const int lane = tid & 63;
    const int wave = tid >> 6;
    const int wr = wave >> 1, wc = wave & 1;
    const int bm = blockIdx.y * BM;
    const int bn = blockIdx.x * BN;

    const int ar = tid >> 1;
    const int ac = (tid & 1) << 4;
    const float* aptr = A + (size_t)(bm + ar) * lda + ac;
    short* awr = &As[ar * SA + ac];

    const int br = tid / BRT;
    const int bc = (tid % BRT) * (32 / BRT);
    const float* wptr = W + (size_t)(bn + br) * ldw + bc;
    short* bwr = &Bs[br * SA + bc];

    f32x4 acc[FM][FN];
#pragma unroll
    for (int i = 0; i < FM; ++i)
#pragma unroll
        for (int j = 0; j < FN; ++j)
            acc[i][j] = (f32x4){0.f, 0.f, 0.f, 0.f};

    const short* ard = &As[(wr * 64 + (lane & 15)) * SA + ((lane >> 4) << 3)];
    const short* brd = &Bs[(wc * WN + (lane & 15)) * SA + ((lane >> 4) << 3)];

    float4 aR[4], bR[NB4];
    auto loadA = [&](int k0) {
        if (k0 + ac < Kd) {
#pragma unroll
            for (int i = 0; i < 4; ++i)
                aR[i] = *(const float4*)(aptr + k0 + i * 4);
        } else {
#pragma unroll
            for (int i = 0; i < 4; ++i) aR[i] = {0.f, 0.f, 0.f, 0.f};
        }
    };
    auto loadW = [&](int k0) {
        const float* p = wptr + k0;
        if (k0 + bc < Kd) {
            if (walign) {
#pragma unroll
                for (int i = 0; i < NB4; ++i)
                    bR[i] = *(const float4*)(p + i * 4);
            } else {
#pragma unroll
                for (int i = 0; i < NB4; ++i) {
                    bR[i].x = p[i * 4 + 0]; bR[i].y = p[i * 4 + 1];
                    bR[i].z = p[i * 4 + 2]; bR[i].w = p[i * 4 + 3];
                }
            }
        } else {
#pragma unroll
            for (int i = 0; i < NB4; ++i) bR[i] = {0.f, 0.f, 0.f, 0.f};
        }
    };

    const int NT = (Kd + 31) / 32;
    loadA(0); loadW(0);

    for (int t = 0; t < NT; ++t) {
        __syncthreads();
        st8(awr, aR[0], aR[1]);
        st8(awr + 8, aR[2], aR[3]);
        st8(bwr, bR[0], bR[1]);
        if constexpr (NB4 == 4) st8(bwr + 8, bR[2], bR[3]);
        __syncthreads();
        if (t + 1 < NT) { loadA((t + 1) * 32); loadW((t + 1) * 32); }
        bf16x8 af[FM], bf[FN];
#pragma unroll
        for (int m = 0; m < FM; ++m)
            af[m] = *(const bf16x8*)(ard + m * 16 * SA);
#pragma unroll
        for (int n = 0; n < FN; ++n)
            bf[n] = *(const bf16x8*)(brd + n * 16 * SA);
#pragma unroll
        for (int m = 0; m < FM; ++m)
#pragma unroll
            for (int n = 0; n < FN; ++n)
                acc[m][n] = __builtin_amdgcn_mfma_f32_16x16x32_bf16(
                    af[m], bf[n], acc[m][n], 0, 0, 0);
    }

#pragma unroll
    for (int m = 0; m < FM; ++m) {
        const int row0 = bm + wr * 64 + m * 16 + ((lane >> 4) << 2);
#pragma unroll
        for (int n = 0; n < FN; ++n) {
            const int col = bn + wc * WN + n * 16 + (lane & 15);
            const float bia = bias ? bias[col] : 0.f;
            const float vv = u ? v[(size_t)col * vstride] : 0.f;
#pragma unroll
            for (int r = 0; r < 4; ++r) {
                float val = acc[m][n][r] + bia;
                if (u) val += u[row0 + r] * vv;
                if (act == 1)      val = val / (1.f + __expf(-val));
                else if (act == 2) val = 1.f / (1.f + __expf(-val));
                else if (act == 3) val = (val > 20.f) ? val : log1pf(__expf(val));
                C[(size_t)(row0 + r) * ldc + col] = val;
            }
        }
    }
}

// ---------------------------------------------------------------------------
// x_proj split-K MFMA (reg-staged f32)
// ---------------------------------------------------------------------------
__global__ __launch_bounds__(256) void xproj_mfma(
    const float* __restrict__ A, const float* __restrict__ W,
    float* __restrict__ part)
{
    constexpr int SA = 40;
    __shared__ short As[128 * SA];
    __shared__ short Ws[80 * SA];

    const int tid  = threadIdx.x;
    const int lane = tid & 63;
    const int wave = tid >> 6;
    const int sk = blockIdx.x;
    const int bm = blockIdx.y * 128;
    const int kbase = sk * KS_;

    const int ar = tid >> 1;
    const int ac = (tid & 1) << 4;
    const float* aptr = A + (size_t)(bm + ar) * E_ + kbase + ac;
    short* awr = &As[ar * SA + ac];

    const bool wact = tid < 160;
    const int wrow = tid >> 1;
    const float* wptr = W + (size_t)wrow * E_ + kbase + ac;
    short* wwr = &Ws[wrow * SA + ac];

    f32x4 acc[2][5];
#pragma unroll
    for (int i = 0; i < 2; ++i)
#pragma unroll
        for (int j = 0; j < 5; ++j)
            acc[i][j] = (f32x4){0.f, 0.f, 0.f, 0.f};

    const short* ard = &As[(wave * 32 + (lane & 15)) * SA + ((lane >> 4) << 3)];
    const short* brd = &Ws[(lane & 15) * SA + ((lane >> 4) << 3)];

    float4 aR[4], wR[4];
    auto loadT = [&](int k0) {
#pragma unroll
        for (int i = 0; i < 4; ++i)
            aR[i] = *(const float4*)(aptr + k0 + i * 4);
        if (wact) {
#pragma unroll
            for (int i = 0; i < 4; ++i)
                wR[i] = *(const float4*)(wptr + k0 + i * 4);
        }
    };

    constexpr int NT = KS_ / 32;
    loadT(0);
    for (int t = 0; t < NT; ++t) {
        __syncthreads();
        st8(awr, aR[0], aR[1]);
        st8(awr + 8, aR[2], aR[3]);
        if (wact) {
            st8(wwr, wR[0], wR[1]);
            st8(wwr + 8, wR[2], wR[3]);
        }
        __syncthreads();
        if (t + 1 < NT) loadT((t + 1) * 32);
        bf16x8 af[2], bf[5];
#pragma unroll
        for (int m = 0; m < 2; ++m)
            af[m] = *(const bf16x8*)(ard + m * 16 * SA);
#pragma unroll
        for (int n = 0; n < 5; ++n)
            bf[n] = *(const bf16x8*)(brd + n * 16 * SA);
#pragma unroll
        for (int m = 0; m < 2; ++m)
#pragma unroll
            for (int n = 0; n < 5; ++n)
                acc[m][n] = __builtin_amdgcn_mfma_f32_16x16x32_bf16(
                    af[m], bf[n], acc[m][n], 0, 0, 0);
    }

    float* pout = part + (size_t)sk * M_ * 80;
#pragma unroll
    for (int m = 0; m < 2; ++m) {
        const int row0 = bm + wave * 32 + m * 16 + ((lane >> 4) << 2);
#pragma unroll
        for (int n = 0; n < 5; ++n) {
            const int col = n * 16 + (lane & 15);
#pragma unroll
            for (int r = 0; r < 4; ++r)
                pout[(size_t)(row0 + r) * 80 + col] = acc[m][n][r];
        }
    }
}

__global__ __launch_bounds__(256) void xproj_reduce(
    const float* __restrict__ part, float* __restrict__ dbl)
{
    int idx = blockIdx.x * 256 + threadIdx.x;
    float s = 0.f;
#pragma unroll
    for (int k = 0; k < SK_; ++k) s += part[(size_t)k * M_ * 80 + idx];
    dbl[idx] = s;
}

// ---------------------------------------------------------------------------
__device__ __forceinline__ float block_sum(float val, float* sm) {
#pragma unroll
    for (int o = 32; o > 0; o >>= 1) val += __shfl_down(val, o);
    int lane = threadIdx.x & 63, wid = threadIdx.x >> 6;
    __syncthreads();
    if (lane == 0) sm[wid] = val;
    __syncthreads();
    return sm[0] + sm[1] + sm[2] + sm[3];
}

// ---------------------------------------------------------------------------
__global__ __launch_bounds__(256) void add_ln_kernel(
    const float* __restrict__ src, float* __restrict__ resid,
    const float* __restrict__ w, const float* __restrict__ b,
    float* __restrict__ outf, __bf16* __restrict__ outb, int do_add)
{
    constexpr int D = DM_;
    const int row = blockIdx.x;
    const int tid = threadIdx.x;
    __shared__ float sm[4];
    const float* sp = src + (size_t)row * D;
    float* rp = resid + (size_t)row * D;

    float v[3];
    float s = 0.f;
#pragma unroll
    for (int j = 0; j < 3; ++j) {
        int d = j * 256 + tid;
        float vv = sp[d];
        if (do_add) vv += rp[d];
        rp[d] = vv;
        v[j] = vv;
        s += vv;
    }
    float mean = block_sum(s, sm) * (1.f / D);
    float s2 = 0.f;
#pragma unroll
    for (int j = 0; j < 3; ++j) { float dlt = v[j] - mean; s2 += dlt * dlt; }
    float var = block_sum(s2, sm) * (1.f / D);
    float inv = rsqrtf(var + 1e-5f);
#pragma unroll
    for (int j = 0; j < 3; ++j) {
        int d = j * 256 + tid;
        float r = (v[j] - mean) * inv * w[d] + b[d];
        if (outf) outf[(size_t)row * D + d] = r;
        if (outb) outb[(size_t)row * D + d] = (__bf16)r;
    }
}

// ---------------------------------------------------------------------------
// Causal depthwise conv (K=4) + bias + silu, 4 channels per thread (float4).
// ---------------------------------------------------------------------------
__global__ __launch_bounds__(256) void conv_silu_kernel(
    const float* __restrict__ xz, const float* __restrict__ cw,
    const float* __restrict__ cb, float* __restrict__ xc)
{
    const int idx = blockIdx.x * 256 + threadIdx.x;    // over M_*E_/4
    if (idx >= M_ * E_ / 4) return;
    const int ec = (idx % (E_ / 4)) * 4;
    const int m  = idx / (E_ / 4);
    const int l  = m % L_;

    const float4 z4 = {0.f, 0.f, 0.f, 0.f};
    const float* base = xz + (size_t)m * (2 * E_) + ec;
    float4 x0 = *(const float4*)base;                          // l
    float4 x1 = (l >= 1) ? *(const float4*)(base - 2 * E_) : z4;
    float4 x2 = (l >= 2) ? *(const float4*)(base - 4 * E_) : z4;
    float4 x3 = (l >= 3) ? *(const float4*)(base - 6 * E_) : z4;
    const float4* wp = (const float4*)(cw + (size_t)ec * 4);   // w[ec+j][0..3]
    float4 w0 = wp[0], w1 = wp[1], w2 = wp[2], w3 = wp[3];
    float4 bv = *(const float4*)(cb + ec);

    float4 o;
    o.x = bv.x + x3.x * w0.x + x2.x * w0.y + x1.x * w0.z + x0.x * w0.w;
    o.y = bv.y + x3.y * w1.x + x2.y * w1.y + x1.y * w1.z + x0.y * w1.w;
    o.z = bv.z + x3.z * w2.x + x2.z * w2.y + x1.z * w2.z + x0.z * w2.w;
    o.w = bv.w + x3.w * w3.x + x2.w * w3.y + x1.w * w3.z + x0.w * w3.w;
    o.x = o.x / (1.f + __expf(-o.x));
    o.y = o.y / (1.f + __expf(-o.y));
    o.z = o.z / (1.f + __expf(-o.z));
    o.w = o.w / (1.f + __expf(-o.w));
    *(float4*)(xc + (size_t)m * E_ + ec) = o;
}

// ---------------------------------------------------------------------------
// Register-state chunked scan (NC=128, T=8).  One thread per (channel,chunk),
// 16 states in VGPRs.  Av is pre-scaled by log2(e) so dA = exp2f(dt*Av).
// Summary layout [chunk][n][c] (c = b*E+e), fully coalesced in c.
// ---------------------------------------------------------------------------
__global__ __launch_bounds__(256) void scan_part1(
    const float* __restrict__ xc, const float* __restrict__ dt,
    const float* __restrict__ dbl, const float* __restrict__ A_log,
    float* __restrict__ sumA, float* __restrict__ sumH)
{
    const int gid = blockIdx.x * 256 + threadIdx.x;   // over NC_*B_*E_
    const int c = gid % (B_ * E_);
    const int chunk = gid / (B_ * E_);
    const int b = c / E_;
    const int e = c % E_;

    float Av[N_];
    {
        const float4* Ap = (const float4*)(A_log + e * N_);
        float4 A0 = Ap[0], A1 = Ap[1], A2 = Ap[2], A3 = Ap[3];
        float Ax[N_] = {A0.x, A0.y, A0.z, A0.w, A1.x, A1.y, A1.z, A1.w,
                        A2.x, A2.y, A2.z, A2.w, A3.x, A3.y, A3.z, A3.w};
#pragma unroll
        for (int n = 0; n < N_; ++n) Av[n] = -__expf(Ax[n]) * LOG2E_;
    }

    float h[N_];
#pragma unroll
    for (int n = 0; n < N_; ++n) h[n] = 0.f;
    float dts = 0.f;

    const size_t m0 = (size_t)b * L_ + (size_t)chunk * T_;
#pragma unroll
    for (int l = 0; l < T_; ++l) {
        size_t m = m0 + l;
        float dtv = dt[m * E_ + e];
        float xv  = xc[m * E_ + e];
        float dtx = dtv * xv;
        const float4* Bp = (const float4*)(dbl + m * 80 + R_);
        float4 B0 = Bp[0], B1 = Bp[1], B2 = Bp[2], B3 = Bp[3];
        float Bv[N_] = {B0.x, B0.y, B0.z, B0.w, B1.x, B1.y, B1.z, B1.w,
                        B2.x, B2.y, B2.z, B2.w, B3.x, B3.y, B3.z, B3.w};
        dts += dtv;
#pragma unroll
        for (int n = 0; n < N_; ++n) {
            float dA = exp2f(dtv * Av[n]);
            h[n] = dA * h[n] + dtx * Bv[n];
        }
    }
#pragma unroll
    for (int n = 0; n < N_; ++n) {
        size_t o = (size_t)(chunk * N_ + n) * (B_ * E_) + c;
        sumA[o] = exp2f(Av[n] * dts);
        sumH[o] = h[n];
    }
}

// Phase 2: sequential combine across chunks; writes hstart IN PLACE over sumH.
__global__ __launch_bounds__(256) void scan_part2(
    const float* __restrict__ sumA, float* __restrict__ sumH)
{
    const int idx = blockIdx.x * 256 + threadIdx.x;   // n*(B*E) + c
    if (idx >= B_ * E_ * N_) return;
    float h = 0.f;
    for (int j = 0; j < NC_; ++j) {
        size_t o = (size_t)j * N_ * (B_ * E_) + idx;
        float a  = sumA[o];
        float hh = sumH[o];
        sumH[o] = h;                      // hstart for chunk j
        h = a * h + hh;
    }
}

// Phase 3: recompute chunk from hstart, emit y = (h·C + xc*D) * silu(z).
__global__ __launch_bounds__(256) void scan_part3(
    const float* __restrict__ xc, const float* __restrict__ dt,
    const float* __restrict__ dbl, const float* __restrict__ xz,
    const float* __restrict__ A_log, const float* __restrict__ ssm_D,
    const float* __restrict__ hstart, __bf16* __restrict__ y)
{
    const int gid = blockIdx.x * 256 + threadIdx.x;   // over NC_*B_*E_
    const int c = gid % (B_ * E_);
    const int chunk = gid / (B_ * E_);
    const int b = c / E_;
    const int e = c % E_;

    float Av[N_];
    {
        const float4* Ap = (const float4*)(A_log + e * N_);
        float4 A0 = Ap[0], A1 = Ap[1], A2 = Ap[2], A3 = Ap[3];
        float Ax[N_] = {A0.x, A0.y, A0.z, A0.w, A1.x, A1.y, A1.z, A1.w,
                        A2.x, A2.y, A2.z, A2.w, A3.x, A3.y, A3.z, A3.w};
#pragma unroll
        for (int n = 0; n < N_; ++n) Av[n] = -__expf(Ax[n]) * LOG2E_;
    }
    const float Dv = ssm_D[e];

    float h[N_];
#pragma unroll
    for (int n = 0; n < N_; ++n)
        h[n] = hstart[(size_t)(chunk * N_ + n) * (B_ * E_) + c];

    const size_t m0 = (size_t)b * L_ + (size_t)chunk * T_;
#pragma unroll
    for (int l = 0; l < T_; ++l) {
        size_t m = m0 + l;
        float dtv = dt[m * E_ + e];
        float xv  = xc[m * E_ + e];
        float dtx = dtv * xv;
        const float4* Bp = (const float4*)(dbl + m * 80 + R_);
        float4 B0 = Bp[0], B1 = Bp[1], B2 = Bp[2], B3 = Bp[3];
        float4 C0 = Bp[4], C1 = Bp[5], C2 = Bp[6], C3 = Bp[7];
        float Bv[N_] = {B0.x, B0.y, B0.z, B0.w, B1.x, B1.y, B1.z, B1.w,
                        B2.x, B2.y, B2.z, B2.w, B3.x, B3.y, B3.z, B3.w};
        float Cv[N_] = {C0.x, C0.y, C0.z, C0.w, C1.x, C1.y, C1.z, C1.w,
                        C2.x, C2.y, C2.z, C2.w, C3.x, C3.y, C3.z, C3.w};
        float p = 0.f;
#pragma unroll
        for (int n = 0; n < N_; ++n) {
            float dA = exp2f(dtv * Av[n]);
            h[n] = dA * h[n] + dtx * Bv[n];
            p += h[n] * Cv[n];
        }
        float zv = xz[m * (2 * E_) + E_ + e];
        float yv = (p + xv * Dv) * (zv / (1.f + __expf(-zv)));
        y[m * E_ + e] = (__bf16)yv;
    }
}

// ---------------------------------------------------------------------------
__global__ __launch_bounds__(256) void final_out_kernel(
    const float* __restrict__ x, const float* __restrict__ gate,
    const float* __restrict__ mixed, const float* __restrict__ w,
    const float* __restrict__ b, float* __restrict__ outp)
{
    constexpr int D = DM_;
    const int row = blockIdx.x;
    const int tid = threadIdx.x;
    __shared__ float sm[4];
    const float* xp = x + (size_t)row * D;
    const float* gp = gate + (size_t)row * D;
    const float* mp = mixed + (size_t)row * D;

    float v[3];
    float s = 0.f;
#pragma unroll
    for (int j = 0; j < 3; ++j) {
        int d = j * 256 + tid;
        float xv = xp[d];
        float o = xv + gp[d] * (mp[d] - xv);
        v[j] = o;
        s += o;
    }
    float mean = block_sum(s, sm) * (1.f / D);
    float s2 = 0.f;
#pragma unroll
    for (int j = 0; j < 3; ++j) { float dlt = v[j] - mean; s2 += dlt * dlt; }
    float var = block_sum(s2, sm) * (1.f / D);
    float inv = rsqrtf(var + 1e-5f);
    float* op = outp + (size_t)row * D;
#pragma unroll
    for (int j = 0; j < 3; ++j) {
        int d = j * 256 + tid;
        op[d] = (v[j] - mean) * inv * w[d] + b[d];
    }
}

// ---------------------------------------------------------------------------
extern "C" void kernel_launch(void* const* d_in, const int* in_sizes, int n_in,
                              void* d_out, int out_size, void* d_ws, size_t ws_size,
                              hipStream_t stream)
{
    const float* x    = (const float*)d_in[0];
    const float* bp   = (const float*)d_in[1];
    const float* inw  = (const float*)d_in[2];
    const float* cw   = (const float*)d_in[3];
    const float* cb   = (const float*)d_in[4];
    const float* xpw  = (const float*)d_in[5];
    const float* dpw  = (const float*)d_in[6];
    const float* dpb  = (const float*)d_in[7];
    const float* alog = (const float*)d_in[8];
    const float* sD   = (const float*)d_in[9];
    const float* opw  = (const float*)d_in[10];
    const float* lnw  = (const float*)d_in[11];
    const float* lnb  = (const float*)d_in[12];
    const float* nfw  = (const float*)d_in[13];
    const float* nfb  = (const float*)d_in[14];
    const float* cw1  = (const float*)d_in[15];
    const float* cb1  = (const float*)d_in[16];
    const float* cw2  = (const float*)d_in[17];
    const float* cb2  = (const float*)d_in[18];
    const float* olnw = (const float*)d_in[19];
    const float* olnb = (const float*)d_in[20];
    float* out = (float*)d_out;

    // ---- workspace carve (floats), total ~184 MB (ws_size = 256 MiB) ----
    float* p = (float*)d_ws;
    float* resid  = p;  p += (size_t)M_ * DM_;            // 6.3 MB
    float* xzb    = p;  p += (size_t)M_ * 2 * E_;         // 25.2 MB
    float* xcb    = p;  p += (size_t)M_ * E_;             // 12.6 MB
    float* dblb   = p;  p += (size_t)M_ * 80;             // 0.66 MB
    float* dtb    = p;  p += (size_t)M_ * E_;             // 12.6 MB
    float* hs     = p;  p += (size_t)M_ * DM_;            // 6.3 MB
    float* mixedf = p;  p += (size_t)M_ * DM_;            // 6.3 MB
    float* sumA   = p;  p += (size_t)NC_ * N_ * B_ * E_;  // 25.2 MB
    float* sumHst = p;  p += (size_t)NC_ * N_ * B_ * E_;  // 25.2 MB
    float* part01 = p;  p += (size_t)2 * M_ * DM_;        // 12.6 MB
    float* xpart  = p;  p += (size_t)SK_ * M_ * 80;       // 5.2 MB
    __bf16* y_bf   = (__bf16*)p; p += (size_t)M_ * E_ / 2;          // 6.3 MB
    __bf16* hln_bf = (__bf16*)p; p += (size_t)M_ * DM_ / 2;         // 3.1 MB
    __bf16* inw_bf = (__bf16*)p; p += (size_t)NL_ * 2 * E_ * DM_ / 2; // 18.9 MB
    __bf16* opw_bf = (__bf16*)p; p += (size_t)NL_ * DM_ * E_ / 2;   // 9.4 MB
    __bf16* cw1b   = (__bf16*)p; p += (size_t)DM_ * DM_ / 2;        // 1.2 MB
    __bf16* cw2b   = (__bf16*)p; p += (size_t)DM_ * DM_ / 2;        // 1.2 MB
    __bf16* x_bf   = (__bf16*)p; p += (size_t)M_ * DM_ / 2;         // 3.1 MB
    __bf16* h1_bf  = (__bf16*)p; p += (size_t)M_ * DM_ / 2;         // 3.1 MB
    float* gate   = out + (size_t)M_ * DM_;

    // ---- one-time weight conversions (all layers) ----
    cvt_bf16_kernel<<<(NL_ * 2 * E_ * DM_ / 8) / 256, 256, 0, stream>>>(
        inw, inw_bf, NL_ * 2 * E_ * DM_ / 8);
    cvt_bf16_kernel<<<(NL_ * DM_ * E_ / 8) / 256, 256, 0, stream>>>(
        opw, opw_bf, NL_ * DM_ * E_ / 8);
    cvt_cw1_kernel<<<(DM_ * DM_) / 256, 256, 0, stream>>>(cw1, cw1b);
    cvt_bf16_kernel<<<(DM_ * DM_ / 8 + 255) / 256, 256, 0, stream>>>(
        cw2, cw2b, DM_ * DM_ / 8);
    cvt_bf16_kernel<<<(M_ * DM_ / 8) / 256, 256, 0, stream>>>(
        x, x_bf, M_ * DM_ / 8);

    for (int i = 0; i < NL_; ++i) {
        // resid (+)= src ; hln_bf = LN(resid) [bf16]
        add_ln_kernel<<<M_, 256, 0, stream>>>(i == 0 ? x : hs, resid,
                                              lnw + i * DM_, lnb + i * DM_,
                                              nullptr, hln_bf, i > 0 ? 1 : 0);
        // xz = hln @ in_proj^T : 2048 x 3072, K=768
        gemm_bf16<128><<<dim3(2 * E_ / 128, M_ / 128, 1), 256, 0, stream>>>(
            hln_bf, DM_, inw_bf + (size_t)i * 2 * E_ * DM_, DM_, xzb, 2 * E_,
            DM_, 0, nullptr, 0, nullptr, nullptr, 0);
        conv_silu_kernel<<<(M_ * E_ / 4) / 256, 256, 0, stream>>>(
            xzb, cw + (size_t)i * E_ * K_, cb + (size_t)i * E_, xcb);
        // dbl = xc @ x_proj^T (split-K)
        xproj_mfma<<<dim3(SK_, M_ / 128), 256, 0, stream>>>(
            xcb, xpw + (size_t)i * 80 * E_, xpart);
        xproj_reduce<<<(M_ * 80) / 256, 256, 0, stream>>>(xpart, dblb);
        // dt = softplus(dbl[:,:48] @ dt_proj^T + b)
        gemm_mfma<64><<<dim3(E_ / 64, M_ / 128), 256, 0, stream>>>(
            dblb, 80, dpw + (size_t)i * E_ * R_, R_, 1,
            dtb, E_, R_, dpb + (size_t)i * E_, 3, nullptr, nullptr, 0);
        // chunked scan
        scan_part1<<<(NC_ * B_ * E_) / 256, 256, 0, stream>>>(
            xcb, dtb, dblb, alog + (size_t)i * E_ * N_, sumA, sumHst);
        scan_part2<<<(B_ * E_ * N_) / 256, 256, 0, stream>>>(sumA, sumHst);
        scan_part3<<<(NC_ * B_ * E_) / 256, 256, 0, stream>>>(
            xcb, dtb, dblb, xzb, alog + (size_t)i * E_ * N_, sD + (size_t)i * E_,
            sumHst, y_bf);
        // hs = y @ out_proj^T : split-K=2
        gemm_bf16<64><<<dim3(DM_ / 64, M_ / 128, 2), 256, 0, stream>>>(
            y_bf, E_, opw_bf + (size_t)i * DM_ * E_, E_, part01, DM_,
            E_ / 2, 0, nullptr, 0, nullptr, nullptr, 0);
        reduce2_kernel<<<(M_ * DM_) / 256, 256, 0, stream>>>(part01, hs);
    }

    // resid += hs ; mixed = LN(resid, normf)
    add_ln_kernel<<<M_, 256, 0, stream>>>(hs, resid, nfw, nfb,
                                          mixedf, nullptr, 1);
    // h1 = silu(x @ ctrl_w1[:,:768]^T + bp ⊗ ctrl_w1[:,768] + b1) -> bf16
    gemm_bf16<64><<<dim3(DM_ / 64, M_ / 128, 1), 256, 0, stream>>>(
        x_bf, DM_, cw1b, DM_, h1_bf, DM_, DM_, 1,
        cb1, 1, bp, cw1 + DM_, DM_ + 1);
    // gate = sigmoid(h1 @ ctrl_w2^T + b2) -> d_out[BLD:]
    gemm_bf16<64><<<dim3(DM_ / 64, M_ / 128, 1), 256, 0, stream>>>(
        h1_bf, DM_, cw2b, DM_, gate, DM_, DM_, 0,
        cb2, 2, nullptr, nullptr, 0);
    // out = x + gate*(mixed-x); d_out[:BLD] = LN(out)
    final_out_kernel<<<M_, 256, 0, stream>>>(x, gate, mixedf, olnw, olnb, out);
}